// Round 4
// baseline (65934.705 us; speedup 1.0000x reference)
//
#include <hip/hip_runtime.h>
#include <hip/hip_bf16.h>

#define Bb   64
#define Tt   12
#define Nn   1024
#define HORt 12
#define Hh   128
#define Ee   16
#define Mm   20
#define MDd  64
#define DECHd 192
#define LDXG 582              // xg row length = 3*194 (max of enc 387 / dec 582)
#define LDX  (Bb*LDXG)        // per-node stride in xg = 37248
#define LDZR 384

// ---------------------------------------------------------------------------
// diagnostic: if ws_size is too small, report it via the output (absmax ~ MB)
// ---------------------------------------------------------------------------
__global__ void ws_probe_kernel(float* __restrict__ out, float val)
{
    size_t i = (size_t)blockIdx.x*256 + threadIdx.x;
    out[i] = val;
}

// ---------------------------------------------------------------------------
// supports = softmax(relu(emb @ emb^T), axis=1)   (one block per row)
// ---------------------------------------------------------------------------
__global__ __launch_bounds__(256) void supports_kernel(const float* __restrict__ emb,
                                                       float* __restrict__ S)
{
    int n = blockIdx.x;
    __shared__ float row[Nn];
    __shared__ float en[Ee];
    __shared__ float red[256];
    int tid = threadIdx.x;
    if (tid < Ee) en[tid] = emb[n*Ee + tid];
    __syncthreads();
    float lmax = -1e30f;
    for (int j = tid; j < Nn; j += 256){
        float d = 0.f;
        #pragma unroll
        for (int e = 0; e < Ee; ++e) d += en[e]*emb[j*Ee + e];
        d = d > 0.f ? d : 0.f;
        row[j] = d;
        lmax = fmaxf(lmax, d);
    }
    red[tid] = lmax; __syncthreads();
    for (int s = 128; s > 0; s >>= 1){ if (tid < s) red[tid] = fmaxf(red[tid], red[tid+s]); __syncthreads(); }
    float mx = red[0]; __syncthreads();
    float lsum = 0.f;
    for (int j = tid; j < Nn; j += 256){ float e = expf(row[j]-mx); row[j] = e; lsum += e; }
    red[tid] = lsum; __syncthreads();
    for (int s = 128; s > 0; s >>= 1){ if (tid < s) red[tid] += red[tid+s]; __syncthreads(); }
    float inv = 1.f/red[0];
    for (int j = tid; j < Nn; j += 256) S[n*Nn + j] = row[j]*inv;
}

// ---------------------------------------------------------------------------
// T2 = 2*S@S - I    (64x64 tiles, BK=16, 4x4 micro)
// ---------------------------------------------------------------------------
__global__ __launch_bounds__(256) void t2_gemm(const float* __restrict__ S,
                                               float* __restrict__ T2)
{
    int n0 = blockIdx.y*64, j0 = blockIdx.x*64;
    __shared__ float As[16][65];
    __shared__ float Xs[16][65];
    int tid = threadIdx.x; int tx = tid & 15, ty = tid >> 4;
    float acc[4][4] = {};
    for (int k0 = 0; k0 < Nn; k0 += 16){
        #pragma unroll
        for (int r = 0; r < 4; ++r){
            int idx = tid + r*256;
            int ar = idx >> 4, ak = idx & 15;
            As[ak][ar] = S[(n0+ar)*Nn + k0+ak];
        }
        #pragma unroll
        for (int r = 0; r < 4; ++r){
            int idx = tid + r*256;
            int xm = idx >> 6, xj = idx & 63;
            Xs[xm][xj] = S[(k0+xm)*Nn + j0+xj];
        }
        __syncthreads();
        #pragma unroll
        for (int kk = 0; kk < 16; ++kk){
            float a[4], xv[4];
            #pragma unroll
            for (int i = 0; i < 4; ++i) a[i]  = As[kk][ty*4+i];
            #pragma unroll
            for (int j = 0; j < 4; ++j) xv[j] = Xs[kk][tx*4+j];
            #pragma unroll
            for (int i = 0; i < 4; ++i)
                #pragma unroll
                for (int j = 0; j < 4; ++j) acc[i][j] += a[i]*xv[j];
        }
        __syncthreads();
    }
    #pragma unroll
    for (int i = 0; i < 4; ++i){
        int n = n0 + ty*4 + i;
        #pragma unroll
        for (int j = 0; j < 4; ++j){
            int c = j0 + tx*4 + j;
            T2[n*Nn + c] = 2.f*acc[i][j] - (n == c ? 1.f : 0.f);
        }
    }
}

// ---------------------------------------------------------------------------
// GCN GEMM: out_k[n][j] = sum_m A_k[n][m] * cat[m][j],  j = b*C + c
// cat lives in xg k0 slice (offset b*LDXG + c), output to k1/k2 slices.
// grid: (C, 16, 2)
// ---------------------------------------------------------------------------
__global__ __launch_bounds__(256) void gcn_gemm(const float* __restrict__ S,
                                                const float* __restrict__ T2,
                                                float* __restrict__ xg, int C)
{
    const float* A = blockIdx.z ? T2 : S;
    int kOff = ((int)blockIdx.z + 1) * C;
    int n0 = blockIdx.y*64;
    int j0 = blockIdx.x*64;
    __shared__ float As[16][65];
    __shared__ float Xs[16][65];
    __shared__ int colOff[64];
    int tid = threadIdx.x;
    if (tid < 64){
        int j = j0 + tid;
        colOff[tid] = (j / C) * LDXG + (j % C);
    }
    __syncthreads();
    int tx = tid & 15, ty = tid >> 4;
    float acc[4][4] = {};
    for (int k0 = 0; k0 < Nn; k0 += 16){
        #pragma unroll
        for (int r = 0; r < 4; ++r){
            int idx = tid + r*256;
            int ar = idx >> 4, ak = idx & 15;
            As[ak][ar] = A[(n0+ar)*Nn + k0+ak];
        }
        #pragma unroll
        for (int r = 0; r < 4; ++r){
            int idx = tid + r*256;
            int xm = idx >> 6, xj = idx & 63;
            Xs[xm][xj] = xg[(size_t)(k0+xm)*LDX + colOff[xj]];
        }
        __syncthreads();
        #pragma unroll
        for (int kk = 0; kk < 16; ++kk){
            float a[4], xv[4];
            #pragma unroll
            for (int i = 0; i < 4; ++i) a[i]  = As[kk][ty*4+i];
            #pragma unroll
            for (int j = 0; j < 4; ++j) xv[j] = Xs[kk][tx*4+j];
            #pragma unroll
            for (int i = 0; i < 4; ++i)
                #pragma unroll
                for (int j = 0; j < 4; ++j) acc[i][j] += a[i]*xv[j];
        }
        __syncthreads();
    }
    #pragma unroll
    for (int i = 0; i < 4; ++i){
        int n = n0 + ty*4 + i;
        #pragma unroll
        for (int j = 0; j < 4; ++j){
            xg[(size_t)n*LDX + colOff[tx*4+j] + kOff] = acc[i][j];
        }
    }
}

// ---------------------------------------------------------------------------
// gate GEMM: zr = sigmoid(XG(65536 x Kdim, ld LDXG) @ W(Kdim x Nout) + b)
// grid: (Nout/64, 1024)
// ---------------------------------------------------------------------------
__global__ __launch_bounds__(256) void gate_gemm(const float* __restrict__ XG,
                                                 const float* __restrict__ W,
                                                 const float* __restrict__ bias,
                                                 float* __restrict__ zr,
                                                 int Kdim, int Nout)
{
    int r0 = blockIdx.y*64;
    int j0 = blockIdx.x*64;
    __shared__ float As[16][65];
    __shared__ float Bs[16][65];
    int tid = threadIdx.x; int tx = tid & 15, ty = tid >> 4;
    float acc[4][4] = {};
    for (int k0 = 0; k0 < Kdim; k0 += 16){
        #pragma unroll
        for (int r = 0; r < 4; ++r){
            int idx = tid + r*256;
            int ar = idx >> 4, ak = idx & 15;
            As[ak][ar] = (k0+ak < Kdim) ? XG[(size_t)(r0+ar)*LDXG + k0+ak] : 0.f;
        }
        #pragma unroll
        for (int r = 0; r < 4; ++r){
            int idx = tid + r*256;
            int bk = idx >> 6, bj = idx & 63;
            Bs[bk][bj] = (k0+bk < Kdim) ? W[(size_t)(k0+bk)*Nout + j0+bj] : 0.f;
        }
        __syncthreads();
        #pragma unroll
        for (int kk = 0; kk < 16; ++kk){
            float a[4], bv[4];
            #pragma unroll
            for (int i = 0; i < 4; ++i) a[i]  = As[kk][ty*4+i];
            #pragma unroll
            for (int j = 0; j < 4; ++j) bv[j] = Bs[kk][tx*4+j];
            #pragma unroll
            for (int i = 0; i < 4; ++i)
                #pragma unroll
                for (int j = 0; j < 4; ++j) acc[i][j] += a[i]*bv[j];
        }
        __syncthreads();
    }
    #pragma unroll
    for (int i = 0; i < 4; ++i){
        int rb = r0 + ty*4 + i;
        #pragma unroll
        for (int j = 0; j < 4; ++j){
            int oc = j0 + tx*4 + j;
            float v = acc[i][j] + bias[oc];
            zr[(size_t)rb*LDZR + oc] = 1.f/(1.f + expf(-v));
        }
    }
}

// ---------------------------------------------------------------------------
// update GEMM: hc = tanh(XG2 @ Wu + bu); h = r*h_old + (1-r)*hc
// grid: (Hd/64, 1024)
// ---------------------------------------------------------------------------
__global__ __launch_bounds__(256) void update_gemm(const float* __restrict__ XG,
                                                   const float* __restrict__ W,
                                                   const float* __restrict__ bias,
                                                   const float* __restrict__ zr,
                                                   float* __restrict__ h,
                                                   int Kdim, int Hd)
{
    int r0 = blockIdx.y*64;
    int j0 = blockIdx.x*64;
    __shared__ float As[16][65];
    __shared__ float Bs[16][65];
    int tid = threadIdx.x; int tx = tid & 15, ty = tid >> 4;
    float acc[4][4] = {};
    for (int k0 = 0; k0 < Kdim; k0 += 16){
        #pragma unroll
        for (int r = 0; r < 4; ++r){
            int idx = tid + r*256;
            int ar = idx >> 4, ak = idx & 15;
            As[ak][ar] = (k0+ak < Kdim) ? XG[(size_t)(r0+ar)*LDXG + k0+ak] : 0.f;
        }
        #pragma unroll
        for (int r = 0; r < 4; ++r){
            int idx = tid + r*256;
            int bk = idx >> 6, bj = idx & 63;
            Bs[bk][bj] = (k0+bk < Kdim) ? W[(size_t)(k0+bk)*Hd + j0+bj] : 0.f;
        }
        __syncthreads();
        #pragma unroll
        for (int kk = 0; kk < 16; ++kk){
            float a[4], bv[4];
            #pragma unroll
            for (int i = 0; i < 4; ++i) a[i]  = As[kk][ty*4+i];
            #pragma unroll
            for (int j = 0; j < 4; ++j) bv[j] = Bs[kk][tx*4+j];
            #pragma unroll
            for (int i = 0; i < 4; ++i)
                #pragma unroll
                for (int j = 0; j < 4; ++j) acc[i][j] += a[i]*bv[j];
        }
        __syncthreads();
    }
    #pragma unroll
    for (int i = 0; i < 4; ++i){
        int rb = r0 + ty*4 + i;
        #pragma unroll
        for (int j = 0; j < 4; ++j){
            int oc = j0 + tx*4 + j;
            float hc = tanhf(acc[i][j] + bias[oc]);
            float rr = zr[(size_t)rb*LDZR + Hd + oc];
            float ho = h[(size_t)rb*Hd + oc];
            h[(size_t)rb*Hd + oc] = rr*ho + (1.f-rr)*hc;
        }
    }
}

// ---------------------------------------------------------------------------
// cat builders (write the k0 slice of xg)
// ---------------------------------------------------------------------------
__global__ void build_cat1_enc(const float* __restrict__ x, const float* __restrict__ h,
                               float* __restrict__ xg, int t)
{
    size_t idx = (size_t)blockIdx.x*256 + threadIdx.x;      // N*B*129
    int c = (int)(idx % 129); int rb = (int)(idx / 129);
    int n = rb / Bb, b = rb % Bb;
    float v = (c == 0) ? x[((size_t)b*Tt + t)*Nn + n] : h[(size_t)rb*Hh + (c-1)];
    xg[(size_t)rb*LDXG + c] = v;
}

__global__ void build_cat2_enc(const float* __restrict__ x, const float* __restrict__ h,
                               const float* __restrict__ zr, float* __restrict__ xg, int t)
{
    size_t idx = (size_t)blockIdx.x*256 + threadIdx.x;
    int c = (int)(idx % 129); int rb = (int)(idx / 129);
    int n = rb / Bb, b = rb % Bb;
    float v;
    if (c == 0) v = x[((size_t)b*Tt + t)*Nn + n];
    else        v = zr[(size_t)rb*LDZR + (c-1)] * h[(size_t)rb*Hh + (c-1)];
    xg[(size_t)rb*LDXG + c] = v;
}

__global__ void build_cat1_dec(const float* __restrict__ go, const float* __restrict__ yc,
                               const float* __restrict__ h, float* __restrict__ xg, int t)
{
    size_t idx = (size_t)blockIdx.x*256 + threadIdx.x;      // N*B*194
    int c = (int)(idx % 194); int rb = (int)(idx / 194);
    int n = rb / Bb, b = rb % Bb;
    float v;
    if (c == 0)      v = go[rb];
    else if (c == 1) v = yc[((size_t)b*HORt + t)*Nn + n];
    else             v = h[(size_t)rb*DECHd + (c-2)];
    xg[(size_t)rb*LDXG + c] = v;
}

__global__ void build_cat2_dec(const float* __restrict__ go, const float* __restrict__ yc,
                               const float* __restrict__ h, const float* __restrict__ zr,
                               float* __restrict__ xg, int t)
{
    size_t idx = (size_t)blockIdx.x*256 + threadIdx.x;
    int c = (int)(idx % 194); int rb = (int)(idx / 194);
    int n = rb / Bb, b = rb % Bb;
    float v;
    if (c == 0)      v = go[rb];
    else if (c == 1) v = yc[((size_t)b*HORt + t)*Nn + n];
    else             v = zr[(size_t)rb*LDZR + (c-2)] * h[(size_t)rb*DECHd + (c-2)];
    xg[(size_t)rb*LDXG + c] = v;
}

// ---------------------------------------------------------------------------
// attention: query/att/value/pos + h_dec init + argmax index
// one 64-thread block per (n,b)
// ---------------------------------------------------------------------------
__global__ __launch_bounds__(64) void attn_kernel(const float* __restrict__ hT,
                                                  const float* __restrict__ Wq,
                                                  const float* __restrict__ Mem,
                                                  float* __restrict__ hdec,
                                                  int* __restrict__ ind0,
                                                  float* __restrict__ outv,
                                                  float* __restrict__ outq,
                                                  float* __restrict__ outp)
{
    int rb = blockIdx.x; int n = rb / Bb, b = rb % Bb;
    int tid = threadIdx.x;
    __shared__ float hl[Hh];
    __shared__ float ql[MDd];
    __shared__ float sm[Mm];
    __shared__ float stats[2];
    __shared__ int   smind;
    hl[tid]      = hT[(size_t)rb*Hh + tid];
    hl[tid + 64] = hT[(size_t)rb*Hh + tid + 64];
    __syncthreads();
    float q = 0.f;
    for (int hh = 0; hh < Hh; ++hh) q += hl[hh]*Wq[hh*MDd + tid];
    ql[tid] = q;
    size_t bn = (size_t)b*Nn + n;
    outq[bn*MDd + tid] = q;
    __syncthreads();
    if (tid < Mm){
        float s = 0.f;
        for (int d = 0; d < MDd; ++d) s += ql[d]*Mem[tid*MDd + d];
        sm[tid] = s;
    }
    __syncthreads();
    if (tid == 0){
        float mx = -1e30f; int am = 0;
        for (int m = 0; m < Mm; ++m) if (sm[m] > mx){ mx = sm[m]; am = m; }
        float ssum = 0.f;
        for (int m = 0; m < Mm; ++m){ float e = expf(sm[m]-mx); sm[m] = e; ssum += e; }
        stats[0] = 1.f/ssum; smind = am;
    }
    __syncthreads();
    float inv = stats[0]; int am = smind;
    float val = 0.f;
    for (int m = 0; m < Mm; ++m) val += sm[m]*inv*Mem[m*MDd + tid];
    outv[bn*MDd + tid] = val;
    outp[bn*MDd + tid] = Mem[am*MDd + tid];
    hdec[(size_t)rb*DECHd + tid]       = hl[tid];
    hdec[(size_t)rb*DECHd + 64 + tid]  = hl[tid + 64];
    hdec[(size_t)rb*DECHd + 128 + tid] = val;
    if (tid == 0) ind0[rb] = am;
}

__global__ void neg_kernel(const float* __restrict__ Mem, float* __restrict__ outn)
{
    size_t idx = (size_t)blockIdx.x*256 + threadIdx.x;      // B*N*M*MD
    outn[idx] = Mem[idx % (Mm*MDd)];
}

__global__ void mask_kernel(const int* __restrict__ ind0, float* __restrict__ outm)
{
    size_t idx = (size_t)blockIdx.x*256 + threadIdx.x;      // B*N*M
    int m   = (int)(idx % Mm);
    size_t bn = idx / Mm;
    int n = (int)(bn % Nn);
    int b = (int)(bn / Nn);
    int rb = n*Bb + b;
    outm[idx] = (m != ind0[rb]) ? 1.f : 0.f;
}

// ---------------------------------------------------------------------------
// projection: go2 = h @ proj_W + proj_b ; one wave per row (4 rows/block)
// ---------------------------------------------------------------------------
__global__ __launch_bounds__(256) void proj_kernel(const float* __restrict__ h,
                                                   const float* __restrict__ pw,
                                                   const float* __restrict__ pb,
                                                   float* __restrict__ go,
                                                   float* __restrict__ out0, int t)
{
    int rb = blockIdx.x*4 + (threadIdx.x >> 6);
    int lane = threadIdx.x & 63;
    float s = 0.f;
    #pragma unroll
    for (int r = 0; r < 3; ++r){
        int i = lane + r*64;
        s += h[(size_t)rb*DECHd + i]*pw[i];
    }
    #pragma unroll
    for (int off = 32; off > 0; off >>= 1) s += __shfl_down(s, off, 64);
    if (lane == 0){
        float v = s + pb[0];
        go[rb] = v;
        int n = rb / Bb, b = rb % Bb;
        out0[((size_t)b*HORt + t)*Nn + n] = v;
    }
}

// ---------------------------------------------------------------------------
extern "C" void kernel_launch(void* const* d_in, const int* in_sizes, int n_in,
                              void* d_out, int out_size, void* d_ws, size_t ws_size,
                              hipStream_t stream)
{
    const float* x    = (const float*)d_in[0];
    const float* ycov = (const float*)d_in[1];
    const float* emb  = (const float*)d_in[2];
    const float* Mem  = (const float*)d_in[3];
    const float* Wq   = (const float*)d_in[4];
    const float* eWg  = (const float*)d_in[5];
    const float* ebg  = (const float*)d_in[6];
    const float* eWu  = (const float*)d_in[7];
    const float* ebu  = (const float*)d_in[8];
    const float* dWg  = (const float*)d_in[9];
    const float* dbg  = (const float*)d_in[10];
    const float* dWu  = (const float*)d_in[11];
    const float* dbu  = (const float*)d_in[12];
    const float* pW   = (const float*)d_in[13];
    const float* pb   = (const float*)d_in[14];

    float* out        = (float*)d_out;
    float* out_output = out;                     // (B,HOR,N,1)     786432
    float* out_value  = out + 786432;            // (B,N,64)       4194304
    float* out_query  = out + 4980736;           // (B,N,64)       4194304
    float* out_pos    = out + 9175040;           // (B,N,64)       4194304
    float* out_neg    = out + 13369344;          // (B,N,20,64)   83886080
    float* out_mask   = out + 97255424;          // (B,N,20)       1310720

    // ---- scratch: xg/zr live in the out_neg region (written only at the end)
    float* xg = out_neg;                         // 38,141,952 floats
    float* zr = out_neg + 38141952;              // 25,165,824 floats  (end 63,307,776 < 85,196,800)

    // ---- d_ws: 23,265,280 floats = 93.1 MB (ws_size >= 173 MB confirmed r3)
    const size_t NEED = 23265280ull*4ull;
    if (ws_size < NEED){
        ws_probe_kernel<<<3072, 256, 0, stream>>>(out_output, (float)(ws_size >> 20));
        return;
    }
    float* S    = (float*)d_ws;                  // 1,048,576
    float* T2   = S    + 1048576;                // 1,048,576
    float* henc = T2   + 1048576;                // 8,388,608
    float* hdec = henc + 8388608;                // 12,582,912
    float* go   = hdec + 12582912;               // 65,536
    int*   ind0 = (int*)(go + 65536);            // 65,536 ints

    hipMemsetAsync(henc, 0, (size_t)8388608*4, stream);
    hipMemsetAsync(go,   0, (size_t)65536*4,   stream);

    supports_kernel<<<Nn, 256, 0, stream>>>(emb, S);
    t2_gemm<<<dim3(16,16), 256, 0, stream>>>(S, T2);

    // -------- encoder: 12 steps, C=129 --------
    for (int t = 0; t < Tt; ++t){
        build_cat1_enc<<<33024, 256, 0, stream>>>(x, henc, xg, t);
        gcn_gemm<<<dim3(129,16,2), 256, 0, stream>>>(S, T2, xg, 129);
        gate_gemm<<<dim3(4,1024), 256, 0, stream>>>(xg, eWg, ebg, zr, 387, 256);
        build_cat2_enc<<<33024, 256, 0, stream>>>(x, henc, zr, xg, t);
        gcn_gemm<<<dim3(129,16,2), 256, 0, stream>>>(S, T2, xg, 129);
        update_gemm<<<dim3(2,1024), 256, 0, stream>>>(xg, eWu, ebu, zr, henc, 387, 128);
    }

    // -------- attention (value/query/pos + hdec init + ind0) --------
    attn_kernel<<<65536, 64, 0, stream>>>(henc, Wq, Mem, hdec, ind0,
                                          out_value, out_query, out_pos);

    // -------- decoder: 12 steps, C=194 --------
    for (int t = 0; t < HORt; ++t){
        build_cat1_dec<<<49664, 256, 0, stream>>>(go, ycov, hdec, xg, t);
        gcn_gemm<<<dim3(194,16,2), 256, 0, stream>>>(S, T2, xg, 194);
        gate_gemm<<<dim3(6,1024), 256, 0, stream>>>(xg, dWg, dbg, zr, 582, 384);
        build_cat2_dec<<<49664, 256, 0, stream>>>(go, ycov, hdec, zr, xg, t);
        gcn_gemm<<<dim3(194,16,2), 256, 0, stream>>>(S, T2, xg, 194);
        update_gemm<<<dim3(3,1024), 256, 0, stream>>>(xg, dWu, dbu, zr, hdec, 582, 192);
        proj_kernel<<<16384, 256, 0, stream>>>(hdec, pW, pb, go, out_output, t);
    }

    // -------- aux outputs LAST (out_neg region doubled as scratch above) ----
    neg_kernel<<<327680, 256, 0, stream>>>(Mem, out_neg);
    mask_kernel<<<5120, 256, 0, stream>>>(ind0, out_mask);
}

// Round 7
// 31925.189 us; speedup vs baseline: 2.0653x; 2.0653x over previous
//
#include <hip/hip_runtime.h>
#include <hip/hip_bf16.h>

typedef __hip_bfloat16 bf16;
typedef __attribute__((ext_vector_type(8))) short short8;
typedef __attribute__((ext_vector_type(4))) float f32x4;
typedef __attribute__((ext_vector_type(4))) int   int4v;

#define Bb   64
#define Tt   12
#define Nn   1024
#define HORt 12
#define Hh   128
#define Ee   16
#define Mm   20
#define MDd  64
#define DECHd 192
#define LDXG 582               // fp32 encoder xg row length (round-4 layout)
#define LDX  (Bb*LDXG)
#define LDZR 384
#define CPd  224               // padded dec cat width (194 -> 224)
#define JPd  (Bb*CPd)          // 14336

__device__ __forceinline__ float b2f(bf16 v){ return __bfloat162float(v); }
__device__ __forceinline__ bf16  f2b(float v){ return __float2bfloat16(v); }

// ---------------------------------------------------------------------------
__global__ void ws_probe_kernel(float* __restrict__ out, float val)
{
    size_t i = (size_t)blockIdx.x*256 + threadIdx.x;
    out[i] = val;
}

__global__ void conv_f2b(const float* __restrict__ src, bf16* __restrict__ dst)
{
    size_t i = (size_t)blockIdx.x*256 + threadIdx.x;
    dst[i] = f2b(src[i]);
}

// ---------------------------------------------------------------------------
// supports = softmax(relu(emb @ emb^T), axis=1)  (fp32, round-4 verified)
// ---------------------------------------------------------------------------
__global__ __launch_bounds__(256) void supports_kernel(const float* __restrict__ emb,
                                                       float* __restrict__ S)
{
    int n = blockIdx.x;
    __shared__ float row[Nn];
    __shared__ float en[Ee];
    __shared__ float red[256];
    int tid = threadIdx.x;
    if (tid < Ee) en[tid] = emb[n*Ee + tid];
    __syncthreads();
    float lmax = -1e30f;
    for (int j = tid; j < Nn; j += 256){
        float d = 0.f;
        #pragma unroll
        for (int e = 0; e < Ee; ++e) d += en[e]*emb[j*Ee + e];
        d = d > 0.f ? d : 0.f;
        row[j] = d;
        lmax = fmaxf(lmax, d);
    }
    red[tid] = lmax; __syncthreads();
    for (int s = 128; s > 0; s >>= 1){ if (tid < s) red[tid] = fmaxf(red[tid], red[tid+s]); __syncthreads(); }
    float mx = red[0]; __syncthreads();
    float lsum = 0.f;
    for (int j = tid; j < Nn; j += 256){ float e = expf(row[j]-mx); row[j] = e; lsum += e; }
    red[tid] = lsum; __syncthreads();
    for (int s = 128; s > 0; s >>= 1){ if (tid < s) red[tid] += red[tid+s]; __syncthreads(); }
    float inv = 1.f/red[0];
    for (int j = tid; j < Nn; j += 256) S[n*Nn + j] = row[j]*inv;
}

// ---------------------------------------------------------------------------
// T2 = 2*S@S - I   (fp32, round-4 verified)
// ---------------------------------------------------------------------------
__global__ __launch_bounds__(256) void t2_gemm(const float* __restrict__ S,
                                               float* __restrict__ T2)
{
    int n0 = blockIdx.y*64, j0 = blockIdx.x*64;
    __shared__ float As[16][65];
    __shared__ float Xs[16][65];
    int tid = threadIdx.x; int tx = tid & 15, ty = tid >> 4;
    float acc[4][4] = {};
    for (int k0 = 0; k0 < Nn; k0 += 16){
        #pragma unroll
        for (int r = 0; r < 4; ++r){
            int idx = tid + r*256;
            int ar = idx >> 4, ak = idx & 15;
            As[ak][ar] = S[(n0+ar)*Nn + k0+ak];
        }
        #pragma unroll
        for (int r = 0; r < 4; ++r){
            int idx = tid + r*256;
            int xm = idx >> 6, xj = idx & 63;
            Xs[xm][xj] = S[(k0+xm)*Nn + j0+xj];
        }
        __syncthreads();
        #pragma unroll
        for (int kk = 0; kk < 16; ++kk){
            float a[4], xv[4];
            #pragma unroll
            for (int i = 0; i < 4; ++i) a[i]  = As[kk][ty*4+i];
            #pragma unroll
            for (int j = 0; j < 4; ++j) xv[j] = Xs[kk][tx*4+j];
            #pragma unroll
            for (int i = 0; i < 4; ++i)
                #pragma unroll
                for (int j = 0; j < 4; ++j) acc[i][j] += a[i]*xv[j];
        }
        __syncthreads();
    }
    #pragma unroll
    for (int i = 0; i < 4; ++i){
        int n = n0 + ty*4 + i;
        #pragma unroll
        for (int j = 0; j < 4; ++j){
            int c = j0 + tx*4 + j;
            T2[n*Nn + c] = 2.f*acc[i][j] - (n == c ? 1.f : 0.f);
        }
    }
}

// ---------------------------------------------------------------------------
// fp32 encoder GEMMs (round-4 verified, byte-identical)
// ---------------------------------------------------------------------------
__global__ __launch_bounds__(256) void gcn_gemm(const float* __restrict__ S,
                                                const float* __restrict__ T2,
                                                float* __restrict__ xg, int C)
{
    const float* A = blockIdx.z ? T2 : S;
    int kOff = ((int)blockIdx.z + 1) * C;
    int n0 = blockIdx.y*64;
    int j0 = blockIdx.x*64;
    __shared__ float As[16][65];
    __shared__ float Xs[16][65];
    __shared__ int colOff[64];
    int tid = threadIdx.x;
    if (tid < 64){
        int j = j0 + tid;
        colOff[tid] = (j / C) * LDXG + (j % C);
    }
    __syncthreads();
    int tx = tid & 15, ty = tid >> 4;
    float acc[4][4] = {};
    for (int k0 = 0; k0 < Nn; k0 += 16){
        #pragma unroll
        for (int r = 0; r < 4; ++r){
            int idx = tid + r*256;
            int ar = idx >> 4, ak = idx & 15;
            As[ak][ar] = A[(n0+ar)*Nn + k0+ak];
        }
        #pragma unroll
        for (int r = 0; r < 4; ++r){
            int idx = tid + r*256;
            int xm = idx >> 6, xj = idx & 63;
            Xs[xm][xj] = xg[(size_t)(k0+xm)*LDX + colOff[xj]];
        }
        __syncthreads();
        #pragma unroll
        for (int kk = 0; kk < 16; ++kk){
            float a[4], xv[4];
            #pragma unroll
            for (int i = 0; i < 4; ++i) a[i]  = As[kk][ty*4+i];
            #pragma unroll
            for (int j = 0; j < 4; ++j) xv[j] = Xs[kk][tx*4+j];
            #pragma unroll
            for (int i = 0; i < 4; ++i)
                #pragma unroll
                for (int j = 0; j < 4; ++j) acc[i][j] += a[i]*xv[j];
        }
        __syncthreads();
    }
    #pragma unroll
    for (int i = 0; i < 4; ++i){
        int n = n0 + ty*4 + i;
        #pragma unroll
        for (int j = 0; j < 4; ++j){
            xg[(size_t)n*LDX + colOff[tx*4+j] + kOff] = acc[i][j];
        }
    }
}

__global__ __launch_bounds__(256) void gate_gemm(const float* __restrict__ XG,
                                                 const float* __restrict__ W,
                                                 const float* __restrict__ bias,
                                                 float* __restrict__ zr,
                                                 int Kdim, int Nout)
{
    int r0 = blockIdx.y*64;
    int j0 = blockIdx.x*64;
    __shared__ float As[16][65];
    __shared__ float Bs[16][65];
    int tid = threadIdx.x; int tx = tid & 15, ty = tid >> 4;
    float acc[4][4] = {};
    for (int k0 = 0; k0 < Kdim; k0 += 16){
        #pragma unroll
        for (int r = 0; r < 4; ++r){
            int idx = tid + r*256;
            int ar = idx >> 4, ak = idx & 15;
            As[ak][ar] = (k0+ak < Kdim) ? XG[(size_t)(r0+ar)*LDXG + k0+ak] : 0.f;
        }
        #pragma unroll
        for (int r = 0; r < 4; ++r){
            int idx = tid + r*256;
            int bk = idx >> 6, bj = idx & 63;
            Bs[bk][bj] = (k0+bk < Kdim) ? W[(size_t)(k0+bk)*Nout + j0+bj] : 0.f;
        }
        __syncthreads();
        #pragma unroll
        for (int kk = 0; kk < 16; ++kk){
            float a[4], bv[4];
            #pragma unroll
            for (int i = 0; i < 4; ++i) a[i]  = As[kk][ty*4+i];
            #pragma unroll
            for (int j = 0; j < 4; ++j) bv[j] = Bs[kk][tx*4+j];
            #pragma unroll
            for (int i = 0; i < 4; ++i)
                #pragma unroll
                for (int j = 0; j < 4; ++j) acc[i][j] += a[i]*bv[j];
        }
        __syncthreads();
    }
    #pragma unroll
    for (int i = 0; i < 4; ++i){
        int rb = r0 + ty*4 + i;
        #pragma unroll
        for (int j = 0; j < 4; ++j){
            int oc = j0 + tx*4 + j;
            float v = acc[i][j] + bias[oc];
            zr[(size_t)rb*LDZR + oc] = 1.f/(1.f + expf(-v));
        }
    }
}

__global__ __launch_bounds__(256) void update_gemm(const float* __restrict__ XG,
                                                   const float* __restrict__ W,
                                                   const float* __restrict__ bias,
                                                   const float* __restrict__ zr,
                                                   float* __restrict__ h,
                                                   int Kdim, int Hd)
{
    int r0 = blockIdx.y*64;
    int j0 = blockIdx.x*64;
    __shared__ float As[16][65];
    __shared__ float Bs[16][65];
    int tid = threadIdx.x; int tx = tid & 15, ty = tid >> 4;
    float acc[4][4] = {};
    for (int k0 = 0; k0 < Kdim; k0 += 16){
        #pragma unroll
        for (int r = 0; r < 4; ++r){
            int idx = tid + r*256;
            int ar = idx >> 4, ak = idx & 15;
            As[ak][ar] = (k0+ak < Kdim) ? XG[(size_t)(r0+ar)*LDXG + k0+ak] : 0.f;
        }
        #pragma unroll
        for (int r = 0; r < 4; ++r){
            int idx = tid + r*256;
            int bk = idx >> 6, bj = idx & 63;
            Bs[bk][bj] = (k0+bk < Kdim) ? W[(size_t)(k0+bk)*Hd + j0+bj] : 0.f;
        }
        __syncthreads();
        #pragma unroll
        for (int kk = 0; kk < 16; ++kk){
            float a[4], bv[4];
            #pragma unroll
            for (int i = 0; i < 4; ++i) a[i]  = As[kk][ty*4+i];
            #pragma unroll
            for (int j = 0; j < 4; ++j) bv[j] = Bs[kk][tx*4+j];
            #pragma unroll
            for (int i = 0; i < 4; ++i)
                #pragma unroll
                for (int j = 0; j < 4; ++j) acc[i][j] += a[i]*bv[j];
        }
        __syncthreads();
    }
    #pragma unroll
    for (int i = 0; i < 4; ++i){
        int rb = r0 + ty*4 + i;
        #pragma unroll
        for (int j = 0; j < 4; ++j){
            int oc = j0 + tx*4 + j;
            float hc = tanhf(acc[i][j] + bias[oc]);
            float rr = zr[(size_t)rb*LDZR + Hd + oc];
            float ho = h[(size_t)rb*Hd + oc];
            h[(size_t)rb*Hd + oc] = rr*ho + (1.f-rr)*hc;
        }
    }
}

__global__ void build_cat1_enc(const float* __restrict__ x, const float* __restrict__ h,
                               float* __restrict__ xg, int t)
{
    size_t idx = (size_t)blockIdx.x*256 + threadIdx.x;      // N*B*129
    int c = (int)(idx % 129); int rb = (int)(idx / 129);
    int n = rb / Bb, b = rb % Bb;
    float v = (c == 0) ? x[((size_t)b*Tt + t)*Nn + n] : h[(size_t)rb*Hh + (c-1)];
    xg[(size_t)rb*LDXG + c] = v;
}

__global__ void build_cat2_enc(const float* __restrict__ x, const float* __restrict__ h,
                               const float* __restrict__ zr, float* __restrict__ xg, int t)
{
    size_t idx = (size_t)blockIdx.x*256 + threadIdx.x;
    int c = (int)(idx % 129); int rb = (int)(idx / 129);
    int n = rb / Bb, b = rb % Bb;
    float v;
    if (c == 0) v = x[((size_t)b*Tt + t)*Nn + n];
    else        v = zr[(size_t)rb*LDZR + (c-1)] * h[(size_t)rb*Hh + (c-1)];
    xg[(size_t)rb*LDXG + c] = v;
}

// ---------------------------------------------------------------------------
// weight convert+pad: W fp32 (3*C x No) -> bf16 [3][CP][NoP], zero pads
// (both pad rows c>=C and pad cols o>=No are zero so staging reads stay
//  in-bounds and padded MFMA columns contribute nothing)
// ---------------------------------------------------------------------------
__global__ void conv_w(const float* __restrict__ W, bf16* __restrict__ dst,
                       int C, int CP, int No, int NoP)
{
    int idx = blockIdx.x*256 + threadIdx.x;
    int tot = 3*CP*NoP;
    if (idx >= tot) return;
    int km = idx / (CP*NoP);
    int r  = idx % (CP*NoP);
    int c  = r / NoP, o = r % NoP;
    dst[idx] = (c < C && o < No) ? f2b(W[(size_t)(km*C + c)*No + o]) : f2b(0.f);
}

// ---------------------------------------------------------------------------
// bf16 MFMA GEMM (round-6 first-call-verified): out = sum_km A_km @ B_km
// 128x128 tile, BK=32, 4 waves, 4x4 16x16x32 frags; XOR chunk swizzle.
// EPI 0: bf16 store  EPI 1: sigmoid->bf16  EPI 2: GRU update (fp32 h)
// ---------------------------------------------------------------------------
template<int EPI>
__global__ __launch_bounds__(256) void mfma_gemm(
    const ushort* __restrict__ A0, const ushort* __restrict__ A1, const ushort* __restrict__ A2,
    const ushort* __restrict__ B0, const ushort* __restrict__ B1, const ushort* __restrict__ B2,
    int nmat, int Ksz, int lda, int ldb,
    bf16* __restrict__ Cout, int ldc, int Ncols,
    const float* __restrict__ bias,
    const bf16* __restrict__ zr, float* __restrict__ hbuf, int Hd)
{
    __shared__ short As[128*32];
    __shared__ short Bs[128*32];
    int tid = threadIdx.x;
    int m0 = blockIdx.y * 128;
    int n0 = blockIdx.x * 128;
    int wave = tid >> 6, lane = tid & 63;
    int wr = wave >> 1, wc = wave & 1;
    int lr = lane & 15, lk8 = lane >> 4;

    f32x4 acc[4][4];
    #pragma unroll
    for (int i = 0; i < 4; ++i)
        #pragma unroll
        for (int j = 0; j < 4; ++j) acc[i][j] = (f32x4){0.f,0.f,0.f,0.f};

    const ushort* Aps[3] = {A0, A1, A2};
    const ushort* Bps[3] = {B0, B1, B2};

    int bkp = tid & 15;
    int bcc = tid >> 4;

    for (int km = 0; km < nmat; ++km){
        const ushort* Ag = Aps[km];
        const ushort* Bg = Bps[km];
        for (int k0 = 0; k0 < Ksz; k0 += 32){
            #pragma unroll
            for (int r = 0; r < 2; ++r){
                int i = tid + r*256;
                int row = i >> 2, cc = i & 3;
                const ushort* src = Ag + (size_t)(m0+row)*lda + k0 + cc*8;
                int4v v = *(const int4v*)src;
                int dst = row*64 + ((cc ^ (row & 3)) << 4);
                *(int4v*)((char*)As + dst) = v;
            }
            {
                int kk = k0 + bkp*2;
                const ushort* s1 = Bg + (size_t)kk*ldb + n0 + bcc*8;
                const ushort* s2 = s1 + ldb;
                int4v v1 = *(const int4v*)s1;
                int4v v2 = *(const int4v*)s2;
                const ushort* g1 = (const ushort*)&v1;
                const ushort* g2 = (const ushort*)&v2;
                #pragma unroll
                for (int e = 0; e < 8; ++e){
                    int col = bcc*8 + e;
                    unsigned pv = (unsigned)g1[e] | ((unsigned)g2[e] << 16);
                    int kc = (bkp >> 2) ^ (col & 3);
                    int dst = col*64 + kc*16 + (bkp & 3)*4;
                    *(unsigned*)((char*)Bs + dst) = pv;
                }
            }
            __syncthreads();
            short8 af[4], bfv[4];
            #pragma unroll
            for (int mi = 0; mi < 4; ++mi){
                int row = wr*64 + mi*16 + lr;
                int off = row*64 + ((lk8 ^ (row & 3)) << 4);
                af[mi] = *(const short8*)((const char*)As + off);
            }
            #pragma unroll
            for (int ni = 0; ni < 4; ++ni){
                int col = wc*64 + ni*16 + lr;
                int off = col*64 + ((lk8 ^ (col & 3)) << 4);
                bfv[ni] = *(const short8*)((const char*)Bs + off);
            }
            #pragma unroll
            for (int mi = 0; mi < 4; ++mi)
                #pragma unroll
                for (int ni = 0; ni < 4; ++ni)
                    acc[mi][ni] = __builtin_amdgcn_mfma_f32_16x16x32_bf16(
                                      af[mi], bfv[ni], acc[mi][ni], 0, 0, 0);
            __syncthreads();
        }
    }

    int rbase = lk8 * 4;
    #pragma unroll
    for (int mi = 0; mi < 4; ++mi){
        #pragma unroll
        for (int ni = 0; ni < 4; ++ni){
            int gn = n0 + wc*64 + ni*16 + lr;
            if (gn >= Ncols) continue;
            #pragma unroll
            for (int rg = 0; rg < 4; ++rg){
                int gm = m0 + wr*64 + mi*16 + rbase + rg;
                float v = acc[mi][ni][rg];
                if (EPI == 0){
                    Cout[(size_t)gm*ldc + gn] = f2b(v);
                } else if (EPI == 1){
                    v += bias[gn];
                    Cout[(size_t)gm*ldc + gn] = f2b(1.f/(1.f + expf(-v)));
                } else {
                    float hc = tanhf(v + bias[gn]);
                    float rr = b2f(zr[(size_t)gm*LDZR + Hd + gn]);
                    float ho = hbuf[(size_t)gm*Hd + gn];
                    hbuf[(size_t)gm*Hd + gn] = rr*ho + (1.f-rr)*hc;
                }
            }
        }
    }
}

// ---------------------------------------------------------------------------
// decoder cat builders (bf16)
// ---------------------------------------------------------------------------
__global__ void build_dec1(const float* __restrict__ go, const float* __restrict__ yc,
                           const float* __restrict__ h, bf16* __restrict__ cat0, int t)
{
    size_t idx = (size_t)blockIdx.x*256 + threadIdx.x;      // N*B*CPd
    int c = (int)(idx % CPd); size_t rb = idx / CPd;
    int n = (int)(rb >> 6), b = (int)(rb & 63);
    float v;
    if (c == 0)        v = go[rb];
    else if (c == 1)   v = yc[((size_t)b*HORt + t)*Nn + n];
    else if (c < 194)  v = h[rb*DECHd + (c-2)];
    else               v = 0.f;
    cat0[idx] = f2b(v);
}

__global__ void build_dec2(const float* __restrict__ go, const float* __restrict__ yc,
                           const float* __restrict__ h, const bf16* __restrict__ zr,
                           bf16* __restrict__ cat0, int t)
{
    size_t idx = (size_t)blockIdx.x*256 + threadIdx.x;
    int c = (int)(idx % CPd); size_t rb = idx / CPd;
    int n = (int)(rb >> 6), b = (int)(rb & 63);
    float v;
    if (c == 0)        v = go[rb];
    else if (c == 1)   v = yc[((size_t)b*HORt + t)*Nn + n];
    else if (c < 194)  v = b2f(zr[rb*LDZR + (c-2)]) * h[rb*DECHd + (c-2)];
    else               v = 0.f;
    cat0[idx] = f2b(v);
}

// ---------------------------------------------------------------------------
// attention (fp32, round-4 verified)
// ---------------------------------------------------------------------------
__global__ __launch_bounds__(64) void attn_kernel(const float* __restrict__ hT,
                                                  const float* __restrict__ Wq,
                                                  const float* __restrict__ Mem,
                                                  float* __restrict__ hdec,
                                                  int* __restrict__ ind0,
                                                  float* __restrict__ outv,
                                                  float* __restrict__ outq,
                                                  float* __restrict__ outp)
{
    int rb = blockIdx.x; int n = rb / Bb, b = rb % Bb;
    int tid = threadIdx.x;
    __shared__ float hl[Hh];
    __shared__ float ql[MDd];
    __shared__ float sm[Mm];
    __shared__ float stats[2];
    __shared__ int   smind;
    hl[tid]      = hT[(size_t)rb*Hh + tid];
    hl[tid + 64] = hT[(size_t)rb*Hh + tid + 64];
    __syncthreads();
    float q = 0.f;
    for (int hh = 0; hh < Hh; ++hh) q += hl[hh]*Wq[hh*MDd + tid];
    ql[tid] = q;
    size_t bn = (size_t)b*Nn + n;
    outq[bn*MDd + tid] = q;
    __syncthreads();
    if (tid < Mm){
        float s = 0.f;
        for (int d = 0; d < MDd; ++d) s += ql[d]*Mem[tid*MDd + d];
        sm[tid] = s;
    }
    __syncthreads();
    if (tid == 0){
        float mx = -1e30f; int am = 0;
        for (int m = 0; m < Mm; ++m) if (sm[m] > mx){ mx = sm[m]; am = m; }
        float ssum = 0.f;
        for (int m = 0; m < Mm; ++m){ float e = expf(sm[m]-mx); sm[m] = e; ssum += e; }
        stats[0] = 1.f/ssum; smind = am;
    }
    __syncthreads();
    float inv = stats[0]; int am = smind;
    float val = 0.f;
    for (int m = 0; m < Mm; ++m) val += sm[m]*inv*Mem[m*MDd + tid];
    outv[bn*MDd + tid] = val;
    outp[bn*MDd + tid] = Mem[am*MDd + tid];
    hdec[(size_t)rb*DECHd + tid]       = hl[tid];
    hdec[(size_t)rb*DECHd + 64 + tid]  = hl[tid + 64];
    hdec[(size_t)rb*DECHd + 128 + tid] = val;
    if (tid == 0) ind0[rb] = am;
}

__global__ void neg_kernel(const float* __restrict__ Mem, float* __restrict__ outn)
{
    size_t idx = (size_t)blockIdx.x*256 + threadIdx.x;
    outn[idx] = Mem[idx % (Mm*MDd)];
}

__global__ void mask_kernel(const int* __restrict__ ind0, float* __restrict__ outm)
{
    size_t idx = (size_t)blockIdx.x*256 + threadIdx.x;
    int m   = (int)(idx % Mm);
    size_t bn = idx / Mm;
    int n = (int)(bn % Nn);
    int b = (int)(bn / Nn);
    int rb = n*Bb + b;
    outm[idx] = (m != ind0[rb]) ? 1.f : 0.f;
}

__global__ __launch_bounds__(256) void proj_kernel(const float* __restrict__ h,
                                                   const float* __restrict__ pw,
                                                   const float* __restrict__ pb,
                                                   float* __restrict__ go,
                                                   float* __restrict__ out0, int t)
{
    int rb = blockIdx.x*4 + (threadIdx.x >> 6);
    int lane = threadIdx.x & 63;
    float s = 0.f;
    #pragma unroll
    for (int r = 0; r < 3; ++r){
        int i = lane + r*64;
        s += h[(size_t)rb*DECHd + i]*pw[i];
    }
    #pragma unroll
    for (int off = 32; off > 0; off >>= 1) s += __shfl_down(s, off, 64);
    if (lane == 0){
        float v = s + pb[0];
        go[rb] = v;
        int n = rb / Bb, b = rb % Bb;
        out0[((size_t)b*HORt + t)*Nn + n] = v;
    }
}

// ---------------------------------------------------------------------------
extern "C" void kernel_launch(void* const* d_in, const int* in_sizes, int n_in,
                              void* d_out, int out_size, void* d_ws, size_t ws_size,
                              hipStream_t stream)
{
    const float* x    = (const float*)d_in[0];
    const float* ycov = (const float*)d_in[1];
    const float* emb  = (const float*)d_in[2];
    const float* Mem  = (const float*)d_in[3];
    const float* Wq   = (const float*)d_in[4];
    const float* eWg  = (const float*)d_in[5];
    const float* ebg  = (const float*)d_in[6];
    const float* eWu  = (const float*)d_in[7];
    const float* ebu  = (const float*)d_in[8];
    const float* dWg  = (const float*)d_in[9];
    const float* dbg  = (const float*)d_in[10];
    const float* dWu  = (const float*)d_in[11];
    const float* dbu  = (const float*)d_in[12];
    const float* pW   = (const float*)d_in[13];
    const float* pb   = (const float*)d_in[14];

    float* out        = (float*)d_out;
    float* out_output = out;                     // (B,HOR,N,1)     786432
    float* out_value  = out + 786432;
    float* out_query  = out + 4980736;
    float* out_pos    = out + 9175040;
    float* out_neg    = out + 13369344;          // 83,886,080 floats
    float* out_mask   = out + 97255424;

    // === determinism hammer: reproduce the validated first-call environment
    // (harness memset d_out to 0 before the validation call) on EVERY call.
    // All outputs + scratch are rewritten after this each launch.
    hipMemsetAsync(d_out, 0, (size_t)out_size * 4, stream);

    // ---- scratch in out_neg region (time-shared: encoder then decoder) ----
    float* xg  = out_neg;                        // 38,141,952 fp32
    float* zr  = out_neg + 38141952;             // 25,165,824 fp32
    bf16*  cat0 = (bf16*)out_neg;                // 14,680,064 bf16
    bf16*  cat1 = cat0 + 14680064;
    bf16*  cat2 = cat1 + 14680064;
    bf16*  zrb  = cat2 + 14680064;               // 25,165,824 bf16

    // ---- d_ws layout: 24,463,104 floats = 97.9 MB (ws >= 173 MB, r3) ----
    const size_t NEED = 24463104ull*4ull;
    if (ws_size < NEED){
        ws_probe_kernel<<<3072, 256, 0, stream>>>(out_output, (float)(ws_size >> 20));
        return;
    }
    float* Sf   = (float*)d_ws;                  // 1,048,576
    float* T2f  = Sf  + 1048576;                 // 1,048,576
    bf16*  Sb   = (bf16*)(T2f + 1048576);        // 1,048,576 bf16
    bf16*  T2b  = Sb + 1048576;                  // 1,048,576 bf16
    bf16*  wgD  = T2b + 1048576;                 // 3*224*384 = 258,048 bf16
    bf16*  wuD  = wgD + 258048;                  // 3*224*256 = 172,032 bf16 (192 padded to 256)
    float* henc = (float*)(wuD + 172032);        // 8,388,608 fp32
    float* hdec = henc + 8388608;                // 12,582,912 fp32
    float* go   = hdec + 12582912;               // 65,536 fp32
    int*   ind0 = (int*)(go + 65536);            // 65,536 int

    hipMemsetAsync(henc, 0, (size_t)8388608*4, stream);
    hipMemsetAsync(go,   0, (size_t)65536*4,   stream);

    supports_kernel<<<Nn, 256, 0, stream>>>(emb, Sf);
    t2_gemm<<<dim3(16,16), 256, 0, stream>>>(Sf, T2f);
    conv_f2b<<<4096, 256, 0, stream>>>(Sf,  Sb);
    conv_f2b<<<4096, 256, 0, stream>>>(T2f, T2b);
    conv_w<<<1008, 256, 0, stream>>>(dWg, wgD, 194, CPd, 384, 384);
    conv_w<<<672,  256, 0, stream>>>(dWu, wuD, 194, CPd, 192, 256);

    // -------- encoder: 12 steps, fp32 (round-4 verified path) --------
    for (int t = 0; t < Tt; ++t){
        build_cat1_enc<<<33024, 256, 0, stream>>>(x, henc, xg, t);
        gcn_gemm<<<dim3(129,16,2), 256, 0, stream>>>(Sf, T2f, xg, 129);
        gate_gemm<<<dim3(4,1024), 256, 0, stream>>>(xg, eWg, ebg, zr, 387, 256);
        build_cat2_enc<<<33024, 256, 0, stream>>>(x, henc, zr, xg, t);
        gcn_gemm<<<dim3(129,16,2), 256, 0, stream>>>(Sf, T2f, xg, 129);
        update_gemm<<<dim3(2,1024), 256, 0, stream>>>(xg, eWu, ebu, zr, henc, 387, 128);
    }

    // -------- attention (fp32 scores -> exact argmax) --------
    attn_kernel<<<65536, 64, 0, stream>>>(henc, Wq, Mem, hdec, ind0,
                                          out_value, out_query, out_pos);

    const ushort* Su  = (const ushort*)Sb;
    const ushort* T2u = (const ushort*)T2b;
    const ushort* c0u = (const ushort*)cat0;
    const ushort* c1u = (const ushort*)cat1;
    const ushort* c2u = (const ushort*)cat2;

    // -------- decoder: 12 steps, bf16 MFMA --------
    for (int t = 0; t < HORt; ++t){
        build_dec1<<<57344, 256, 0, stream>>>(go, ycov, hdec, cat0, t);
        mfma_gemm<0><<<dim3(JPd/128, 8), 256, 0, stream>>>(
            Su, nullptr, nullptr, c0u, nullptr, nullptr, 1, 1024, 1024, JPd,
            cat1, JPd, JPd, nullptr, nullptr, nullptr, 0);
        mfma_gemm<0><<<dim3(JPd/128, 8), 256, 0, stream>>>(
            T2u, nullptr, nullptr, c0u, nullptr, nullptr, 1, 1024, 1024, JPd,
            cat2, JPd, JPd, nullptr, nullptr, nullptr, 0);
        mfma_gemm<1><<<dim3(3, 512), 256, 0, stream>>>(
            c0u, c1u, c2u,
            (const ushort*)wgD, (const ushort*)(wgD + CPd*384), (const ushort*)(wgD + 2*CPd*384),
            3, CPd, CPd, 384, zrb, LDZR, 384, dbg, nullptr, nullptr, 0);
        build_dec2<<<57344, 256, 0, stream>>>(go, ycov, hdec, zrb, cat0, t);
        mfma_gemm<0><<<dim3(JPd/128, 8), 256, 0, stream>>>(
            Su, nullptr, nullptr, c0u, nullptr, nullptr, 1, 1024, 1024, JPd,
            cat1, JPd, JPd, nullptr, nullptr, nullptr, 0);
        mfma_gemm<0><<<dim3(JPd/128, 8), 256, 0, stream>>>(
            T2u, nullptr, nullptr, c0u, nullptr, nullptr, 1, 1024, 1024, JPd,
            cat2, JPd, JPd, nullptr, nullptr, nullptr, 0);
        mfma_gemm<2><<<dim3(2, 512), 256, 0, stream>>>(
            c0u, c1u, c2u,
            (const ushort*)wuD, (const ushort*)(wuD + CPd*256), (const ushort*)(wuD + 2*CPd*256),
            3, CPd, CPd, 256, nullptr, 0, 192, dbu, zrb, hdec, 192);
        proj_kernel<<<16384, 256, 0, stream>>>(hdec, pW, pb, go, out_output, t);
    }

    // -------- aux outputs LAST (out_neg doubled as scratch above) --------
    neg_kernel<<<327680, 256, 0, stream>>>(Mem, out_neg);
    mask_kernel<<<5120, 256, 0, stream>>>(ind0, out_mask);
}

// Round 8
// 14600.079 us; speedup vs baseline: 4.5161x; 2.1866x over previous
//
#include <hip/hip_runtime.h>
#include <hip/hip_bf16.h>

typedef __hip_bfloat16 bf16;
typedef __attribute__((ext_vector_type(8))) short short8;
typedef __attribute__((ext_vector_type(8))) _Float16 half8;
typedef __attribute__((ext_vector_type(4))) float f32x4;
typedef __attribute__((ext_vector_type(4))) int   int4v;

#define Bb   64
#define Tt   12
#define Nn   1024
#define HORt 12
#define Hh   128
#define Ee   16
#define Mm   20
#define MDd  64
#define DECHd 192
#define CPe  160               // padded enc cat width (129 -> 160)
#define JPe  (Bb*CPe)          // 10240
#define CPd  224               // padded dec cat width (194 -> 224)
#define JPd  (Bb*CPd)          // 14336
#define LDZR 384               // decoder zr stride (bf16)
#define ZRE  256               // encoder zr stride (fp32)

// split scales (exact powers of 2): S/T2 x4096, cat x16, weights x256.
// products carry 2^12 (gate/update) or 2^16->(store x2^4) (gcn): both unscale by 2^-12.
#define INV_SCALE (1.f/4096.f)

__device__ __forceinline__ float b2f(bf16 v){ return __bfloat162float(v); }
__device__ __forceinline__ bf16  f2b(float v){ return __float2bfloat16(v); }
__device__ __forceinline__ void splitf16(float v, ushort& hi, ushort& lo){
    _Float16 h = (_Float16)v;
    _Float16 l = (_Float16)(v - (float)h);
    hi = __builtin_bit_cast(ushort, h);
    lo = __builtin_bit_cast(ushort, l);
}

// ---------------------------------------------------------------------------
__global__ void ws_probe_kernel(float* __restrict__ out, float val)
{
    size_t i = (size_t)blockIdx.x*256 + threadIdx.x;
    out[i] = val;
}

__global__ void conv_f2b(const float* __restrict__ src, bf16* __restrict__ dst)
{
    size_t i = (size_t)blockIdx.x*256 + threadIdx.x;
    dst[i] = f2b(src[i]);
}

// fp32 -> scaled f16 hi/lo split (for S, T2)
__global__ void conv_split(const float* __restrict__ src, ushort* __restrict__ hi,
                           ushort* __restrict__ lo, float scale)
{
    size_t i = (size_t)blockIdx.x*256 + threadIdx.x;
    splitf16(src[i]*scale, hi[i], lo[i]);
}

// encoder weights: fp32 (3*C x No) -> f16 hi/lo [3][CP][No] x256, zero pads
__global__ void conv_w_split(const float* __restrict__ W, ushort* __restrict__ hi,
                             ushort* __restrict__ lo, int C, int CP, int No)
{
    int idx = blockIdx.x*256 + threadIdx.x;
    if (idx >= 3*CP*No) return;
    int km = idx / (CP*No);
    int r  = idx % (CP*No);
    int c  = r / No, o = r % No;
    float v = (c < C) ? W[(size_t)(km*C + c)*No + o]*256.f : 0.f;
    splitf16(v, hi[idx], lo[idx]);
}

// decoder weights (bf16, round-7 verified)
__global__ void conv_w(const float* __restrict__ W, bf16* __restrict__ dst,
                       int C, int CP, int No, int NoP)
{
    int idx = blockIdx.x*256 + threadIdx.x;
    int tot = 3*CP*NoP;
    if (idx >= tot) return;
    int km = idx / (CP*NoP);
    int r  = idx % (CP*NoP);
    int c  = r / NoP, o = r % NoP;
    dst[idx] = (c < C && o < No) ? f2b(W[(size_t)(km*C + c)*No + o]) : f2b(0.f);
}

// ---------------------------------------------------------------------------
// supports = softmax(relu(emb @ emb^T), axis=1)  (fp32, verified)
// ---------------------------------------------------------------------------
__global__ __launch_bounds__(256) void supports_kernel(const float* __restrict__ emb,
                                                       float* __restrict__ S)
{
    int n = blockIdx.x;
    __shared__ float row[Nn];
    __shared__ float en[Ee];
    __shared__ float red[256];
    int tid = threadIdx.x;
    if (tid < Ee) en[tid] = emb[n*Ee + tid];
    __syncthreads();
    float lmax = -1e30f;
    for (int j = tid; j < Nn; j += 256){
        float d = 0.f;
        #pragma unroll
        for (int e = 0; e < Ee; ++e) d += en[e]*emb[j*Ee + e];
        d = d > 0.f ? d : 0.f;
        row[j] = d;
        lmax = fmaxf(lmax, d);
    }
    red[tid] = lmax; __syncthreads();
    for (int s = 128; s > 0; s >>= 1){ if (tid < s) red[tid] = fmaxf(red[tid], red[tid+s]); __syncthreads(); }
    float mx = red[0]; __syncthreads();
    float lsum = 0.f;
    for (int j = tid; j < Nn; j += 256){ float e = expf(row[j]-mx); row[j] = e; lsum += e; }
    red[tid] = lsum; __syncthreads();
    for (int s = 128; s > 0; s >>= 1){ if (tid < s) red[tid] += red[tid+s]; __syncthreads(); }
    float inv = 1.f/red[0];
    for (int j = tid; j < Nn; j += 256) S[n*Nn + j] = row[j]*inv;
}

// ---------------------------------------------------------------------------
// T2 = 2*S@S - I   (fp32, verified)
// ---------------------------------------------------------------------------
__global__ __launch_bounds__(256) void t2_gemm(const float* __restrict__ S,
                                               float* __restrict__ T2)
{
    int n0 = blockIdx.y*64, j0 = blockIdx.x*64;
    __shared__ float As[16][65];
    __shared__ float Xs[16][65];
    int tid = threadIdx.x; int tx = tid & 15, ty = tid >> 4;
    float acc[4][4] = {};
    for (int k0 = 0; k0 < Nn; k0 += 16){
        #pragma unroll
        for (int r = 0; r < 4; ++r){
            int idx = tid + r*256;
            int ar = idx >> 4, ak = idx & 15;
            As[ak][ar] = S[(n0+ar)*Nn + k0+ak];
        }
        #pragma unroll
        for (int r = 0; r < 4; ++r){
            int idx = tid + r*256;
            int xm = idx >> 6, xj = idx & 63;
            Xs[xm][xj] = S[(k0+xm)*Nn + j0+xj];
        }
        __syncthreads();
        #pragma unroll
        for (int kk = 0; kk < 16; ++kk){
            float a[4], xv[4];
            #pragma unroll
            for (int i = 0; i < 4; ++i) a[i]  = As[kk][ty*4+i];
            #pragma unroll
            for (int j = 0; j < 4; ++j) xv[j] = Xs[kk][tx*4+j];
            #pragma unroll
            for (int i = 0; i < 4; ++i)
                #pragma unroll
                for (int j = 0; j < 4; ++j) acc[i][j] += a[i]*xv[j];
        }
        __syncthreads();
    }
    #pragma unroll
    for (int i = 0; i < 4; ++i){
        int n = n0 + ty*4 + i;
        #pragma unroll
        for (int j = 0; j < 4; ++j){
            int c = j0 + tx*4 + j;
            T2[n*Nn + c] = 2.f*acc[i][j] - (n == c ? 1.f : 0.f);
        }
    }
}

// ---------------------------------------------------------------------------
// split-fp16 3-pass MFMA GEMM: OUT = sum_km (Ahi+Alo)_km @ (Bhi+Blo)_km
// (computes hh + hl + lh; missing ll ~ 2^-22 rel). 128x128 tile, BK=32,
// 4 waves, 4x4 16x16x32 f16 frags; XOR chunk swizzle (verified structure).
// EPI 0: v=acc*INV_SCALE -> split-store f16 hi/lo (cat-scale, x16 embedded)
// EPI 1: v=acc*INV_SCALE+bias -> sigmoid -> fp32 OutF
// EPI 2: hc=tanh(acc*INV_SCALE+bias); r=zrf[gm*ldo+Hd+gn]; h=r*h+(1-r)*hc
// ---------------------------------------------------------------------------
template<int EPI>
__global__ __launch_bounds__(256) void mfma_split(
    const ushort* __restrict__ Ah0, const ushort* __restrict__ Al0,
    const ushort* __restrict__ Ah1, const ushort* __restrict__ Al1,
    const ushort* __restrict__ Ah2, const ushort* __restrict__ Al2,
    const ushort* __restrict__ Bh0, const ushort* __restrict__ Bl0,
    const ushort* __restrict__ Bh1, const ushort* __restrict__ Bl1,
    const ushort* __restrict__ Bh2, const ushort* __restrict__ Bl2,
    int nmat, int Ksz, int lda, int ldb,
    ushort* __restrict__ OutHi, ushort* __restrict__ OutLo, int ldc, int Ncols,
    float* __restrict__ OutF, int ldo,
    const float* __restrict__ bias, const float* __restrict__ zrf,
    float* __restrict__ hbuf, int Hd)
{
    __shared__ short Ah_s[128*32];
    __shared__ short Al_s[128*32];
    __shared__ short Bh_s[128*32];
    __shared__ short Bl_s[128*32];
    int tid = threadIdx.x;
    int m0 = blockIdx.y * 128;
    int n0 = blockIdx.x * 128;
    int wave = tid >> 6, lane = tid & 63;
    int wr = wave >> 1, wc = wave & 1;
    int lr = lane & 15, lk8 = lane >> 4;

    f32x4 acc[4][4];
    #pragma unroll
    for (int i = 0; i < 4; ++i)
        #pragma unroll
        for (int j = 0; j < 4; ++j) acc[i][j] = (f32x4){0.f,0.f,0.f,0.f};

    const ushort* Ahs[3] = {Ah0, Ah1, Ah2};
    const ushort* Als[3] = {Al0, Al1, Al2};
    const ushort* Bhs[3] = {Bh0, Bh1, Bh2};
    const ushort* Bls[3] = {Bl0, Bl1, Bl2};

    int bkp = tid & 15;        // k-pair index (rows 2*bkp, 2*bkp+1)
    int bcc = tid >> 4;        // col-chunk (8 cols)

    for (int km = 0; km < nmat; ++km){
        const ushort* Agh = Ahs[km]; const ushort* Agl = Als[km];
        const ushort* Bgh = Bhs[km]; const ushort* Bgl = Bls[km];
        for (int k0 = 0; k0 < Ksz; k0 += 32){
            // ---- stage A hi/lo tiles (128 x 32), swizzled ----
            #pragma unroll
            for (int r = 0; r < 2; ++r){
                int i = tid + r*256;
                int row = i >> 2, cc = i & 3;
                size_t so = (size_t)(m0+row)*lda + k0 + cc*8;
                int dst = row*64 + ((cc ^ (row & 3)) << 4);
                *(int4v*)((char*)Ah_s + dst) = *(const int4v*)(Agh + so);
                *(int4v*)((char*)Al_s + dst) = *(const int4v*)(Agl + so);
            }
            // ---- stage B hi/lo tiles transposed (Bs[col][k]), swizzled ----
            {
                int kk = k0 + bkp*2;
                size_t so1 = (size_t)kk*ldb + n0 + bcc*8;
                size_t so2 = so1 + ldb;
                int4v vh1 = *(const int4v*)(Bgh + so1);
                int4v vh2 = *(const int4v*)(Bgh + so2);
                int4v vl1 = *(const int4v*)(Bgl + so1);
                int4v vl2 = *(const int4v*)(Bgl + so2);
                const ushort* gh1 = (const ushort*)&vh1;
                const ushort* gh2 = (const ushort*)&vh2;
                const ushort* gl1 = (const ushort*)&vl1;
                const ushort* gl2 = (const ushort*)&vl2;
                #pragma unroll
                for (int e = 0; e < 8; ++e){
                    int col = bcc*8 + e;
                    int kc = (bkp >> 2) ^ (col & 3);
                    int dst = col*64 + kc*16 + (bkp & 3)*4;
                    *(unsigned*)((char*)Bh_s + dst) = (unsigned)gh1[e] | ((unsigned)gh2[e] << 16);
                    *(unsigned*)((char*)Bl_s + dst) = (unsigned)gl1[e] | ((unsigned)gl2[e] << 16);
                }
            }
            __syncthreads();
            // ---- fragments + 3-pass MFMA ----
            half8 ah[4], al[4], bh[4], bl[4];
            #pragma unroll
            for (int mi = 0; mi < 4; ++mi){
                int row = wr*64 + mi*16 + lr;
                int off = row*64 + ((lk8 ^ (row & 3)) << 4);
                ah[mi] = *(const half8*)((const char*)Ah_s + off);
                al[mi] = *(const half8*)((const char*)Al_s + off);
            }
            #pragma unroll
            for (int ni = 0; ni < 4; ++ni){
                int col = wc*64 + ni*16 + lr;
                int off = col*64 + ((lk8 ^ (col & 3)) << 4);
                bh[ni] = *(const half8*)((const char*)Bh_s + off);
                bl[ni] = *(const half8*)((const char*)Bl_s + off);
            }
            #pragma unroll
            for (int mi = 0; mi < 4; ++mi)
                #pragma unroll
                for (int ni = 0; ni < 4; ++ni){
                    acc[mi][ni] = __builtin_amdgcn_mfma_f32_16x16x32_f16(ah[mi], bh[ni], acc[mi][ni], 0, 0, 0);
                    acc[mi][ni] = __builtin_amdgcn_mfma_f32_16x16x32_f16(ah[mi], bl[ni], acc[mi][ni], 0, 0, 0);
                    acc[mi][ni] = __builtin_amdgcn_mfma_f32_16x16x32_f16(al[mi], bh[ni], acc[mi][ni], 0, 0, 0);
                }
            __syncthreads();
        }
    }

    // ---- epilogue: C/D layout col=lane&15, row=(lane>>4)*4+reg ----
    int rbase = lk8 * 4;
    #pragma unroll
    for (int mi = 0; mi < 4; ++mi){
        #pragma unroll
        for (int ni = 0; ni < 4; ++ni){
            int gn = n0 + wc*64 + ni*16 + lr;
            if (gn >= Ncols) continue;
            #pragma unroll
            for (int rg = 0; rg < 4; ++rg){
                int gm = m0 + wr*64 + mi*16 + rbase + rg;
                float v = acc[mi][ni][rg] * INV_SCALE;
                if (EPI == 0){
                    ushort h, l;
                    splitf16(v, h, l);
                    OutHi[(size_t)gm*ldc + gn] = h;
                    OutLo[(size_t)gm*ldc + gn] = l;
                } else if (EPI == 1){
                    v += bias[gn];
                    OutF[(size_t)gm*ldo + gn] = 1.f/(1.f + expf(-v));
                } else {
                    float hc = tanhf(v + bias[gn]);
                    float rr = zrf[(size_t)gm*ldo + Hd + gn];
                    float ho = hbuf[(size_t)gm*Hd + gn];
                    hbuf[(size_t)gm*Hd + gn] = rr*ho + (1.f-rr)*hc;
                }
            }
        }
    }
}

// ---------------------------------------------------------------------------
// encoder cat builders: split-f16 hi/lo (x16 cat scale), zero pads
// ---------------------------------------------------------------------------
__global__ void build_enc1_split(const float* __restrict__ x, const float* __restrict__ h,
                                 ushort* __restrict__ chi, ushort* __restrict__ clo, int t)
{
    size_t idx = (size_t)blockIdx.x*256 + threadIdx.x;      // N*B*CPe
    int c = (int)(idx % CPe); size_t rb = idx / CPe;
    int n = (int)(rb >> 6), b = (int)(rb & 63);
    float v;
    if (c == 0)        v = x[((size_t)b*Tt + t)*Nn + n];
    else if (c < 129)  v = h[rb*Hh + (c-1)];
    else               v = 0.f;
    splitf16(v*16.f, chi[idx], clo[idx]);
}

__global__ void build_enc2_split(const float* __restrict__ x, const float* __restrict__ h,
                                 const float* __restrict__ zre,
                                 ushort* __restrict__ chi, ushort* __restrict__ clo, int t)
{
    size_t idx = (size_t)blockIdx.x*256 + threadIdx.x;
    int c = (int)(idx % CPe); size_t rb = idx / CPe;
    int n = (int)(rb >> 6), b = (int)(rb & 63);
    float v;
    if (c == 0)        v = x[((size_t)b*Tt + t)*Nn + n];
    else if (c < 129)  v = zre[rb*ZRE + (c-1)] * h[rb*Hh + (c-1)];
    else               v = 0.f;
    splitf16(v*16.f, chi[idx], clo[idx]);
}

// ---------------------------------------------------------------------------
// decoder bf16 MFMA GEMM (round-7 verified, verbatim)
// ---------------------------------------------------------------------------
template<int EPI>
__global__ __launch_bounds__(256) void mfma_gemm(
    const ushort* __restrict__ A0, const ushort* __restrict__ A1, const ushort* __restrict__ A2,
    const ushort* __restrict__ B0, const ushort* __restrict__ B1, const ushort* __restrict__ B2,
    int nmat, int Ksz, int lda, int ldb,
    bf16* __restrict__ Cout, int ldc, int Ncols,
    const float* __restrict__ bias,
    const bf16* __restrict__ zr, float* __restrict__ hbuf, int Hd)
{
    __shared__ short As[128*32];
    __shared__ short Bs[128*32];
    int tid = threadIdx.x;
    int m0 = blockIdx.y * 128;
    int n0 = blockIdx.x * 128;
    int wave = tid >> 6, lane = tid & 63;
    int wr = wave >> 1, wc = wave & 1;
    int lr = lane & 15, lk8 = lane >> 4;

    f32x4 acc[4][4];
    #pragma unroll
    for (int i = 0; i < 4; ++i)
        #pragma unroll
        for (int j = 0; j < 4; ++j) acc[i][j] = (f32x4){0.f,0.f,0.f,0.f};

    const ushort* Aps[3] = {A0, A1, A2};
    const ushort* Bps[3] = {B0, B1, B2};

    int bkp = tid & 15;
    int bcc = tid >> 4;

    for (int km = 0; km < nmat; ++km){
        const ushort* Ag = Aps[km];
        const ushort* Bg = Bps[km];
        for (int k0 = 0; k0 < Ksz; k0 += 32){
            #pragma unroll
            for (int r = 0; r < 2; ++r){
                int i = tid + r*256;
                int row = i >> 2, cc = i & 3;
                const ushort* src = Ag + (size_t)(m0+row)*lda + k0 + cc*8;
                int4v v = *(const int4v*)src;
                int dst = row*64 + ((cc ^ (row & 3)) << 4);
                *(int4v*)((char*)As + dst) = v;
            }
            {
                int kk = k0 + bkp*2;
                const ushort* s1 = Bg + (size_t)kk*ldb + n0 + bcc*8;
                const ushort* s2 = s1 + ldb;
                int4v v1 = *(const int4v*)s1;
                int4v v2 = *(const int4v*)s2;
                const ushort* g1 = (const ushort*)&v1;
                const ushort* g2 = (const ushort*)&v2;
                #pragma unroll
                for (int e = 0; e < 8; ++e){
                    int col = bcc*8 + e;
                    unsigned pv = (unsigned)g1[e] | ((unsigned)g2[e] << 16);
                    int kc = (bkp >> 2) ^ (col & 3);
                    int dst = col*64 + kc*16 + (bkp & 3)*4;
                    *(unsigned*)((char*)Bs + dst) = pv;
                }
            }
            __syncthreads();
            short8 af[4], bfv[4];
            #pragma unroll
            for (int mi = 0; mi < 4; ++mi){
                int row = wr*64 + mi*16 + lr;
                int off = row*64 + ((lk8 ^ (row & 3)) << 4);
                af[mi] = *(const short8*)((const char*)As + off);
            }
            #pragma unroll
            for (int ni = 0; ni < 4; ++ni){
                int col = wc*64 + ni*16 + lr;
                int off = col*64 + ((lk8 ^ (col & 3)) << 4);
                bfv[ni] = *(const short8*)((const char*)Bs + off);
            }
            #pragma unroll
            for (int mi = 0; mi < 4; ++mi)
                #pragma unroll
                for (int ni = 0; ni < 4; ++ni)
                    acc[mi][ni] = __builtin_amdgcn_mfma_f32_16x16x32_bf16(
                                      af[mi], bfv[ni], acc[mi][ni], 0, 0, 0);
            __syncthreads();
        }
    }

    int rbase = lk8 * 4;
    #pragma unroll
    for (int mi = 0; mi < 4; ++mi){
        #pragma unroll
        for (int ni = 0; ni < 4; ++ni){
            int gn = n0 + wc*64 + ni*16 + lr;
            if (gn >= Ncols) continue;
            #pragma unroll
            for (int rg = 0; rg < 4; ++rg){
                int gm = m0 + wr*64 + mi*16 + rbase + rg;
                float v = acc[mi][ni][rg];
                if (EPI == 0){
                    Cout[(size_t)gm*ldc + gn] = f2b(v);
                } else if (EPI == 1){
                    v += bias[gn];
                    Cout[(size_t)gm*ldc + gn] = f2b(1.f/(1.f + expf(-v)));
                } else {
                    float hc = tanhf(v + bias[gn]);
                    float rr = b2f(zr[(size_t)gm*LDZR + Hd + gn]);
                    float ho = hbuf[(size_t)gm*Hd + gn];
                    hbuf[(size_t)gm*Hd + gn] = rr*ho + (1.f-rr)*hc;
                }
            }
        }
    }
}

// decoder bias conv helper: fp32 bias used directly (dbg/dbu are fp32)
__global__ void build_dec1(const float* __restrict__ go, const float* __restrict__ yc,
                           const float* __restrict__ h, bf16* __restrict__ cat0, int t)
{
    size_t idx = (size_t)blockIdx.x*256 + threadIdx.x;      // N*B*CPd
    int c = (int)(idx % CPd); size_t rb = idx / CPd;
    int n = (int)(rb >> 6), b = (int)(rb & 63);
    float v;
    if (c == 0)        v = go[rb];
    else if (c == 1)   v = yc[((size_t)b*HORt + t)*Nn + n];
    else if (c < 194)  v = h[rb*DECHd + (c-2)];
    else               v = 0.f;
    cat0[idx] = f2b(v);
}

__global__ void build_dec2(const float* __restrict__ go, const float* __restrict__ yc,
                           const float* __restrict__ h, const bf16* __restrict__ zr,
                           bf16* __restrict__ cat0, int t)
{
    size_t idx = (size_t)blockIdx.x*256 + threadIdx.x;
    int c = (int)(idx % CPd); size_t rb = idx / CPd;
    int n = (int)(rb >> 6), b = (int)(rb & 63);
    float v;
    if (c == 0)        v = go[rb];
    else if (c == 1)   v = yc[((size_t)b*HORt + t)*Nn + n];
    else if (c < 194)  v = b2f(zr[rb*LDZR + (c-2)]) * h[rb*DECHd + (c-2)];
    else               v = 0.f;
    cat0[idx] = f2b(v);
}

// ---------------------------------------------------------------------------
// attention (fp32, verified)
// ---------------------------------------------------------------------------
__global__ __launch_bounds__(64) void attn_kernel(const float* __restrict__ hT,
                                                  const float* __restrict__ Wq,
                                                  const float* __restrict__ Mem,
                                                  float* __restrict__ hdec,
                                                  int* __restrict__ ind0,
                                                  float* __restrict__ outv,
                                                  float* __restrict__ outq,
                                                  float* __restrict__ outp)
{
    int rb = blockIdx.x; int n = rb / Bb, b = rb % Bb;
    int tid = threadIdx.x;
    __shared__ float hl[Hh];
    __shared__ float ql[MDd];
    __shared__ float sm[Mm];
    __shared__ float stats[2];
    __shared__ int   smind;
    hl[tid]      = hT[(size_t)rb*Hh + tid];
    hl[tid + 64] = hT[(size_t)rb*Hh + tid + 64];
    __syncthreads();
    float q = 0.f;
    for (int hh = 0; hh < Hh; ++hh) q += hl[hh]*Wq[hh*MDd + tid];
    ql[tid] = q;
    size_t bn = (size_t)b*Nn + n;
    outq[bn*MDd + tid] = q;
    __syncthreads();
    if (tid < Mm){
        float s = 0.f;
        for (int d = 0; d < MDd; ++d) s += ql[d]*Mem[tid*MDd + d];
        sm[tid] = s;
    }
    __syncthreads();
    if (tid == 0){
        float mx = -1e30f; int am = 0;
        for (int m = 0; m < Mm; ++m) if (sm[m] > mx){ mx = sm[m]; am = m; }
        float ssum = 0.f;
        for (int m = 0; m < Mm; ++m){ float e = expf(sm[m]-mx); sm[m] = e; ssum += e; }
        stats[0] = 1.f/ssum; smind = am;
    }
    __syncthreads();
    float inv = stats[0]; int am = smind;
    float val = 0.f;
    for (int m = 0; m < Mm; ++m) val += sm[m]*inv*Mem[m*MDd + tid];
    outv[bn*MDd + tid] = val;
    outp[bn*MDd + tid] = Mem[am*MDd + tid];
    hdec[(size_t)rb*DECHd + tid]       = hl[tid];
    hdec[(size_t)rb*DECHd + 64 + tid]  = hl[tid + 64];
    hdec[(size_t)rb*DECHd + 128 + tid] = val;
    if (tid == 0) ind0[rb] = am;
}

__global__ void neg_kernel(const float* __restrict__ Mem, float* __restrict__ outn)
{
    size_t idx = (size_t)blockIdx.x*256 + threadIdx.x;
    outn[idx] = Mem[idx % (Mm*MDd)];
}

__global__ void mask_kernel(const int* __restrict__ ind0, float* __restrict__ outm)
{
    size_t idx = (size_t)blockIdx.x*256 + threadIdx.x;
    int m   = (int)(idx % Mm);
    size_t bn = idx / Mm;
    int n = (int)(bn % Nn);
    int b = (int)(bn / Nn);
    int rb = n*Bb + b;
    outm[idx] = (m != ind0[rb]) ? 1.f : 0.f;
}

__global__ __launch_bounds__(256) void proj_kernel(const float* __restrict__ h,
                                                   const float* __restrict__ pw,
                                                   const float* __restrict__ pb,
                                                   float* __restrict__ go,
                                                   float* __restrict__ out0, int t)
{
    int rb = blockIdx.x*4 + (threadIdx.x >> 6);
    int lane = threadIdx.x & 63;
    float s = 0.f;
    #pragma unroll
    for (int r = 0; r < 3; ++r){
        int i = lane + r*64;
        s += h[(size_t)rb*DECHd + i]*pw[i];
    }
    #pragma unroll
    for (int off = 32; off > 0; off >>= 1) s += __shfl_down(s, off, 64);
    if (lane == 0){
        float v = s + pb[0];
        go[rb] = v;
        int n = rb / Bb, b = rb % Bb;
        out0[((size_t)b*HORt + t)*Nn + n] = v;
    }
}

// ---------------------------------------------------------------------------
extern "C" void kernel_launch(void* const* d_in, const int* in_sizes, int n_in,
                              void* d_out, int out_size, void* d_ws, size_t ws_size,
                              hipStream_t stream)
{
    const float* x    = (const float*)d_in[0];
    const float* ycov = (const float*)d_in[1];
    const float* emb  = (const float*)d_in[2];
    const float* Mem  = (const float*)d_in[3];
    const float* Wq   = (const float*)d_in[4];
    const float* eWg  = (const float*)d_in[5];
    const float* ebg  = (const float*)d_in[6];
    const float* eWu  = (const float*)d_in[7];
    const float* ebu  = (const float*)d_in[8];
    const float* dWg  = (const float*)d_in[9];
    const float* dbg  = (const float*)d_in[10];
    const float* dWu  = (const float*)d_in[11];
    const float* dbu  = (const float*)d_in[12];
    const float* pW   = (const float*)d_in[13];
    const float* pb   = (const float*)d_in[14];

    float* out        = (float*)d_out;
    float* out_output = out;
    float* out_value  = out + 786432;
    float* out_query  = out + 4980736;
    float* out_pos    = out + 9175040;
    float* out_neg    = out + 13369344;          // 83,886,080 floats (335.5 MB)
    float* out_mask   = out + 97255424;

    // determinism hammer (round-7 verified): identical state every call
    hipMemsetAsync(d_out, 0, (size_t)out_size * 4, stream);

    // ---- out_neg scratch, time-shared ----
    // encoder: catEh [3][65536][160] f16 (62.9MB) + catEl (62.9MB) + zrE fp32 (67MB)
    ushort* catEh = (ushort*)out_neg;                        // 31,457,280 halves
    ushort* catEl = catEh + 31457280;                        // 31,457,280 halves
    float*  zrE   = (float*)(catEl + 31457280);              // 16,777,216 fp32
    // decoder: cat0/1/2 + zrb (bf16), overwrites encoder scratch
    bf16*  cat0 = (bf16*)out_neg;
    bf16*  cat1 = cat0 + 14680064;
    bf16*  cat2 = cat1 + 14680064;
    bf16*  zrb  = cat2 + 14680064;

    // ---- d_ws layout (~107 MB; ws >= 173 MB established r3) ----
    const size_t NEED = 106979328;
    if (ws_size < NEED){
        ws_probe_kernel<<<3072, 256, 0, stream>>>(out_output, (float)(ws_size >> 20));
        return;
    }
    float*  Sf   = (float*)d_ws;                 // 1,048,576 f32
    float*  T2f  = Sf + 1048576;                 // 1,048,576 f32
    ushort* Sh   = (ushort*)(T2f + 1048576);     // 1,048,576 f16
    ushort* Sl   = Sh  + 1048576;
    ushort* T2h  = Sl  + 1048576;
    ushort* T2l  = T2h + 1048576;
    bf16*   Sb   = (bf16*)(T2l + 1048576);       // 1,048,576 bf16
    bf16*   T2b  = Sb + 1048576;
    ushort* wgEh = (ushort*)(T2b + 1048576);     // 3*160*256 = 122,880
    ushort* wgEl = wgEh + 122880;
    ushort* wuEh = wgEl + 122880;                // 3*160*128 = 61,440
    ushort* wuEl = wuEh + 61440;
    bf16*   wgD  = (bf16*)(wuEl + 61440);        // 3*224*384 = 258,048
    bf16*   wuD  = wgD + 258048;                 // 3*224*256 = 172,032
    float*  henc = (float*)(wuD + 172032);       // 8,388,608 f32
    float*  hdec = henc + 8388608;               // 12,582,912 f32
    float*  go   = hdec + 12582912;              // 65,536 f32
    int*    ind0 = (int*)(go + 65536);           // 65,536 int

    hipMemsetAsync(henc, 0, (size_t)8388608*4, stream);
    hipMemsetAsync(go,   0, (size_t)65536*4,   stream);

    supports_kernel<<<Nn, 256, 0, stream>>>(emb, Sf);
    t2_gemm<<<dim3(16,16), 256, 0, stream>>>(Sf, T2f);
    conv_split<<<4096, 256, 0, stream>>>(Sf,  Sh,  Sl,  4096.f);
    conv_split<<<4096, 256, 0, stream>>>(T2f, T2h, T2l, 4096.f);
    conv_f2b<<<4096, 256, 0, stream>>>(Sf,  Sb);
    conv_f2b<<<4096, 256, 0, stream>>>(T2f, T2b);
    conv_w_split<<<480, 256, 0, stream>>>(eWg, wgEh, wgEl, 129, CPe, 256);
    conv_w_split<<<240, 256, 0, stream>>>(eWu, wuEh, wuEl, 129, CPe, 128);
    conv_w<<<1008, 256, 0, stream>>>(dWg, wgD, 194, CPd, 384, 384);
    conv_w<<<672,  256, 0, stream>>>(dWu, wuD, 194, CPd, 192, 256);

    const size_t SL = (size_t)65536*CPe;         // cat slice elems = 10,485,760

    // -------- encoder: 12 steps, split-fp16 MFMA --------
    for (int t = 0; t < Tt; ++t){
        build_enc1_split<<<40960, 256, 0, stream>>>(x, henc, catEh, catEl, t);
        mfma_split<0><<<dim3(JPe/128, 8), 256, 0, stream>>>(
            Sh, Sl, nullptr, nullptr, nullptr, nullptr,
            catEh, catEl, nullptr, nullptr, nullptr, nullptr,
            1, Nn, Nn, JPe,
            catEh + SL, catEl + SL, JPe, JPe, nullptr, 0, nullptr, nullptr, nullptr, 0);
        mfma_split<0><<<dim3(JPe/128, 8), 256, 0, stream>>>(
            T2h, T2l, nullptr, nullptr, nullptr, nullptr,
            catEh, catEl, nullptr, nullptr, nullptr, nullptr,
            1, Nn, Nn, JPe,
            catEh + 2*SL, catEl + 2*SL, JPe, JPe, nullptr, 0, nullptr, nullptr, nullptr, 0);
        mfma_split<1><<<dim3(2, 512), 256, 0, stream>>>(
            catEh, catEl, catEh + SL, catEl + SL, catEh + 2*SL, catEl + 2*SL,
            wgEh, wgEl, wgEh + CPe*256, wgEl + CPe*256, wgEh + 2*CPe*256, wgEl + 2*CPe*256,
            3, CPe, CPe, 256,
            nullptr, nullptr, 0, 256, zrE, ZRE, ebg, nullptr, nullptr, 0);
        build_enc2_split<<<40960, 256, 0, stream>>>(x, henc, zrE, catEh, catEl, t);
        mfma_split<0><<<dim3(JPe/128, 8), 256, 0, stream>>>(
            Sh, Sl, nullptr, nullptr, nullptr, nullptr,
            catEh, catEl, nullptr, nullptr, nullptr, nullptr,
            1, Nn, Nn, JPe,
            catEh + SL, catEl + SL, JPe, JPe, nullptr, 0, nullptr, nullptr, nullptr, 0);
        mfma_split<0><<<dim3(JPe/128, 8), 256, 0, stream>>>(
            T2h, T2l, nullptr, nullptr, nullptr, nullptr,
            catEh, catEl, nullptr, nullptr, nullptr, nullptr,
            1, Nn, Nn, JPe,
            catEh + 2*SL, catEl + 2*SL, JPe, JPe, nullptr, 0, nullptr, nullptr, nullptr, 0);
        mfma_split<2><<<dim3(1, 512), 256, 0, stream>>>(
            catEh, catEl, catEh + SL, catEl + SL, catEh + 2*SL, catEl + 2*SL,
            wuEh, wuEl, wuEh + CPe*128, wuEl + CPe*128, wuEh + 2*CPe*128, wuEl + 2*CPe*128,
            3, CPe, CPe, 128,
            nullptr, nullptr, 0, 128, nullptr, ZRE, ebu, zrE, henc, 128);
    }

    // -------- attention (fp32 scores -> exact argmax) --------
    attn_kernel<<<65536, 64, 0, stream>>>(henc, Wq, Mem, hdec, ind0,
                                          out_value, out_query, out_pos);

    const ushort* Su  = (const ushort*)Sb;
    const ushort* T2u = (const ushort*)T2b;
    const ushort* c0u = (const ushort*)cat0;
    const ushort* c1u = (const ushort*)cat1;
    const ushort* c2u = (const ushort*)cat2;

    // -------- decoder: 12 steps, bf16 MFMA (round-7 verified) --------
    for (int t = 0; t < HORt; ++t){
        build_dec1<<<57344, 256, 0, stream>>>(go, ycov, hdec, cat0, t);
        mfma_gemm<0><<<dim3(JPd/128, 8), 256, 0, stream>>>(
            Su, nullptr, nullptr, c0u, nullptr, nullptr, 1, 1024, 1024, JPd,
            cat1, JPd, JPd, nullptr, nullptr, nullptr, 0);
        mfma_gemm<0><<<dim3(JPd/128, 8), 256, 0, stream>>>(
            T2u, nullptr, nullptr, c0u, nullptr, nullptr, 1, 1024, 1024, JPd,
            cat2, JPd, JPd, nullptr, nullptr, nullptr, 0);
        mfma_gemm<1><<<dim3(3, 512), 256, 0, stream>>>(
            c0u, c1u, c2u,
            (const ushort*)wgD, (const ushort*)(wgD + CPd*384), (const ushort*)(wgD + 2*CPd*384),
            3, CPd, CPd, 384, zrb, LDZR, 384, dbg, nullptr, nullptr, 0);
        build_dec2<<<57344, 256, 0, stream>>>(go, ycov, hdec, zrb, cat0, t);
        mfma_gemm<0><<<dim3(JPd/128, 8), 256, 0, stream>>>(
            Su, nullptr, nullptr, c0u, nullptr, nullptr, 1, 1024, 1024, JPd,
            cat1, JPd, JPd, nullptr, nullptr, nullptr, 0);
        mfma_gemm<0><<<dim3(JPd/128, 8), 256, 0, stream>>>(
            T2u, nullptr, nullptr, c0u, nullptr, nullptr, 1, 1024, 1024, JPd,
            cat2, JPd, JPd, nullptr, nullptr, nullptr, 0);
        mfma_gemm<2><<<dim3(2, 512), 256, 0, stream>>>(
            c0u, c1u, c2u,
            (const ushort*)wuD, (const ushort*)(wuD + CPd*256), (const ushort*)(wuD + 2*CPd*256),
            3, CPd, CPd, 256, nullptr, 0, 192, dbu, zrb, hdec, 192);
        proj_kernel<<<16384, 256, 0, stream>>>(hdec, pW, pb, go, out_output, t);
    }

    // -------- aux outputs LAST --------
    neg_kernel<<<327680, 256, 0, stream>>>(Mem, out_neg);
    mask_kernel<<<5120, 256, 0, stream>>>(ind0, out_mask);
}

// Round 10
// 12275.832 us; speedup vs baseline: 5.3711x; 1.1893x over previous
//
#include <hip/hip_runtime.h>
#include <hip/hip_bf16.h>

typedef __hip_bfloat16 bf16;
typedef __attribute__((ext_vector_type(8))) short short8;
typedef __attribute__((ext_vector_type(8))) _Float16 half8;
typedef __attribute__((ext_vector_type(4))) float f32x4;
typedef __attribute__((ext_vector_type(4))) int   int4v;

#define Bb   64
#define Tt   12
#define Nn   1024
#define HORt 12
#define Hh   128
#define Ee   16
#define Mm   20
#define MDd  64
#define DECHd 192
#define CPe  160               // padded enc cat width (129 -> 160)
#define JPe  (Bb*CPe)          // 10240
#define CPd  224               // padded dec cat width (194 -> 224)
#define JPd  (Bb*CPd)          // 14336
#define LDZR 384               // decoder zr stride (bf16)
#define ZRE  256               // encoder zr stride (fp32)

#define INV_SCALE (1.f/4096.f)

// async global->LDS: wave-uniform LDS base + lane*16; per-lane global src.
#define GLOAD_LDS16(gp, lp) \
    __builtin_amdgcn_global_load_lds((const __attribute__((address_space(1))) void*)(gp), \
                                     (__attribute__((address_space(3))) void*)(lp), 16, 0, 0)

__device__ __forceinline__ float b2f(bf16 v){ return __bfloat162float(v); }
__device__ __forceinline__ bf16  f2b(float v){ return __float2bfloat16(v); }
__device__ __forceinline__ void splitf16(float v, ushort& hi, ushort& lo){
    _Float16 h = (_Float16)v;
    _Float16 l = (_Float16)(v - (float)h);
    hi = __builtin_bit_cast(ushort, h);
    lo = __builtin_bit_cast(ushort, l);
}

// ---------------------------------------------------------------------------
__global__ void ws_probe_kernel(float* __restrict__ out, float val)
{
    size_t i = (size_t)blockIdx.x*256 + threadIdx.x;
    out[i] = val;
}

__global__ void conv_f2b(const float* __restrict__ src, bf16* __restrict__ dst)
{
    size_t i = (size_t)blockIdx.x*256 + threadIdx.x;
    dst[i] = f2b(src[i]);
}

__global__ void conv_split(const float* __restrict__ src, ushort* __restrict__ hi,
                           ushort* __restrict__ lo, float scale)
{
    size_t i = (size_t)blockIdx.x*256 + threadIdx.x;
    splitf16(src[i]*scale, hi[i], lo[i]);
}

__global__ void conv_w_split(const float* __restrict__ W, ushort* __restrict__ hi,
                             ushort* __restrict__ lo, int C, int CP, int No)
{
    int idx = blockIdx.x*256 + threadIdx.x;
    if (idx >= 3*CP*No) return;
    int km = idx / (CP*No);
    int r  = idx % (CP*No);
    int c  = r / No, o = r % No;
    float v = (c < C) ? W[(size_t)(km*C + c)*No + o]*256.f : 0.f;
    splitf16(v, hi[idx], lo[idx]);
}

__global__ void conv_w(const float* __restrict__ W, bf16* __restrict__ dst,
                       int C, int CP, int No, int NoP)
{
    int idx = blockIdx.x*256 + threadIdx.x;
    int tot = 3*CP*NoP;
    if (idx >= tot) return;
    int km = idx / (CP*NoP);
    int r  = idx % (CP*NoP);
    int c  = r / NoP, o = r % NoP;
    dst[idx] = (c < C && o < No) ? f2b(W[(size_t)(km*C + c)*No + o]) : f2b(0.f);
}

// ---------------------------------------------------------------------------
// supports = softmax(relu(emb @ emb^T), axis=1)  (fp32, verified)
// ---------------------------------------------------------------------------
__global__ __launch_bounds__(256) void supports_kernel(const float* __restrict__ emb,
                                                       float* __restrict__ S)
{
    int n = blockIdx.x;
    __shared__ float row[Nn];
    __shared__ float en[Ee];
    __shared__ float red[256];
    int tid = threadIdx.x;
    if (tid < Ee) en[tid] = emb[n*Ee + tid];
    __syncthreads();
    float lmax = -1e30f;
    for (int j = tid; j < Nn; j += 256){
        float d = 0.f;
        #pragma unroll
        for (int e = 0; e < Ee; ++e) d += en[e]*emb[j*Ee + e];
        d = d > 0.f ? d : 0.f;
        row[j] = d;
        lmax = fmaxf(lmax, d);
    }
    red[tid] = lmax; __syncthreads();
    for (int s = 128; s > 0; s >>= 1){ if (tid < s) red[tid] = fmaxf(red[tid], red[tid+s]); __syncthreads(); }
    float mx = red[0]; __syncthreads();
    float lsum = 0.f;
    for (int j = tid; j < Nn; j += 256){ float e = expf(row[j]-mx); row[j] = e; lsum += e; }
    red[tid] = lsum; __syncthreads();
    for (int s = 128; s > 0; s >>= 1){ if (tid < s) red[tid] += red[tid+s]; __syncthreads(); }
    float inv = 1.f/red[0];
    for (int j = tid; j < Nn; j += 256) S[n*Nn + j] = row[j]*inv;
}

// ---------------------------------------------------------------------------
// T2 = 2*S@S - I   (fp32, verified)
// ---------------------------------------------------------------------------
__global__ __launch_bounds__(256) void t2_gemm(const float* __restrict__ S,
                                               float* __restrict__ T2)
{
    int n0 = blockIdx.y*64, j0 = blockIdx.x*64;
    __shared__ float As[16][65];
    __shared__ float Xs[16][65];
    int tid = threadIdx.x; int tx = tid & 15, ty = tid >> 4;
    float acc[4][4] = {};
    for (int k0 = 0; k0 < Nn; k0 += 16){
        #pragma unroll
        for (int r = 0; r < 4; ++r){
            int idx = tid + r*256;
            int ar = idx >> 4, ak = idx & 15;
            As[ak][ar] = S[(n0+ar)*Nn + k0+ak];
        }
        #pragma unroll
        for (int r = 0; r < 4; ++r){
            int idx = tid + r*256;
            int xm = idx >> 6, xj = idx & 63;
            Xs[xm][xj] = S[(k0+xm)*Nn + j0+xj];
        }
        __syncthreads();
        #pragma unroll
        for (int kk = 0; kk < 16; ++kk){
            float a[4], xv[4];
            #pragma unroll
            for (int i = 0; i < 4; ++i) a[i]  = As[kk][ty*4+i];
            #pragma unroll
            for (int j = 0; j < 4; ++j) xv[j] = Xs[kk][tx*4+j];
            #pragma unroll
            for (int i = 0; i < 4; ++i)
                #pragma unroll
                for (int j = 0; j < 4; ++j) acc[i][j] += a[i]*xv[j];
        }
        __syncthreads();
    }
    #pragma unroll
    for (int i = 0; i < 4; ++i){
        int n = n0 + ty*4 + i;
        #pragma unroll
        for (int j = 0; j < 4; ++j){
            int c = j0 + tx*4 + j;
            T2[n*Nn + c] = 2.f*acc[i][j] - (n == c ? 1.f : 0.f);
        }
    }
}

// ---------------------------------------------------------------------------
// split-fp16 3-pass MFMA GEMM (r8-verified math; A staged via global_load_lds
// with source-side inverse swizzle -> LDS content identical to r8).
// ---------------------------------------------------------------------------
template<int EPI>
__global__ __launch_bounds__(256) void mfma_split(
    const ushort* __restrict__ Ah0, const ushort* __restrict__ Al0,
    const ushort* __restrict__ Ah1, const ushort* __restrict__ Al1,
    const ushort* __restrict__ Ah2, const ushort* __restrict__ Al2,
    const ushort* __restrict__ Bh0, const ushort* __restrict__ Bl0,
    const ushort* __restrict__ Bh1, const ushort* __restrict__ Bl1,
    const ushort* __restrict__ Bh2, const ushort* __restrict__ Bl2,
    int nmat, int Ksz, int lda, int ldb,
    ushort* __restrict__ OutHi, ushort* __restrict__ OutLo, int ldc, int Ncols,
    float* __restrict__ OutF, int ldo,
    const float* __restrict__ bias, const float* __restrict__ zrf,
    float* __restrict__ hbuf, int Hd)
{
    __shared__ short Ah_s[128*32];
    __shared__ short Al_s[128*32];
    __shared__ short Bh_s[128*32];
    __shared__ short Bl_s[128*32];
    int tid = threadIdx.x;
    int m0 = blockIdx.y * 128;
    int n0 = blockIdx.x * 128;
    int wave = tid >> 6, lane = tid & 63;
    int wr = wave >> 1, wc = wave & 1;
    int lr = lane & 15, lk8 = lane >> 4;

    f32x4 acc[4][4];
    #pragma unroll
    for (int i = 0; i < 4; ++i)
        #pragma unroll
        for (int j = 0; j < 4; ++j) acc[i][j] = (f32x4){0.f,0.f,0.f,0.f};

    const ushort* Ahs[3] = {Ah0, Ah1, Ah2};
    const ushort* Als[3] = {Al0, Al1, Al2};
    const ushort* Bhs[3] = {Bh0, Bh1, Bh2};
    const ushort* Bls[3] = {Bl0, Bl1, Bl2};

    int bkp = tid & 15;        // k-pair index (rows 2*bkp, 2*bkp+1)
    int bcc = tid >> 4;        // col-chunk (8 cols)
    int wbase = wave * 1024;   // wave-uniform LDS byte base for A DMA

    for (int km = 0; km < nmat; ++km){
        const ushort* Agh = Ahs[km]; const ushort* Agl = Als[km];
        const ushort* Bgh = Bhs[km]; const ushort* Bgl = Bls[km];
        for (int k0 = 0; k0 < Ksz; k0 += 32){
            // ---- A hi/lo tiles via global_load_lds (inverse-swizzled src) ----
            #pragma unroll
            for (int r = 0; r < 2; ++r){
                int i = tid + r*256;
                int row = i >> 2, q = i & 3;
                int sq = q ^ (row & 3);
                size_t so = (size_t)(m0+row)*lda + k0 + sq*8;
                int lofs = r*4096 + wbase;
                GLOAD_LDS16(Agh + so, (char*)Ah_s + lofs);
                GLOAD_LDS16(Agl + so, (char*)Al_s + lofs);
            }
            // ---- B hi/lo tiles transposed (reg-staged, r8-verified) ----
            {
                int kk = k0 + bkp*2;
                size_t so1 = (size_t)kk*ldb + n0 + bcc*8;
                size_t so2 = so1 + ldb;
                int4v vh1 = *(const int4v*)(Bgh + so1);
                int4v vh2 = *(const int4v*)(Bgh + so2);
                int4v vl1 = *(const int4v*)(Bgl + so1);
                int4v vl2 = *(const int4v*)(Bgl + so2);
                const ushort* gh1 = (const ushort*)&vh1;
                const ushort* gh2 = (const ushort*)&vh2;
                const ushort* gl1 = (const ushort*)&vl1;
                const ushort* gl2 = (const ushort*)&vl2;
                #pragma unroll
                for (int e = 0; e < 8; ++e){
                    int col = bcc*8 + e;
                    int kc = (bkp >> 2) ^ (col & 3);
                    int dst = col*64 + kc*16 + (bkp & 3)*4;
                    *(unsigned*)((char*)Bh_s + dst) = (unsigned)gh1[e] | ((unsigned)gh2[e] << 16);
                    *(unsigned*)((char*)Bl_s + dst) = (unsigned)gl1[e] | ((unsigned)gl2[e] << 16);
                }
            }
            __syncthreads();
            half8 ah[4], al[4], bh[4], bl[4];
            #pragma unroll
            for (int mi = 0; mi < 4; ++mi){
                int row = wr*64 + mi*16 + lr;
                int off = row*64 + ((lk8 ^ (row & 3)) << 4);
                ah[mi] = *(const half8*)((const char*)Ah_s + off);
                al[mi] = *(const half8*)((const char*)Al_s + off);
            }
            #pragma unroll
            for (int ni = 0; ni < 4; ++ni){
                int col = wc*64 + ni*16 + lr;
                int off = col*64 + ((lk8 ^ (col & 3)) << 4);
                bh[ni] = *(const half8*)((const char*)Bh_s + off);
                bl[ni] = *(const half8*)((const char*)Bl_s + off);
            }
            #pragma unroll
            for (int mi = 0; mi < 4; ++mi)
                #pragma unroll
                for (int ni = 0; ni < 4; ++ni){
                    acc[mi][ni] = __builtin_amdgcn_mfma_f32_16x16x32_f16(ah[mi], bh[ni], acc[mi][ni], 0, 0, 0);
                    acc[mi][ni] = __builtin_amdgcn_mfma_f32_16x16x32_f16(ah[mi], bl[ni], acc[mi][ni], 0, 0, 0);
                    acc[mi][ni] = __builtin_amdgcn_mfma_f32_16x16x32_f16(al[mi], bh[ni], acc[mi][ni], 0, 0, 0);
                }
            __syncthreads();
        }
    }

    int rbase = lk8 * 4;
    #pragma unroll
    for (int mi = 0; mi < 4; ++mi){
        #pragma unroll
        for (int ni = 0; ni < 4; ++ni){
            int gn = n0 + wc*64 + ni*16 + lr;
            if (gn >= Ncols) continue;
            #pragma unroll
            for (int rg = 0; rg < 4; ++rg){
                int gm = m0 + wr*64 + mi*16 + rbase + rg;
                float v = acc[mi][ni][rg] * INV_SCALE;
                if (EPI == 0){
                    ushort h, l;
                    splitf16(v, h, l);
                    OutHi[(size_t)gm*ldc + gn] = h;
                    OutLo[(size_t)gm*ldc + gn] = l;
                } else if (EPI == 1){
                    v += bias[gn];
                    OutF[(size_t)gm*ldo + gn] = 1.f/(1.f + expf(-v));
                } else {
                    float hc = tanhf(v + bias[gn]);
                    float rr = zrf[(size_t)gm*ldo + Hd + gn];
                    float ho = hbuf[(size_t)gm*Hd + gn];
                    hbuf[(size_t)gm*Hd + gn] = rr*ho + (1.f-rr)*hc;
                }
            }
        }
    }
}

// ---------------------------------------------------------------------------
// encoder cat builders (r8-verified)
// ---------------------------------------------------------------------------
__global__ void build_enc1_split(const float* __restrict__ x, const float* __restrict__ h,
                                 ushort* __restrict__ chi, ushort* __restrict__ clo, int t)
{
    size_t idx = (size_t)blockIdx.x*256 + threadIdx.x;      // N*B*CPe
    int c = (int)(idx % CPe); size_t rb = idx / CPe;
    int n = (int)(rb >> 6), b = (int)(rb & 63);
    float v;
    if (c == 0)        v = x[((size_t)b*Tt + t)*Nn + n];
    else if (c < 129)  v = h[rb*Hh + (c-1)];
    else               v = 0.f;
    splitf16(v*16.f, chi[idx], clo[idx]);
}

__global__ void build_enc2_split(const float* __restrict__ x, const float* __restrict__ h,
                                 const float* __restrict__ zre,
                                 ushort* __restrict__ chi, ushort* __restrict__ clo, int t)
{
    size_t idx = (size_t)blockIdx.x*256 + threadIdx.x;
    int c = (int)(idx % CPe); size_t rb = idx / CPe;
    int n = (int)(rb >> 6), b = (int)(rb & 63);
    float v;
    if (c == 0)        v = x[((size_t)b*Tt + t)*Nn + n];
    else if (c < 129)  v = zre[rb*ZRE + (c-1)] * h[rb*Hh + (c-1)];
    else               v = 0.f;
    splitf16(v*16.f, chi[idx], clo[idx]);
}

// ---------------------------------------------------------------------------
// decoder bf16 MFMA GEMM (r7-verified math; A via global_load_lds)
// ---------------------------------------------------------------------------
template<int EPI>
__global__ __launch_bounds__(256) void mfma_gemm(
    const ushort* __restrict__ A0, const ushort* __restrict__ A1, const ushort* __restrict__ A2,
    const ushort* __restrict__ B0, const ushort* __restrict__ B1, const ushort* __restrict__ B2,
    int nmat, int Ksz, int lda, int ldb,
    bf16* __restrict__ Cout, int ldc, int Ncols,
    const float* __restrict__ bias,
    const bf16* __restrict__ zr, float* __restrict__ hbuf, int Hd)
{
    __shared__ short As[128*32];
    __shared__ short Bs[128*32];
    int tid = threadIdx.x;
    int m0 = blockIdx.y * 128;
    int n0 = blockIdx.x * 128;
    int wave = tid >> 6, lane = tid & 63;
    int wr = wave >> 1, wc = wave & 1;
    int lr = lane & 15, lk8 = lane >> 4;

    f32x4 acc[4][4];
    #pragma unroll
    for (int i = 0; i < 4; ++i)
        #pragma unroll
        for (int j = 0; j < 4; ++j) acc[i][j] = (f32x4){0.f,0.f,0.f,0.f};

    const ushort* Aps[3] = {A0, A1, A2};
    const ushort* Bps[3] = {B0, B1, B2};

    int bkp = tid & 15;
    int bcc = tid >> 4;
    int wbase = wave * 1024;

    for (int km = 0; km < nmat; ++km){
        const ushort* Ag = Aps[km];
        const ushort* Bg = Bps[km];
        for (int k0 = 0; k0 < Ksz; k0 += 32){
            #pragma unroll
            for (int r = 0; r < 2; ++r){
                int i = tid + r*256;
                int row = i >> 2, q = i & 3;
                int sq = q ^ (row & 3);
                size_t so = (size_t)(m0+row)*lda + k0 + sq*8;
                GLOAD_LDS16(Ag + so, (char*)As + r*4096 + wbase);
            }
            {
                int kk = k0 + bkp*2;
                const ushort* s1 = Bg + (size_t)kk*ldb + n0 + bcc*8;
                const ushort* s2 = s1 + ldb;
                int4v v1 = *(const int4v*)s1;
                int4v v2 = *(const int4v*)s2;
                const ushort* g1 = (const ushort*)&v1;
                const ushort* g2 = (const ushort*)&v2;
                #pragma unroll
                for (int e = 0; e < 8; ++e){
                    int col = bcc*8 + e;
                    unsigned pv = (unsigned)g1[e] | ((unsigned)g2[e] << 16);
                    int kc = (bkp >> 2) ^ (col & 3);
                    int dst = col*64 + kc*16 + (bkp & 3)*4;
                    *(unsigned*)((char*)Bs + dst) = pv;
                }
            }
            __syncthreads();
            short8 af[4], bfv[4];
            #pragma unroll
            for (int mi = 0; mi < 4; ++mi){
                int row = wr*64 + mi*16 + lr;
                int off = row*64 + ((lk8 ^ (row & 3)) << 4);
                af[mi] = *(const short8*)((const char*)As + off);
            }
            #pragma unroll
            for (int ni = 0; ni < 4; ++ni){
                int col = wc*64 + ni*16 + lr;
                int off = col*64 + ((lk8 ^ (col & 3)) << 4);
                bfv[ni] = *(const short8*)((const char*)Bs + off);
            }
            #pragma unroll
            for (int mi = 0; mi < 4; ++mi)
                #pragma unroll
                for (int ni = 0; ni < 4; ++ni)
                    acc[mi][ni] = __builtin_amdgcn_mfma_f32_16x16x32_bf16(
                                      af[mi], bfv[ni], acc[mi][ni], 0, 0, 0);
            __syncthreads();
        }
    }

    int rbase = lk8 * 4;
    #pragma unroll
    for (int mi = 0; mi < 4; ++mi){
        #pragma unroll
        for (int ni = 0; ni < 4; ++ni){
            int gn = n0 + wc*64 + ni*16 + lr;
            if (gn >= Ncols) continue;
            #pragma unroll
            for (int rg = 0; rg < 4; ++rg){
                int gm = m0 + wr*64 + mi*16 + rbase + rg;
                float v = acc[mi][ni][rg];
                if (EPI == 0){
                    Cout[(size_t)gm*ldc + gn] = f2b(v);
                } else if (EPI == 1){
                    v += bias[gn];
                    Cout[(size_t)gm*ldc + gn] = f2b(1.f/(1.f + expf(-v)));
                } else {
                    float hc = tanhf(v + bias[gn]);
                    float rr = b2f(zr[(size_t)gm*LDZR + Hd + gn]);
                    float ho = hbuf[(size_t)gm*Hd + gn];
                    hbuf[(size_t)gm*Hd + gn] = rr*ho + (1.f-rr)*hc;
                }
            }
        }
    }
}

// ---------------------------------------------------------------------------
// decoder cat builders (r7-verified)
// ---------------------------------------------------------------------------
__global__ void build_dec1(const float* __restrict__ go, const float* __restrict__ yc,
                           const float* __restrict__ h, bf16* __restrict__ cat0, int t)
{
    size_t idx = (size_t)blockIdx.x*256 + threadIdx.x;      // N*B*CPd
    int c = (int)(idx % CPd); size_t rb = idx / CPd;
    int n = (int)(rb >> 6), b = (int)(rb & 63);
    float v;
    if (c == 0)        v = go[rb];
    else if (c == 1)   v = yc[((size_t)b*HORt + t)*Nn + n];
    else if (c < 194)  v = h[rb*DECHd + (c-2)];
    else               v = 0.f;
    cat0[idx] = f2b(v);
}

__global__ void build_dec2(const float* __restrict__ go, const float* __restrict__ yc,
                           const float* __restrict__ h, const bf16* __restrict__ zr,
                           bf16* __restrict__ cat0, int t)
{
    size_t idx = (size_t)blockIdx.x*256 + threadIdx.x;
    int c = (int)(idx % CPd); size_t rb = idx / CPd;
    int n = (int)(rb >> 6), b = (int)(rb & 63);
    float v;
    if (c == 0)        v = go[rb];
    else if (c == 1)   v = yc[((size_t)b*HORt + t)*Nn + n];
    else if (c < 194)  v = b2f(zr[rb*LDZR + (c-2)]) * h[rb*DECHd + (c-2)];
    else               v = 0.f;
    cat0[idx] = f2b(v);
}

// ---------------------------------------------------------------------------
// attention (fp32, verified)
// ---------------------------------------------------------------------------
__global__ __launch_bounds__(64) void attn_kernel(const float* __restrict__ hT,
                                                  const float* __restrict__ Wq,
                                                  const float* __restrict__ Mem,
                                                  float* __restrict__ hdec,
                                                  int* __restrict__ ind0,
                                                  float* __restrict__ outv,
                                                  float* __restrict__ outq,
                                                  float* __restrict__ outp)
{
    int rb = blockIdx.x; int n = rb / Bb, b = rb % Bb;
    int tid = threadIdx.x;
    __shared__ float hl[Hh];
    __shared__ float ql[MDd];
    __shared__ float sm[Mm];
    __shared__ float stats[2];
    __shared__ int   smind;
    hl[tid]      = hT[(size_t)rb*Hh + tid];
    hl[tid + 64] = hT[(size_t)rb*Hh + tid + 64];
    __syncthreads();
    float q = 0.f;
    for (int hh = 0; hh < Hh; ++hh) q += hl[hh]*Wq[hh*MDd + tid];
    ql[tid] = q;
    size_t bn = (size_t)b*Nn + n;
    outq[bn*MDd + tid] = q;
    __syncthreads();
    if (tid < Mm){
        float s = 0.f;
        for (int d = 0; d < MDd; ++d) s += ql[d]*Mem[tid*MDd + d];
        sm[tid] = s;
    }
    __syncthreads();
    if (tid == 0){
        float mx = -1e30f; int am = 0;
        for (int m = 0; m < Mm; ++m) if (sm[m] > mx){ mx = sm[m]; am = m; }
        float ssum = 0.f;
        for (int m = 0; m < Mm; ++m){ float e = expf(sm[m]-mx); sm[m] = e; ssum += e; }
        stats[0] = 1.f/ssum; smind = am;
    }
    __syncthreads();
    float inv = stats[0]; int am = smind;
    float val = 0.f;
    for (int m = 0; m < Mm; ++m) val += sm[m]*inv*Mem[m*MDd + tid];
    outv[bn*MDd + tid] = val;
    outp[bn*MDd + tid] = Mem[am*MDd + tid];
    hdec[(size_t)rb*DECHd + tid]       = hl[tid];
    hdec[(size_t)rb*DECHd + 64 + tid]  = hl[tid + 64];
    hdec[(size_t)rb*DECHd + 128 + tid] = val;
    if (tid == 0) ind0[rb] = am;
}

__global__ void neg_kernel(const float* __restrict__ Mem, float* __restrict__ outn)
{
    size_t idx = (size_t)blockIdx.x*256 + threadIdx.x;
    outn[idx] = Mem[idx % (Mm*MDd)];
}

__global__ void mask_kernel(const int* __restrict__ ind0, float* __restrict__ outm)
{
    size_t idx = (size_t)blockIdx.x*256 + threadIdx.x;
    int m   = (int)(idx % Mm);
    size_t bn = idx / Mm;
    int n = (int)(bn % Nn);
    int b = (int)(bn / Nn);
    int rb = n*Bb + b;
    outm[idx] = (m != ind0[rb]) ? 1.f : 0.f;
}

__global__ __launch_bounds__(256) void proj_kernel(const float* __restrict__ h,
                                                   const float* __restrict__ pw,
                                                   const float* __restrict__ pb,
                                                   float* __restrict__ go,
                                                   float* __restrict__ out0, int t)
{
    int rb = blockIdx.x*4 + (threadIdx.x >> 6);
    int lane = threadIdx.x & 63;
    float s = 0.f;
    #pragma unroll
    for (int r = 0; r < 3; ++r){
        int i = lane + r*64;
        s += h[(size_t)rb*DECHd + i]*pw[i];
    }
    #pragma unroll
    for (int off = 32; off > 0; off >>= 1) s += __shfl_down(s, off, 64);
    if (lane == 0){
        float v = s + pb[0];
        go[rb] = v;
        int n = rb / Bb, b = rb % Bb;
        out0[((size_t)b*HORt + t)*Nn + n] = v;
    }
}

// ---------------------------------------------------------------------------
extern "C" void kernel_launch(void* const* d_in, const int* in_sizes, int n_in,
                              void* d_out, int out_size, void* d_ws, size_t ws_size,
                              hipStream_t stream)
{
    const float* x    = (const float*)d_in[0];
    const float* ycov = (const float*)d_in[1];
    const float* emb  = (const float*)d_in[2];
    const float* Mem  = (const float*)d_in[3];
    const float* Wq   = (const float*)d_in[4];
    const float* eWg  = (const float*)d_in[5];
    const float* ebg  = (const float*)d_in[6];
    const float* eWu  = (const float*)d_in[7];
    const float* ebu  = (const float*)d_in[8];
    const float* dWg  = (const float*)d_in[9];
    const float* dbg  = (const float*)d_in[10];
    const float* dWu  = (const float*)d_in[11];
    const float* dbu  = (const float*)d_in[12];
    const float* pW   = (const float*)d_in[13];
    const float* pb   = (const float*)d_in[14];

    float* out        = (float*)d_out;
    float* out_output = out;
    float* out_value  = out + 786432;
    float* out_query  = out + 4980736;
    float* out_pos    = out + 9175040;
    float* out_neg    = out + 13369344;          // 83,886,080 floats
    float* out_mask   = out + 97255424;

    // determinism hammer (r7-verified): identical state every call
    hipMemsetAsync(d_out, 0, (size_t)out_size * 4, stream);

    // ---- out_neg scratch, time-shared ----
    ushort* catEh = (ushort*)out_neg;                        // 31,457,280 halves
    ushort* catEl = catEh + 31457280;
    float*  zrE   = (float*)(catEl + 31457280);              // 16,777,216 fp32
    bf16*  cat0 = (bf16*)out_neg;
    bf16*  cat1 = cat0 + 14680064;
    bf16*  cat2 = cat1 + 14680064;
    bf16*  zrb  = cat2 + 14680064;

    // ---- d_ws layout (~107 MB; ws >= 173 MB, r3). Sh/T2h (and Sl/T2l,
    //      Sb/T2b) are CONTIGUOUS so [S;T2] stacks as one 2048-row A. ----
    const size_t NEED = 106979328;
    if (ws_size < NEED){
        ws_probe_kernel<<<3072, 256, 0, stream>>>(out_output, (float)(ws_size >> 20));
        return;
    }
    float*  Sf   = (float*)d_ws;                 // 1,048,576 f32
    float*  T2f  = Sf + 1048576;                 // 1,048,576 f32
    ushort* Sh   = (ushort*)(T2f + 1048576);     // [Sh|T2h] stacked hi
    ushort* T2h  = Sh  + 1048576;
    ushort* Sl   = T2h + 1048576;                // [Sl|T2l] stacked lo
    ushort* T2l  = Sl  + 1048576;
    bf16*   Sb   = (bf16*)(T2l + 1048576);       // [Sb|T2b] stacked bf16
    bf16*   T2b  = Sb + 1048576;
    ushort* wgEh = (ushort*)(T2b + 1048576);     // 3*160*256 = 122,880
    ushort* wgEl = wgEh + 122880;
    ushort* wuEh = wgEl + 122880;                // 3*160*128 = 61,440
    ushort* wuEl = wuEh + 61440;
    bf16*   wgD  = (bf16*)(wuEl + 61440);        // 3*224*384 = 258,048
    bf16*   wuD  = wgD + 258048;                 // 3*224*256 = 172,032
    float*  henc = (float*)(wuD + 172032);       // 8,388,608 f32
    float*  hdec = henc + 8388608;               // 12,582,912 f32
    float*  go   = hdec + 12582912;              // 65,536 f32
    int*    ind0 = (int*)(go + 65536);           // 65,536 int

    hipMemsetAsync(henc, 0, (size_t)8388608*4, stream);
    hipMemsetAsync(go,   0, (size_t)65536*4,   stream);

    supports_kernel<<<Nn, 256, 0, stream>>>(emb, Sf);
    t2_gemm<<<dim3(16,16), 256, 0, stream>>>(Sf, T2f);
    conv_split<<<4096, 256, 0, stream>>>(Sf,  Sh,  Sl,  4096.f);
    conv_split<<<4096, 256, 0, stream>>>(T2f, T2h, T2l, 4096.f);
    conv_f2b<<<4096, 256, 0, stream>>>(Sf,  Sb);
    conv_f2b<<<4096, 256, 0, stream>>>(T2f, T2b);
    conv_w_split<<<480, 256, 0, stream>>>(eWg, wgEh, wgEl, 129, CPe, 256);
    conv_w_split<<<240, 256, 0, stream>>>(eWu, wuEh, wuEl, 129, CPe, 128);
    conv_w<<<1008, 256, 0, stream>>>(dWg, wgD, 194, CPd, 384, 384);
    conv_w<<<672,  256, 0, stream>>>(dWu, wuD, 194, CPd, 192, 256);

    const size_t SL = (size_t)65536*CPe;         // 10,485,760 = 1024*JPe (contig!)

    // -------- encoder: 12 steps, split-fp16 MFMA; stacked [S;T2] GCN --------
    for (int t = 0; t < Tt; ++t){
        build_enc1_split<<<40960, 256, 0, stream>>>(x, henc, catEh, catEl, t);
        mfma_split<0><<<dim3(JPe/128, 16), 256, 0, stream>>>(
            Sh, Sl, nullptr, nullptr, nullptr, nullptr,
            catEh, catEl, nullptr, nullptr, nullptr, nullptr,
            1, Nn, Nn, JPe,
            catEh + SL, catEl + SL, JPe, JPe, nullptr, 0, nullptr, nullptr, nullptr, 0);
        mfma_split<1><<<dim3(2, 512), 256, 0, stream>>>(
            catEh, catEl, catEh + SL, catEl + SL, catEh + 2*SL, catEl + 2*SL,
            wgEh, wgEl, wgEh + CPe*256, wgEl + CPe*256, wgEh + 2*CPe*256, wgEl + 2*CPe*256,
            3, CPe, CPe, 256,
            nullptr, nullptr, 0, 256, zrE, ZRE, ebg, nullptr, nullptr, 0);
        build_enc2_split<<<40960, 256, 0, stream>>>(x, henc, zrE, catEh, catEl, t);
        mfma_split<0><<<dim3(JPe/128, 16), 256, 0, stream>>>(
            Sh, Sl, nullptr, nullptr, nullptr, nullptr,
            catEh, catEl, nullptr, nullptr, nullptr, nullptr,
            1, Nn, Nn, JPe,
            catEh + SL, catEl + SL, JPe, JPe, nullptr, 0, nullptr, nullptr, nullptr, 0);
        mfma_split<2><<<dim3(1, 512), 256, 0, stream>>>(
            catEh, catEl, catEh + SL, catEl + SL, catEh + 2*SL, catEl + 2*SL,
            wuEh, wuEl, wuEh + CPe*128, wuEl + CPe*128, wuEh + 2*CPe*128, wuEl + 2*CPe*128,
            3, CPe, CPe, 128,
            nullptr, nullptr, 0, 128, nullptr, ZRE, ebu, zrE, henc, 128);
    }

    // -------- attention (fp32 scores -> exact argmax) --------
    attn_kernel<<<65536, 64, 0, stream>>>(henc, Wq, Mem, hdec, ind0,
                                          out_value, out_query, out_pos);

    const ushort* Su  = (const ushort*)Sb;       // stacked [Sb|T2b]
    const ushort* c0u = (const ushort*)cat0;
    const ushort* c1u = (const ushort*)cat1;
    const ushort* c2u = (const ushort*)cat2;

    // -------- decoder: 12 steps, bf16 MFMA; stacked [S;T2] GCN --------
    for (int t = 0; t < HORt; ++t){
        build_dec1<<<57344, 256, 0, stream>>>(go, ycov, hdec, cat0, t);
        mfma_gemm<0><<<dim3(JPd/128, 16), 256, 0, stream>>>(
            Su, nullptr, nullptr, c0u, nullptr, nullptr, 1, 1024, 1024, JPd,
            cat1, JPd, JPd, nullptr, nullptr, nullptr, 0);
        mfma_gemm<1><<<dim3(3, 512), 256, 0, stream>>>(
            c0u, c1u, c2u,
            (const ushort*)wgD, (const ushort*)(wgD + CPd*384), (const ushort*)(wgD + 2*CPd*384),
            3, CPd, CPd, 384, zrb, LDZR, 384, dbg, nullptr, nullptr, 0);
        build_dec2<<<57344, 256, 0, stream>>>(go, ycov, hdec, zrb, cat0, t);
        mfma_gemm<0><<<dim3(JPd/128, 16), 256, 0, stream>>>(
            Su, nullptr, nullptr, c0u, nullptr, nullptr, 1, 1024, 1024, JPd,
            cat1, JPd, JPd, nullptr, nullptr, nullptr, 0);
        mfma_gemm<2><<<dim3(2, 512), 256, 0, stream>>>(
            c0u, c1u, c2u,
            (const ushort*)wuD, (const ushort*)(wuD + CPd*256), (const ushort*)(wuD + 2*CPd*256),
            3, CPd, CPd, 256, nullptr, 0, 192, dbu, zrb, hdec, 192);
        proj_kernel<<<16384, 256, 0, stream>>>(hdec, pW, pb, go, out_output, t);
    }

    // -------- aux outputs LAST --------
    neg_kernel<<<327680, 256, 0, stream>>>(Mem, out_neg);
    mask_kernel<<<5120, 256, 0, stream>>>(ind0, out_mask);
}

// Round 11
// 11325.487 us; speedup vs baseline: 5.8218x; 1.0839x over previous
//
#include <hip/hip_runtime.h>
#include <hip/hip_bf16.h>

typedef __hip_bfloat16 bf16;
typedef __attribute__((ext_vector_type(8))) short short8;
typedef __attribute__((ext_vector_type(8))) _Float16 half8;
typedef __attribute__((ext_vector_type(4))) float f32x4;
typedef __attribute__((ext_vector_type(4))) int   int4v;

#define Bb   64
#define Tt   12
#define Nn   1024
#define HORt 12
#define Hh   128
#define Ee   16
#define Mm   20
#define MDd  64
#define DECHd 192
#define CPe  160               // padded enc cat width (129 -> 160)
#define JPe  (Bb*CPe)          // 10240
#define CPd  224               // padded dec cat width (194 -> 224)
#define JPd  (Bb*CPd)          // 14336
#define LDZR 384               // decoder zr stride (bf16)
#define ZRE  256               // encoder zr stride (fp32)

#define INV_SCALE (1.f/4096.f)

// async global->LDS: wave-uniform LDS base + lane*16; per-lane global src.
#define GLOAD_LDS16(gp, lp) \
    __builtin_amdgcn_global_load_lds((const __attribute__((address_space(1))) void*)(gp), \
                                     (__attribute__((address_space(3))) void*)(lp), 16, 0, 0)

__device__ __forceinline__ float b2f(bf16 v){ return __bfloat162float(v); }
__device__ __forceinline__ bf16  f2b(float v){ return __float2bfloat16(v); }
__device__ __forceinline__ void splitf16(float v, ushort& hi, ushort& lo){
    _Float16 h = (_Float16)v;
    _Float16 l = (_Float16)(v - (float)h);
    hi = __builtin_bit_cast(ushort, h);
    lo = __builtin_bit_cast(ushort, l);
}

// ---------------------------------------------------------------------------
__global__ void ws_probe_kernel(float* __restrict__ out, float val)
{
    size_t i = (size_t)blockIdx.x*256 + threadIdx.x;
    out[i] = val;
}

__global__ void conv_f2b(const float* __restrict__ src, bf16* __restrict__ dst)
{
    size_t i = (size_t)blockIdx.x*256 + threadIdx.x;
    dst[i] = f2b(src[i]);
}

__global__ void conv_split(const float* __restrict__ src, ushort* __restrict__ hi,
                           ushort* __restrict__ lo, float scale)
{
    size_t i = (size_t)blockIdx.x*256 + threadIdx.x;
    splitf16(src[i]*scale, hi[i], lo[i]);
}

// encoder weights TRANSPOSED: fp32 (3*C x No) -> f16 hi/lo [3][No][CP] x256
__global__ void conv_w_split_T(const float* __restrict__ W, ushort* __restrict__ hi,
                               ushort* __restrict__ lo, int C, int CP, int No)
{
    int idx = blockIdx.x*256 + threadIdx.x;
    if (idx >= 3*No*CP) return;
    int km = idx / (No*CP);
    int r  = idx % (No*CP);
    int o  = r / CP, k = r % CP;
    float v = (k < C) ? W[(size_t)(km*C + k)*No + o]*256.f : 0.f;
    splitf16(v, hi[idx], lo[idx]);
}

// decoder weights TRANSPOSED: fp32 (3*C x No) -> bf16 [3][NoP][CP]
__global__ void conv_w_T(const float* __restrict__ W, bf16* __restrict__ dst,
                         int C, int CP, int No, int NoP)
{
    int idx = blockIdx.x*256 + threadIdx.x;
    if (idx >= 3*NoP*CP) return;
    int km = idx / (NoP*CP);
    int r  = idx % (NoP*CP);
    int o  = r / CP, k = r % CP;
    dst[idx] = (k < C && o < No) ? f2b(W[(size_t)(km*C + k)*No + o]) : f2b(0.f);
}

// ---------------------------------------------------------------------------
// tiled transposes [1024][C] -> [C][1024] (ushort payload, bit-agnostic)
// 64x64 tiles, 66-pad (bank-stride 33 dwords == conflict-free)
// ---------------------------------------------------------------------------
__global__ __launch_bounds__(256) void transpose2_u16(const ushort* __restrict__ sa, ushort* __restrict__ da,
                                                      const ushort* __restrict__ sb, ushort* __restrict__ db,
                                                      int C)
{
    __shared__ ushort ta[64][66];
    __shared__ ushort tb[64][66];
    int c0 = blockIdx.x*64, r0 = blockIdx.y*64;
    for (int i = threadIdx.x; i < 4096; i += 256){
        int r = i >> 6, c = i & 63;
        size_t s = (size_t)(r0+r)*C + c0+c;
        ta[r][c] = sa[s];
        tb[r][c] = sb[s];
    }
    __syncthreads();
    for (int i = threadIdx.x; i < 4096; i += 256){
        int c = i >> 6, r = i & 63;
        size_t d = (size_t)(c0+c)*1024 + r0+r;
        da[d] = ta[r][c];
        db[d] = tb[r][c];
    }
}

__global__ __launch_bounds__(256) void transpose_u16(const ushort* __restrict__ s, ushort* __restrict__ d,
                                                     int C)
{
    __shared__ ushort t[64][66];
    int c0 = blockIdx.x*64, r0 = blockIdx.y*64;
    for (int i = threadIdx.x; i < 4096; i += 256){
        int r = i >> 6, c = i & 63;
        t[r][c] = s[(size_t)(r0+r)*C + c0+c];
    }
    __syncthreads();
    for (int i = threadIdx.x; i < 4096; i += 256){
        int c = i >> 6, r = i & 63;
        d[(size_t)(c0+c)*1024 + r0+r] = t[r][c];
    }
}

// ---------------------------------------------------------------------------
// supports = softmax(relu(emb @ emb^T), axis=1)  (fp32, verified)
// ---------------------------------------------------------------------------
__global__ __launch_bounds__(256) void supports_kernel(const float* __restrict__ emb,
                                                       float* __restrict__ S)
{
    int n = blockIdx.x;
    __shared__ float row[Nn];
    __shared__ float en[Ee];
    __shared__ float red[256];
    int tid = threadIdx.x;
    if (tid < Ee) en[tid] = emb[n*Ee + tid];
    __syncthreads();
    float lmax = -1e30f;
    for (int j = tid; j < Nn; j += 256){
        float d = 0.f;
        #pragma unroll
        for (int e = 0; e < Ee; ++e) d += en[e]*emb[j*Ee + e];
        d = d > 0.f ? d : 0.f;
        row[j] = d;
        lmax = fmaxf(lmax, d);
    }
    red[tid] = lmax; __syncthreads();
    for (int s = 128; s > 0; s >>= 1){ if (tid < s) red[tid] = fmaxf(red[tid], red[tid+s]); __syncthreads(); }
    float mx = red[0]; __syncthreads();
    float lsum = 0.f;
    for (int j = tid; j < Nn; j += 256){ float e = expf(row[j]-mx); row[j] = e; lsum += e; }
    red[tid] = lsum; __syncthreads();
    for (int s = 128; s > 0; s >>= 1){ if (tid < s) red[tid] += red[tid+s]; __syncthreads(); }
    float inv = 1.f/red[0];
    for (int j = tid; j < Nn; j += 256) S[n*Nn + j] = row[j]*inv;
}

// ---------------------------------------------------------------------------
// T2 = 2*S@S - I   (fp32, verified)
// ---------------------------------------------------------------------------
__global__ __launch_bounds__(256) void t2_gemm(const float* __restrict__ S,
                                               float* __restrict__ T2)
{
    int n0 = blockIdx.y*64, j0 = blockIdx.x*64;
    __shared__ float As[16][65];
    __shared__ float Xs[16][65];
    int tid = threadIdx.x; int tx = tid & 15, ty = tid >> 4;
    float acc[4][4] = {};
    for (int k0 = 0; k0 < Nn; k0 += 16){
        #pragma unroll
        for (int r = 0; r < 4; ++r){
            int idx = tid + r*256;
            int ar = idx >> 4, ak = idx & 15;
            As[ak][ar] = S[(n0+ar)*Nn + k0+ak];
        }
        #pragma unroll
        for (int r = 0; r < 4; ++r){
            int idx = tid + r*256;
            int xm = idx >> 6, xj = idx & 63;
            Xs[xm][xj] = S[(k0+xm)*Nn + j0+xj];
        }
        __syncthreads();
        #pragma unroll
        for (int kk = 0; kk < 16; ++kk){
            float a[4], xv[4];
            #pragma unroll
            for (int i = 0; i < 4; ++i) a[i]  = As[kk][ty*4+i];
            #pragma unroll
            for (int j = 0; j < 4; ++j) xv[j] = Xs[kk][tx*4+j];
            #pragma unroll
            for (int i = 0; i < 4; ++i)
                #pragma unroll
                for (int j = 0; j < 4; ++j) acc[i][j] += a[i]*xv[j];
        }
        __syncthreads();
    }
    #pragma unroll
    for (int i = 0; i < 4; ++i){
        int n = n0 + ty*4 + i;
        #pragma unroll
        for (int j = 0; j < 4; ++j){
            int c = j0 + tx*4 + j;
            T2[n*Nn + c] = 2.f*acc[i][j] - (n == c ? 1.f : 0.f);
        }
    }
}

// ---------------------------------------------------------------------------
// split-fp16 3-pass MFMA GEMM. BOTH operands via global_load_lds from
// row-contiguous layouts (A: [M][K]; B: B^T = [N][K]); source-side XOR
// swizzle -> LDS content byte-identical to r8/r10's verified layout.
// ---------------------------------------------------------------------------
template<int EPI>
__global__ __launch_bounds__(256) void mfma_split(
    const ushort* __restrict__ Ah0, const ushort* __restrict__ Al0,
    const ushort* __restrict__ Ah1, const ushort* __restrict__ Al1,
    const ushort* __restrict__ Ah2, const ushort* __restrict__ Al2,
    const ushort* __restrict__ BhT0, const ushort* __restrict__ BlT0,
    const ushort* __restrict__ BhT1, const ushort* __restrict__ BlT1,
    const ushort* __restrict__ BhT2, const ushort* __restrict__ BlT2,
    int nmat, int Ksz, int lda, int ldbT,
    ushort* __restrict__ OutHi, ushort* __restrict__ OutLo, int ldc, int Ncols,
    float* __restrict__ OutF, int ldo,
    const float* __restrict__ bias, const float* __restrict__ zrf,
    float* __restrict__ hbuf, int Hd)
{
    __shared__ short Ah_s[128*32];
    __shared__ short Al_s[128*32];
    __shared__ short Bh_s[128*32];
    __shared__ short Bl_s[128*32];
    int tid = threadIdx.x;
    int m0 = blockIdx.y * 128;
    int n0 = blockIdx.x * 128;
    int wave = tid >> 6, lane = tid & 63;
    int wr = wave >> 1, wc = wave & 1;
    int lr = lane & 15, lk8 = lane >> 4;

    f32x4 acc[4][4];
    #pragma unroll
    for (int i = 0; i < 4; ++i)
        #pragma unroll
        for (int j = 0; j < 4; ++j) acc[i][j] = (f32x4){0.f,0.f,0.f,0.f};

    const ushort* Ahs[3] = {Ah0, Ah1, Ah2};
    const ushort* Als[3] = {Al0, Al1, Al2};
    const ushort* Bhs[3] = {BhT0, BhT1, BhT2};
    const ushort* Bls[3] = {BlT0, BlT1, BlT2};

    int wbase = wave * 1024;   // wave-uniform LDS byte base for DMA

    for (int km = 0; km < nmat; ++km){
        const ushort* Agh = Ahs[km]; const ushort* Agl = Als[km];
        const ushort* Bgh = Bhs[km]; const ushort* Bgl = Bls[km];
        for (int k0 = 0; k0 < Ksz; k0 += 32){
            #pragma unroll
            for (int r = 0; r < 2; ++r){
                int i = tid + r*256;
                int row = i >> 2, q = i & 3;
                int sq = q ^ (row & 3);
                size_t soA = (size_t)(m0+row)*lda  + k0 + sq*8;
                size_t soB = (size_t)(n0+row)*ldbT + k0 + sq*8;
                int lofs = r*4096 + wbase;
                GLOAD_LDS16(Agh + soA, (char*)Ah_s + lofs);
                GLOAD_LDS16(Agl + soA, (char*)Al_s + lofs);
                GLOAD_LDS16(Bgh + soB, (char*)Bh_s + lofs);
                GLOAD_LDS16(Bgl + soB, (char*)Bl_s + lofs);
            }
            __syncthreads();
            half8 ah[4], al[4], bh[4], bl[4];
            #pragma unroll
            for (int mi = 0; mi < 4; ++mi){
                int row = wr*64 + mi*16 + lr;
                int off = row*64 + ((lk8 ^ (row & 3)) << 4);
                ah[mi] = *(const half8*)((const char*)Ah_s + off);
                al[mi] = *(const half8*)((const char*)Al_s + off);
            }
            #pragma unroll
            for (int ni = 0; ni < 4; ++ni){
                int col = wc*64 + ni*16 + lr;
                int off = col*64 + ((lk8 ^ (col & 3)) << 4);
                bh[ni] = *(const half8*)((const char*)Bh_s + off);
                bl[ni] = *(const half8*)((const char*)Bl_s + off);
            }
            #pragma unroll
            for (int mi = 0; mi < 4; ++mi)
                #pragma unroll
                for (int ni = 0; ni < 4; ++ni){
                    acc[mi][ni] = __builtin_amdgcn_mfma_f32_16x16x32_f16(ah[mi], bh[ni], acc[mi][ni], 0, 0, 0);
                    acc[mi][ni] = __builtin_amdgcn_mfma_f32_16x16x32_f16(ah[mi], bl[ni], acc[mi][ni], 0, 0, 0);
                    acc[mi][ni] = __builtin_amdgcn_mfma_f32_16x16x32_f16(al[mi], bh[ni], acc[mi][ni], 0, 0, 0);
                }
            __syncthreads();
        }
    }

    int rbase = lk8 * 4;
    #pragma unroll
    for (int mi = 0; mi < 4; ++mi){
        #pragma unroll
        for (int ni = 0; ni < 4; ++ni){
            int gn = n0 + wc*64 + ni*16 + lr;
            if (gn >= Ncols) continue;
            #pragma unroll
            for (int rg = 0; rg < 4; ++rg){
                int gm = m0 + wr*64 + mi*16 + rbase + rg;
                float v = acc[mi][ni][rg] * INV_SCALE;
                if (EPI == 0){
                    ushort h, l;
                    splitf16(v, h, l);
                    OutHi[(size_t)gm*ldc + gn] = h;
                    OutLo[(size_t)gm*ldc + gn] = l;
                } else if (EPI == 1){
                    v += bias[gn];
                    OutF[(size_t)gm*ldo + gn] = 1.f/(1.f + expf(-v));
                } else {
                    float hc = tanhf(v + bias[gn]);
                    float rr = zrf[(size_t)gm*ldo + Hd + gn];
                    float ho = hbuf[(size_t)gm*Hd + gn];
                    hbuf[(size_t)gm*Hd + gn] = rr*ho + (1.f-rr)*hc;
                }
            }
        }
    }
}

// ---------------------------------------------------------------------------
// encoder cat builders (r8-verified)
// ---------------------------------------------------------------------------
__global__ void build_enc1_split(const float* __restrict__ x, const float* __restrict__ h,
                                 ushort* __restrict__ chi, ushort* __restrict__ clo, int t)
{
    size_t idx = (size_t)blockIdx.x*256 + threadIdx.x;      // N*B*CPe
    int c = (int)(idx % CPe); size_t rb = idx / CPe;
    int n = (int)(rb >> 6), b = (int)(rb & 63);
    float v;
    if (c == 0)        v = x[((size_t)b*Tt + t)*Nn + n];
    else if (c < 129)  v = h[rb*Hh + (c-1)];
    else               v = 0.f;
    splitf16(v*16.f, chi[idx], clo[idx]);
}

__global__ void build_enc2_split(const float* __restrict__ x, const float* __restrict__ h,
                                 const float* __restrict__ zre,
                                 ushort* __restrict__ chi, ushort* __restrict__ clo, int t)
{
    size_t idx = (size_t)blockIdx.x*256 + threadIdx.x;
    int c = (int)(idx % CPe); size_t rb = idx / CPe;
    int n = (int)(rb >> 6), b = (int)(rb & 63);
    float v;
    if (c == 0)        v = x[((size_t)b*Tt + t)*Nn + n];
    else if (c < 129)  v = zre[rb*ZRE + (c-1)] * h[rb*Hh + (c-1)];
    else               v = 0.f;
    splitf16(v*16.f, chi[idx], clo[idx]);
}

// ---------------------------------------------------------------------------
// decoder bf16 MFMA GEMM; both operands via global_load_lds (B from B^T)
// ---------------------------------------------------------------------------
template<int EPI>
__global__ __launch_bounds__(256) void mfma_gemm(
    const ushort* __restrict__ A0, const ushort* __restrict__ A1, const ushort* __restrict__ A2,
    const ushort* __restrict__ BT0, const ushort* __restrict__ BT1, const ushort* __restrict__ BT2,
    int nmat, int Ksz, int lda, int ldbT,
    bf16* __restrict__ Cout, int ldc, int Ncols,
    const float* __restrict__ bias,
    const bf16* __restrict__ zr, float* __restrict__ hbuf, int Hd)
{
    __shared__ short As[128*32];
    __shared__ short Bs[128*32];
    int tid = threadIdx.x;
    int m0 = blockIdx.y * 128;
    int n0 = blockIdx.x * 128;
    int wave = tid >> 6, lane = tid & 63;
    int wr = wave >> 1, wc = wave & 1;
    int lr = lane & 15, lk8 = lane >> 4;

    f32x4 acc[4][4];
    #pragma unroll
    for (int i = 0; i < 4; ++i)
        #pragma unroll
        for (int j = 0; j < 4; ++j) acc[i][j] = (f32x4){0.f,0.f,0.f,0.f};

    const ushort* Aps[3] = {A0, A1, A2};
    const ushort* Bps[3] = {BT0, BT1, BT2};

    int wbase = wave * 1024;

    for (int km = 0; km < nmat; ++km){
        const ushort* Ag = Aps[km];
        const ushort* Bg = Bps[km];
        for (int k0 = 0; k0 < Ksz; k0 += 32){
            #pragma unroll
            for (int r = 0; r < 2; ++r){
                int i = tid + r*256;
                int row = i >> 2, q = i & 3;
                int sq = q ^ (row & 3);
                size_t soA = (size_t)(m0+row)*lda  + k0 + sq*8;
                size_t soB = (size_t)(n0+row)*ldbT + k0 + sq*8;
                int lofs = r*4096 + wbase;
                GLOAD_LDS16(Ag + soA, (char*)As + lofs);
                GLOAD_LDS16(Bg + soB, (char*)Bs + lofs);
            }
            __syncthreads();
            short8 af[4], bfv[4];
            #pragma unroll
            for (int mi = 0; mi < 4; ++mi){
                int row = wr*64 + mi*16 + lr;
                int off = row*64 + ((lk8 ^ (row & 3)) << 4);
                af[mi] = *(const short8*)((const char*)As + off);
            }
            #pragma unroll
            for (int ni = 0; ni < 4; ++ni){
                int col = wc*64 + ni*16 + lr;
                int off = col*64 + ((lk8 ^ (col & 3)) << 4);
                bfv[ni] = *(const short8*)((const char*)Bs + off);
            }
            #pragma unroll
            for (int mi = 0; mi < 4; ++mi)
                #pragma unroll
                for (int ni = 0; ni < 4; ++ni)
                    acc[mi][ni] = __builtin_amdgcn_mfma_f32_16x16x32_bf16(
                                      af[mi], bfv[ni], acc[mi][ni], 0, 0, 0);
            __syncthreads();
        }
    }

    int rbase = lk8 * 4;
    #pragma unroll
    for (int mi = 0; mi < 4; ++mi){
        #pragma unroll
        for (int ni = 0; ni < 4; ++ni){
            int gn = n0 + wc*64 + ni*16 + lr;
            if (gn >= Ncols) continue;
            #pragma unroll
            for (int rg = 0; rg < 4; ++rg){
                int gm = m0 + wr*64 + mi*16 + rbase + rg;
                float v = acc[mi][ni][rg];
                if (EPI == 0){
                    Cout[(size_t)gm*ldc + gn] = f2b(v);
                } else if (EPI == 1){
                    v += bias[gn];
                    Cout[(size_t)gm*ldc + gn] = f2b(1.f/(1.f + expf(-v)));
                } else {
                    float hc = tanhf(v + bias[gn]);
                    float rr = b2f(zr[(size_t)gm*LDZR + Hd + gn]);
                    float ho = hbuf[(size_t)gm*Hd + gn];
                    hbuf[(size_t)gm*Hd + gn] = rr*ho + (1.f-rr)*hc;
                }
            }
        }
    }
}

// ---------------------------------------------------------------------------
// decoder cat builders (r7-verified)
// ---------------------------------------------------------------------------
__global__ void build_dec1(const float* __restrict__ go, const float* __restrict__ yc,
                           const float* __restrict__ h, bf16* __restrict__ cat0, int t)
{
    size_t idx = (size_t)blockIdx.x*256 + threadIdx.x;      // N*B*CPd
    int c = (int)(idx % CPd); size_t rb = idx / CPd;
    int n = (int)(rb >> 6), b = (int)(rb & 63);
    float v;
    if (c == 0)        v = go[rb];
    else if (c == 1)   v = yc[((size_t)b*HORt + t)*Nn + n];
    else if (c < 194)  v = h[rb*DECHd + (c-2)];
    else               v = 0.f;
    cat0[idx] = f2b(v);
}

__global__ void build_dec2(const float* __restrict__ go, const float* __restrict__ yc,
                           const float* __restrict__ h, const bf16* __restrict__ zr,
                           bf16* __restrict__ cat0, int t)
{
    size_t idx = (size_t)blockIdx.x*256 + threadIdx.x;
    int c = (int)(idx % CPd); size_t rb = idx / CPd;
    int n = (int)(rb >> 6), b = (int)(rb & 63);
    float v;
    if (c == 0)        v = go[rb];
    else if (c == 1)   v = yc[((size_t)b*HORt + t)*Nn + n];
    else if (c < 194)  v = b2f(zr[rb*LDZR + (c-2)]) * h[rb*DECHd + (c-2)];
    else               v = 0.f;
    cat0[idx] = f2b(v);
}

// ---------------------------------------------------------------------------
// attention (fp32, verified)
// ---------------------------------------------------------------------------
__global__ __launch_bounds__(64) void attn_kernel(const float* __restrict__ hT,
                                                  const float* __restrict__ Wq,
                                                  const float* __restrict__ Mem,
                                                  float* __restrict__ hdec,
                                                  int* __restrict__ ind0,
                                                  float* __restrict__ outv,
                                                  float* __restrict__ outq,
                                                  float* __restrict__ outp)
{
    int rb = blockIdx.x; int n = rb / Bb, b = rb % Bb;
    int tid = threadIdx.x;
    __shared__ float hl[Hh];
    __shared__ float ql[MDd];
    __shared__ float sm[Mm];
    __shared__ float stats[2];
    __shared__ int   smind;
    hl[tid]      = hT[(size_t)rb*Hh + tid];
    hl[tid + 64] = hT[(size_t)rb*Hh + tid + 64];
    __syncthreads();
    float q = 0.f;
    for (int hh = 0; hh < Hh; ++hh) q += hl[hh]*Wq[hh*MDd + tid];
    ql[tid] = q;
    size_t bn = (size_t)b*Nn + n;
    outq[bn*MDd + tid] = q;
    __syncthreads();
    if (tid < Mm){
        float s = 0.f;
        for (int d = 0; d < MDd; ++d) s += ql[d]*Mem[tid*MDd + d];
        sm[tid] = s;
    }
    __syncthreads();
    if (tid == 0){
        float mx = -1e30f; int am = 0;
        for (int m = 0; m < Mm; ++m) if (sm[m] > mx){ mx = sm[m]; am = m; }
        float ssum = 0.f;
        for (int m = 0; m < Mm; ++m){ float e = expf(sm[m]-mx); sm[m] = e; ssum += e; }
        stats[0] = 1.f/ssum; smind = am;
    }
    __syncthreads();
    float inv = stats[0]; int am = smind;
    float val = 0.f;
    for (int m = 0; m < Mm; ++m) val += sm[m]*inv*Mem[m*MDd + tid];
    outv[bn*MDd + tid] = val;
    outp[bn*MDd + tid] = Mem[am*MDd + tid];
    hdec[(size_t)rb*DECHd + tid]       = hl[tid];
    hdec[(size_t)rb*DECHd + 64 + tid]  = hl[tid + 64];
    hdec[(size_t)rb*DECHd + 128 + tid] = val;
    if (tid == 0) ind0[rb] = am;
}

__global__ void neg_kernel(const float* __restrict__ Mem, float* __restrict__ outn)
{
    size_t idx = (size_t)blockIdx.x*256 + threadIdx.x;
    outn[idx] = Mem[idx % (Mm*MDd)];
}

__global__ void mask_kernel(const int* __restrict__ ind0, float* __restrict__ outm)
{
    size_t idx = (size_t)blockIdx.x*256 + threadIdx.x;
    int m   = (int)(idx % Mm);
    size_t bn = idx / Mm;
    int n = (int)(bn % Nn);
    int b = (int)(bn / Nn);
    int rb = n*Bb + b;
    outm[idx] = (m != ind0[rb]) ? 1.f : 0.f;
}

__global__ __launch_bounds__(256) void proj_kernel(const float* __restrict__ h,
                                                   const float* __restrict__ pw,
                                                   const float* __restrict__ pb,
                                                   float* __restrict__ go,
                                                   float* __restrict__ out0, int t)
{
    int rb = blockIdx.x*4 + (threadIdx.x >> 6);
    int lane = threadIdx.x & 63;
    float s = 0.f;
    #pragma unroll
    for (int r = 0; r < 3; ++r){
        int i = lane + r*64;
        s += h[(size_t)rb*DECHd + i]*pw[i];
    }
    #pragma unroll
    for (int off = 32; off > 0; off >>= 1) s += __shfl_down(s, off, 64);
    if (lane == 0){
        float v = s + pb[0];
        go[rb] = v;
        int n = rb / Bb, b = rb % Bb;
        out0[((size_t)b*HORt + t)*Nn + n] = v;
    }
}

// ---------------------------------------------------------------------------
extern "C" void kernel_launch(void* const* d_in, const int* in_sizes, int n_in,
                              void* d_out, int out_size, void* d_ws, size_t ws_size,
                              hipStream_t stream)
{
    const float* x    = (const float*)d_in[0];
    const float* ycov = (const float*)d_in[1];
    const float* emb  = (const float*)d_in[2];
    const float* Mem  = (const float*)d_in[3];
    const float* Wq   = (const float*)d_in[4];
    const float* eWg  = (const float*)d_in[5];
    const float* ebg  = (const float*)d_in[6];
    const float* eWu  = (const float*)d_in[7];
    const float* ebu  = (const float*)d_in[8];
    const float* dWg  = (const float*)d_in[9];
    const float* dbg  = (const float*)d_in[10];
    const float* dWu  = (const float*)d_in[11];
    const float* dbu  = (const float*)d_in[12];
    const float* pW   = (const float*)d_in[13];
    const float* pb   = (const float*)d_in[14];

    float* out        = (float*)d_out;
    float* out_output = out;
    float* out_value  = out + 786432;
    float* out_query  = out + 4980736;
    float* out_pos    = out + 9175040;
    float* out_neg    = out + 13369344;          // 83,886,080 floats (335.5 MB)
    float* out_mask   = out + 97255424;

    // determinism hammer (r7-verified): identical state every call
    hipMemsetAsync(d_out, 0, (size_t)out_size * 4, stream);

    // ---- out_neg scratch, time-shared ----
    // encoder: catEh/catEl (3 slices ea) + catETh/catETl (slice-0 transposed) + zrE
    ushort* catEh  = (ushort*)out_neg;                       // 31,457,280
    ushort* catEl  = catEh + 31457280;                       // 31,457,280
    ushort* catETh = catEl + 31457280;                       // 10,485,760
    ushort* catETl = catETh + 10485760;                      // 10,485,760
    float*  zrE    = (float*)(catETl + 10485760);            // 16,777,216 fp32
    // decoder: cat0/1/2 + cat0T + zrb (bf16)
    bf16*  cat0  = (bf16*)out_neg;                           // 14,680,064
    bf16*  cat1  = cat0 + 14680064;
    bf16*  cat2  = cat1 + 14680064;
    bf16*  cat0T = cat2 + 14680064;                          // 14,680,064
    bf16*  zrb   = cat0T + 14680064;                         // 25,165,824

    // ---- d_ws layout (~107 MB; ws >= 173 MB, r3). Sh/T2h (and Sl/T2l,
    //      Sb/T2b) CONTIGUOUS so [S;T2] stacks as one 2048-row A. Weights
    //      are stored TRANSPOSED ([3][No][CP]) for B^T gload_lds staging. ----
    const size_t NEED = 106979328;
    if (ws_size < NEED){
        ws_probe_kernel<<<3072, 256, 0, stream>>>(out_output, (float)(ws_size >> 20));
        return;
    }
    float*  Sf    = (float*)d_ws;                // 1,048,576 f32
    float*  T2f   = Sf + 1048576;                // 1,048,576 f32
    ushort* Sh    = (ushort*)(T2f + 1048576);    // [Sh|T2h] stacked hi
    ushort* T2h   = Sh  + 1048576;
    ushort* Sl    = T2h + 1048576;               // [Sl|T2l] stacked lo
    ushort* T2l   = Sl  + 1048576;
    bf16*   Sb    = (bf16*)(T2l + 1048576);      // [Sb|T2b] stacked bf16
    bf16*   T2b   = Sb + 1048576;
    ushort* wgETh = (ushort*)(T2b + 1048576);    // 3*256*160 = 122,880
    ushort* wgETl = wgETh + 122880;
    ushort* wuETh = wgETl + 122880;              // 3*128*160 = 61,440
    ushort* wuETl = wuETh + 61440;
    bf16*   wgDT  = (bf16*)(wuETl + 61440);      // 3*384*224 = 258,048
    bf16*   wuDT  = wgDT + 258048;               // 3*256*224 = 172,032
    float*  henc  = (float*)(wuDT + 172032);     // 8,388,608 f32
    float*  hdec  = henc + 8388608;              // 12,582,912 f32
    float*  go    = hdec + 12582912;             // 65,536 f32
    int*    ind0  = (int*)(go + 65536);          // 65,536 int

    hipMemsetAsync(henc, 0, (size_t)8388608*4, stream);
    hipMemsetAsync(go,   0, (size_t)65536*4,   stream);

    supports_kernel<<<Nn, 256, 0, stream>>>(emb, Sf);
    t2_gemm<<<dim3(16,16), 256, 0, stream>>>(Sf, T2f);
    conv_split<<<4096, 256, 0, stream>>>(Sf,  Sh,  Sl,  4096.f);
    conv_split<<<4096, 256, 0, stream>>>(T2f, T2h, T2l, 4096.f);
    conv_f2b<<<4096, 256, 0, stream>>>(Sf,  Sb);
    conv_f2b<<<4096, 256, 0, stream>>>(T2f, T2b);
    conv_w_split_T<<<480, 256, 0, stream>>>(eWg, wgETh, wgETl, 129, CPe, 256);
    conv_w_split_T<<<240, 256, 0, stream>>>(eWu, wuETh, wuETl, 129, CPe, 128);
    conv_w_T<<<1008, 256, 0, stream>>>(dWg, wgDT, 194, CPd, 384, 384);
    conv_w_T<<<672,  256, 0, stream>>>(dWu, wuDT, 194, CPd, 192, 256);

    const size_t SL = (size_t)65536*CPe;         // 10,485,760 = 1024*JPe (contig!)

    // -------- encoder: 12 steps, split-fp16 MFMA; stacked [S;T2] GCN --------
    for (int t = 0; t < Tt; ++t){
        build_enc1_split<<<40960, 256, 0, stream>>>(x, henc, catEh, catEl, t);
        transpose2_u16<<<dim3(JPe/64, 16), 256, 0, stream>>>(catEh, catETh, catEl, catETl, JPe);
        mfma_split<0><<<dim3(JPe/128, 16), 256, 0, stream>>>(
            Sh, Sl, nullptr, nullptr, nullptr, nullptr,
            catETh, catETl, nullptr, nullptr, nullptr, nullptr,
            1, Nn, Nn, Nn,
            catEh + SL, catEl + SL, JPe, JPe, nullptr, 0, nullptr, nullptr, nullptr, 0);
        mfma_split<1><<<dim3(2, 512), 256, 0, stream>>>(
            catEh, catEl, catEh + SL, catEl + SL, catEh + 2*SL, catEl + 2*SL,
            wgETh, wgETl, wgETh + 40960, wgETl + 40960, wgETh + 81920, wgETl + 81920,
            3, CPe, CPe, CPe,
            nullptr, nullptr, 0, 256, zrE, ZRE, ebg, nullptr, nullptr, 0);
        build_enc2_split<<<40960, 256, 0, stream>>>(x, henc, zrE, catEh, catEl, t);
        transpose2_u16<<<dim3(JPe/64, 16), 256, 0, stream>>>(catEh, catETh, catEl, catETl, JPe);
        mfma_split<0><<<dim3(JPe/128, 16), 256, 0, stream>>>(
            Sh, Sl, nullptr, nullptr, nullptr, nullptr,
            catETh, catETl, nullptr, nullptr, nullptr, nullptr,
            1, Nn, Nn, Nn,
            catEh + SL, catEl + SL, JPe, JPe, nullptr, 0, nullptr, nullptr, nullptr, 0);
        mfma_split<2><<<dim3(1, 512), 256, 0, stream>>>(
            catEh, catEl, catEh + SL, catEl + SL, catEh + 2*SL, catEl + 2*SL,
            wuETh, wuETl, wuETh + 20480, wuETl + 20480, wuETh + 40960, wuETl + 40960,
            3, CPe, CPe, CPe,
            nullptr, nullptr, 0, 128, nullptr, ZRE, ebu, zrE, henc, 128);
    }

    // -------- attention (fp32 scores -> exact argmax) --------
    attn_kernel<<<65536, 64, 0, stream>>>(henc, Wq, Mem, hdec, ind0,
                                          out_value, out_query, out_pos);

    const ushort* Su   = (const ushort*)Sb;      // stacked [Sb|T2b]
    const ushort* c0u  = (const ushort*)cat0;
    const ushort* c1u  = (const ushort*)cat1;
    const ushort* c2u  = (const ushort*)cat2;
    const ushort* c0Tu = (const ushort*)cat0T;

    // -------- decoder: 12 steps, bf16 MFMA; stacked [S;T2] GCN --------
    for (int t = 0; t < HORt; ++t){
        build_dec1<<<57344, 256, 0, stream>>>(go, ycov, hdec, cat0, t);
        transpose_u16<<<dim3(JPd/64, 16), 256, 0, stream>>>(c0u, (ushort*)cat0T, JPd);
        mfma_gemm<0><<<dim3(JPd/128, 16), 256, 0, stream>>>(
            Su, nullptr, nullptr, c0Tu, nullptr, nullptr, 1, 1024, 1024, 1024,
            cat1, JPd, JPd, nullptr, nullptr, nullptr, 0);
        mfma_gemm<1><<<dim3(3, 512), 256, 0, stream>>>(
            c0u, c1u, c2u,
            (const ushort*)wgDT, (const ushort*)(wgDT + 86016), (const ushort*)(wgDT + 172032),
            3, CPd, CPd, CPd, zrb, LDZR, 384, dbg, nullptr, nullptr, 0);
        build_dec2<<<57344, 256, 0, stream>>>(go, ycov, hdec, zrb, cat0, t);
        transpose_u16<<<dim3(JPd/64, 16), 256, 0, stream>>>(c0u, (ushort*)cat0T, JPd);
        mfma_gemm<0><<<dim3(JPd/128, 16), 256, 0, stream>>>(
            Su, nullptr, nullptr, c0Tu, nullptr, nullptr, 1, 1024, 1024, 1024,
            cat1, JPd, JPd, nullptr, nullptr, nullptr, 0);
        mfma_gemm<2><<<dim3(2, 512), 256, 0, stream>>>(
            c0u, c1u, c2u,
            (const ushort*)wuDT, (const ushort*)(wuDT + 57344), (const ushort*)(wuDT + 114688),
            3, CPd, CPd, CPd, nullptr, 0, 192, dbu, zrb, hdec, 192);
        proj_kernel<<<16384, 256, 0, stream>>>(hdec, pW, pb, go, out_output, t);
    }

    // -------- aux outputs LAST --------
    neg_kernel<<<327680, 256, 0, stream>>>(Mem, out_neg);
    mask_kernel<<<5120, 256, 0, stream>>>(ind0, out_mask);
}

// Round 12
// 11288.409 us; speedup vs baseline: 5.8409x; 1.0033x over previous
//
#include <hip/hip_runtime.h>
#include <hip/hip_bf16.h>

typedef __hip_bfloat16 bf16;
typedef __attribute__((ext_vector_type(8))) short short8;
typedef __attribute__((ext_vector_type(8))) _Float16 half8;
typedef __attribute__((ext_vector_type(4))) float f32x4;
typedef __attribute__((ext_vector_type(4))) int   int4v;

#define Bb   64
#define Tt   12
#define Nn   1024
#define HORt 12
#define Hh   128
#define Ee   16
#define Mm   20
#define MDd  64
#define DECHd 192
#define CPe  160               // padded enc cat width (129 -> 160)
#define JPe  (Bb*CPe)          // 10240
#define CPd  224               // padded dec cat width (194 -> 224)
#define JPd  (Bb*CPd)          // 14336
#define LDZR 384               // decoder zr stride (bf16)
#define ZRE  256               // encoder zr stride (fp32)

#define INV_SCALE (1.f/4096.f)

// LDS chunk swizzle: 2-way-max bank pattern (row>>1 based; XOR involution).
// r11 used (row&3): rows {0,4,8,12} per lane-group collided 4-way.
#define SWZ(row) (((row) >> 1) & 3)

// async global->LDS: wave-uniform LDS base + lane*16; per-lane global src.
#define GLOAD_LDS16(gp, lp) \
    __builtin_amdgcn_global_load_lds((const __attribute__((address_space(1))) void*)(gp), \
                                     (__attribute__((address_space(3))) void*)(lp), 16, 0, 0)

__device__ __forceinline__ float b2f(bf16 v){ return __bfloat162float(v); }
__device__ __forceinline__ bf16  f2b(float v){ return __float2bfloat16(v); }
__device__ __forceinline__ void splitf16(float v, ushort& hi, ushort& lo){
    _Float16 h = (_Float16)v;
    _Float16 l = (_Float16)(v - (float)h);
    hi = __builtin_bit_cast(ushort, h);
    lo = __builtin_bit_cast(ushort, l);
}

// ---------------------------------------------------------------------------
__global__ void ws_probe_kernel(float* __restrict__ out, float val)
{
    size_t i = (size_t)blockIdx.x*256 + threadIdx.x;
    out[i] = val;
}

__global__ void conv_f2b(const float* __restrict__ src, bf16* __restrict__ dst)
{
    size_t i = (size_t)blockIdx.x*256 + threadIdx.x;
    dst[i] = f2b(src[i]);
}

__global__ void conv_split(const float* __restrict__ src, ushort* __restrict__ hi,
                           ushort* __restrict__ lo, float scale)
{
    size_t i = (size_t)blockIdx.x*256 + threadIdx.x;
    splitf16(src[i]*scale, hi[i], lo[i]);
}

// encoder weights TRANSPOSED: fp32 (3*C x No) -> f16 hi/lo [3][No][CP] x256
__global__ void conv_w_split_T(const float* __restrict__ W, ushort* __restrict__ hi,
                               ushort* __restrict__ lo, int C, int CP, int No)
{
    int idx = blockIdx.x*256 + threadIdx.x;
    if (idx >= 3*No*CP) return;
    int km = idx / (No*CP);
    int r  = idx % (No*CP);
    int o  = r / CP, k = r % CP;
    float v = (k < C) ? W[(size_t)(km*C + k)*No + o]*256.f : 0.f;
    splitf16(v, hi[idx], lo[idx]);
}

// decoder weights TRANSPOSED: fp32 (3*C x No) -> bf16 [3][NoP][CP]
__global__ void conv_w_T(const float* __restrict__ W, bf16* __restrict__ dst,
                         int C, int CP, int No, int NoP)
{
    int idx = blockIdx.x*256 + threadIdx.x;
    if (idx >= 3*NoP*CP) return;
    int km = idx / (NoP*CP);
    int r  = idx % (NoP*CP);
    int o  = r / CP, k = r % CP;
    dst[idx] = (k < C && o < No) ? f2b(W[(size_t)(km*C + k)*No + o]) : f2b(0.f);
}

// ---------------------------------------------------------------------------
// tiled transposes [1024][C] -> [C][1024] (ushort payload, bit-agnostic)
// ---------------------------------------------------------------------------
__global__ __launch_bounds__(256) void transpose2_u16(const ushort* __restrict__ sa, ushort* __restrict__ da,
                                                      const ushort* __restrict__ sb, ushort* __restrict__ db,
                                                      int C)
{
    __shared__ ushort ta[64][66];
    __shared__ ushort tb[64][66];
    int c0 = blockIdx.x*64, r0 = blockIdx.y*64;
    for (int i = threadIdx.x; i < 4096; i += 256){
        int r = i >> 6, c = i & 63;
        size_t s = (size_t)(r0+r)*C + c0+c;
        ta[r][c] = sa[s];
        tb[r][c] = sb[s];
    }
    __syncthreads();
    for (int i = threadIdx.x; i < 4096; i += 256){
        int c = i >> 6, r = i & 63;
        size_t d = (size_t)(c0+c)*1024 + r0+r;
        da[d] = ta[r][c];
        db[d] = tb[r][c];
    }
}

__global__ __launch_bounds__(256) void transpose_u16(const ushort* __restrict__ s, ushort* __restrict__ d,
                                                     int C)
{
    __shared__ ushort t[64][66];
    int c0 = blockIdx.x*64, r0 = blockIdx.y*64;
    for (int i = threadIdx.x; i < 4096; i += 256){
        int r = i >> 6, c = i & 63;
        t[r][c] = s[(size_t)(r0+r)*C + c0+c];
    }
    __syncthreads();
    for (int i = threadIdx.x; i < 4096; i += 256){
        int c = i >> 6, r = i & 63;
        d[(size_t)(c0+c)*1024 + r0+r] = t[r][c];
    }
}

// ---------------------------------------------------------------------------
// supports = softmax(relu(emb @ emb^T), axis=1)  (fp32, verified)
// ---------------------------------------------------------------------------
__global__ __launch_bounds__(256) void supports_kernel(const float* __restrict__ emb,
                                                       float* __restrict__ S)
{
    int n = blockIdx.x;
    __shared__ float row[Nn];
    __shared__ float en[Ee];
    __shared__ float red[256];
    int tid = threadIdx.x;
    if (tid < Ee) en[tid] = emb[n*Ee + tid];
    __syncthreads();
    float lmax = -1e30f;
    for (int j = tid; j < Nn; j += 256){
        float d = 0.f;
        #pragma unroll
        for (int e = 0; e < Ee; ++e) d += en[e]*emb[j*Ee + e];
        d = d > 0.f ? d : 0.f;
        row[j] = d;
        lmax = fmaxf(lmax, d);
    }
    red[tid] = lmax; __syncthreads();
    for (int s = 128; s > 0; s >>= 1){ if (tid < s) red[tid] = fmaxf(red[tid], red[tid+s]); __syncthreads(); }
    float mx = red[0]; __syncthreads();
    float lsum = 0.f;
    for (int j = tid; j < Nn; j += 256){ float e = expf(row[j]-mx); row[j] = e; lsum += e; }
    red[tid] = lsum; __syncthreads();
    for (int s = 128; s > 0; s >>= 1){ if (tid < s) red[tid] += red[tid+s]; __syncthreads(); }
    float inv = 1.f/red[0];
    for (int j = tid; j < Nn; j += 256) S[n*Nn + j] = row[j]*inv;
}

// ---------------------------------------------------------------------------
// T2 = 2*S@S - I   (fp32, verified)
// ---------------------------------------------------------------------------
__global__ __launch_bounds__(256) void t2_gemm(const float* __restrict__ S,
                                               float* __restrict__ T2)
{
    int n0 = blockIdx.y*64, j0 = blockIdx.x*64;
    __shared__ float As[16][65];
    __shared__ float Xs[16][65];
    int tid = threadIdx.x; int tx = tid & 15, ty = tid >> 4;
    float acc[4][4] = {};
    for (int k0 = 0; k0 < Nn; k0 += 16){
        #pragma unroll
        for (int r = 0; r < 4; ++r){
            int idx = tid + r*256;
            int ar = idx >> 4, ak = idx & 15;
            As[ak][ar] = S[(n0+ar)*Nn + k0+ak];
        }
        #pragma unroll
        for (int r = 0; r < 4; ++r){
            int idx = tid + r*256;
            int xm = idx >> 6, xj = idx & 63;
            Xs[xm][xj] = S[(k0+xm)*Nn + j0+xj];
        }
        __syncthreads();
        #pragma unroll
        for (int kk = 0; kk < 16; ++kk){
            float a[4], xv[4];
            #pragma unroll
            for (int i = 0; i < 4; ++i) a[i]  = As[kk][ty*4+i];
            #pragma unroll
            for (int j = 0; j < 4; ++j) xv[j] = Xs[kk][tx*4+j];
            #pragma unroll
            for (int i = 0; i < 4; ++i)
                #pragma unroll
                for (int j = 0; j < 4; ++j) acc[i][j] += a[i]*xv[j];
        }
        __syncthreads();
    }
    #pragma unroll
    for (int i = 0; i < 4; ++i){
        int n = n0 + ty*4 + i;
        #pragma unroll
        for (int j = 0; j < 4; ++j){
            int c = j0 + tx*4 + j;
            T2[n*Nn + c] = 2.f*acc[i][j] - (n == c ? 1.f : 0.f);
        }
    }
}

// ---------------------------------------------------------------------------
// split-fp16 3-pass MFMA GEMM. Both operands via global_load_lds from
// row-contiguous layouts; source-side SWZ pre-swizzle pairs with SWZ on
// fragment reads (involution) -> math bit-identical to r8/r10/r11.
// ---------------------------------------------------------------------------
template<int EPI>
__global__ __launch_bounds__(256) void mfma_split(
    const ushort* __restrict__ Ah0, const ushort* __restrict__ Al0,
    const ushort* __restrict__ Ah1, const ushort* __restrict__ Al1,
    const ushort* __restrict__ Ah2, const ushort* __restrict__ Al2,
    const ushort* __restrict__ BhT0, const ushort* __restrict__ BlT0,
    const ushort* __restrict__ BhT1, const ushort* __restrict__ BlT1,
    const ushort* __restrict__ BhT2, const ushort* __restrict__ BlT2,
    int nmat, int Ksz, int lda, int ldbT,
    ushort* __restrict__ OutHi, ushort* __restrict__ OutLo, int ldc, int Ncols,
    float* __restrict__ OutF, int ldo,
    const float* __restrict__ bias, const float* __restrict__ zrf,
    float* __restrict__ hbuf, int Hd)
{
    __shared__ short Ah_s[128*32];
    __shared__ short Al_s[128*32];
    __shared__ short Bh_s[128*32];
    __shared__ short Bl_s[128*32];
    int tid = threadIdx.x;
    int m0 = blockIdx.y * 128;
    int n0 = blockIdx.x * 128;
    int wave = tid >> 6, lane = tid & 63;
    int wr = wave >> 1, wc = wave & 1;
    int lr = lane & 15, lk8 = lane >> 4;

    f32x4 acc[4][4];
    #pragma unroll
    for (int i = 0; i < 4; ++i)
        #pragma unroll
        for (int j = 0; j < 4; ++j) acc[i][j] = (f32x4){0.f,0.f,0.f,0.f};

    const ushort* Ahs[3] = {Ah0, Ah1, Ah2};
    const ushort* Als[3] = {Al0, Al1, Al2};
    const ushort* Bhs[3] = {BhT0, BhT1, BhT2};
    const ushort* Bls[3] = {BlT0, BlT1, BlT2};

    int wbase = wave * 1024;   // wave-uniform LDS byte base for DMA

    for (int km = 0; km < nmat; ++km){
        const ushort* Agh = Ahs[km]; const ushort* Agl = Als[km];
        const ushort* Bgh = Bhs[km]; const ushort* Bgl = Bls[km];
        for (int k0 = 0; k0 < Ksz; k0 += 32){
            #pragma unroll
            for (int r = 0; r < 2; ++r){
                int i = tid + r*256;
                int row = i >> 2, q = i & 3;
                int sq = q ^ SWZ(row);
                size_t soA = (size_t)(m0+row)*lda  + k0 + sq*8;
                size_t soB = (size_t)(n0+row)*ldbT + k0 + sq*8;
                int lofs = r*4096 + wbase;
                GLOAD_LDS16(Agh + soA, (char*)Ah_s + lofs);
                GLOAD_LDS16(Agl + soA, (char*)Al_s + lofs);
                GLOAD_LDS16(Bgh + soB, (char*)Bh_s + lofs);
                GLOAD_LDS16(Bgl + soB, (char*)Bl_s + lofs);
            }
            __syncthreads();
            half8 ah[4], al[4], bh[4], bl[4];
            #pragma unroll
            for (int mi = 0; mi < 4; ++mi){
                int row = wr*64 + mi*16 + lr;
                int off = row*64 + ((lk8 ^ SWZ(row)) << 4);
                ah[mi] = *(const half8*)((const char*)Ah_s + off);
                al[mi] = *(const half8*)((const char*)Al_s + off);
            }
            #pragma unroll
            for (int ni = 0; ni < 4; ++ni){
                int col = wc*64 + ni*16 + lr;
                int off = col*64 + ((lk8 ^ SWZ(col)) << 4);
                bh[ni] = *(const half8*)((const char*)Bh_s + off);
                bl[ni] = *(const half8*)((const char*)Bl_s + off);
            }
            #pragma unroll
            for (int mi = 0; mi < 4; ++mi)
                #pragma unroll
                for (int ni = 0; ni < 4; ++ni){
                    acc[mi][ni] = __builtin_amdgcn_mfma_f32_16x16x32_f16(ah[mi], bh[ni], acc[mi][ni], 0, 0, 0);
                    acc[mi][ni] = __builtin_amdgcn_mfma_f32_16x16x32_f16(ah[mi], bl[ni], acc[mi][ni], 0, 0, 0);
                    acc[mi][ni] = __builtin_amdgcn_mfma_f32_16x16x32_f16(al[mi], bh[ni], acc[mi][ni], 0, 0, 0);
                }
            __syncthreads();
        }
    }

    int rbase = lk8 * 4;
    #pragma unroll
    for (int mi = 0; mi < 4; ++mi){
        #pragma unroll
        for (int ni = 0; ni < 4; ++ni){
            int gn = n0 + wc*64 + ni*16 + lr;
            if (gn >= Ncols) continue;
            #pragma unroll
            for (int rg = 0; rg < 4; ++rg){
                int gm = m0 + wr*64 + mi*16 + rbase + rg;
                float v = acc[mi][ni][rg] * INV_SCALE;
                if (EPI == 0){
                    ushort h, l;
                    splitf16(v, h, l);
                    OutHi[(size_t)gm*ldc + gn] = h;
                    OutLo[(size_t)gm*ldc + gn] = l;
                } else if (EPI == 1){
                    v += bias[gn];
                    OutF[(size_t)gm*ldo + gn] = 1.f/(1.f + expf(-v));
                } else {
                    float hc = tanhf(v + bias[gn]);
                    float rr = zrf[(size_t)gm*ldo + Hd + gn];
                    float ho = hbuf[(size_t)gm*Hd + gn];
                    hbuf[(size_t)gm*Hd + gn] = rr*ho + (1.f-rr)*hc;
                }
            }
        }
    }
}

// ---------------------------------------------------------------------------
// encoder cat builders (r8-verified)
// ---------------------------------------------------------------------------
__global__ void build_enc1_split(const float* __restrict__ x, const float* __restrict__ h,
                                 ushort* __restrict__ chi, ushort* __restrict__ clo, int t)
{
    size_t idx = (size_t)blockIdx.x*256 + threadIdx.x;      // N*B*CPe
    int c = (int)(idx % CPe); size_t rb = idx / CPe;
    int n = (int)(rb >> 6), b = (int)(rb & 63);
    float v;
    if (c == 0)        v = x[((size_t)b*Tt + t)*Nn + n];
    else if (c < 129)  v = h[rb*Hh + (c-1)];
    else               v = 0.f;
    splitf16(v*16.f, chi[idx], clo[idx]);
}

__global__ void build_enc2_split(const float* __restrict__ x, const float* __restrict__ h,
                                 const float* __restrict__ zre,
                                 ushort* __restrict__ chi, ushort* __restrict__ clo, int t)
{
    size_t idx = (size_t)blockIdx.x*256 + threadIdx.x;
    int c = (int)(idx % CPe); size_t rb = idx / CPe;
    int n = (int)(rb >> 6), b = (int)(rb & 63);
    float v;
    if (c == 0)        v = x[((size_t)b*Tt + t)*Nn + n];
    else if (c < 129)  v = zre[rb*ZRE + (c-1)] * h[rb*Hh + (c-1)];
    else               v = 0.f;
    splitf16(v*16.f, chi[idx], clo[idx]);
}

// ---------------------------------------------------------------------------
// decoder bf16 MFMA GEMM; both operands via global_load_lds (B from B^T)
// ---------------------------------------------------------------------------
template<int EPI>
__global__ __launch_bounds__(256) void mfma_gemm(
    const ushort* __restrict__ A0, const ushort* __restrict__ A1, const ushort* __restrict__ A2,
    const ushort* __restrict__ BT0, const ushort* __restrict__ BT1, const ushort* __restrict__ BT2,
    int nmat, int Ksz, int lda, int ldbT,
    bf16* __restrict__ Cout, int ldc, int Ncols,
    const float* __restrict__ bias,
    const bf16* __restrict__ zr, float* __restrict__ hbuf, int Hd)
{
    __shared__ short As[128*32];
    __shared__ short Bs[128*32];
    int tid = threadIdx.x;
    int m0 = blockIdx.y * 128;
    int n0 = blockIdx.x * 128;
    int wave = tid >> 6, lane = tid & 63;
    int wr = wave >> 1, wc = wave & 1;
    int lr = lane & 15, lk8 = lane >> 4;

    f32x4 acc[4][4];
    #pragma unroll
    for (int i = 0; i < 4; ++i)
        #pragma unroll
        for (int j = 0; j < 4; ++j) acc[i][j] = (f32x4){0.f,0.f,0.f,0.f};

    const ushort* Aps[3] = {A0, A1, A2};
    const ushort* Bps[3] = {BT0, BT1, BT2};

    int wbase = wave * 1024;

    for (int km = 0; km < nmat; ++km){
        const ushort* Ag = Aps[km];
        const ushort* Bg = Bps[km];
        for (int k0 = 0; k0 < Ksz; k0 += 32){
            #pragma unroll
            for (int r = 0; r < 2; ++r){
                int i = tid + r*256;
                int row = i >> 2, q = i & 3;
                int sq = q ^ SWZ(row);
                size_t soA = (size_t)(m0+row)*lda  + k0 + sq*8;
                size_t soB = (size_t)(n0+row)*ldbT + k0 + sq*8;
                int lofs = r*4096 + wbase;
                GLOAD_LDS16(Ag + soA, (char*)As + lofs);
                GLOAD_LDS16(Bg + soB, (char*)Bs + lofs);
            }
            __syncthreads();
            short8 af[4], bfv[4];
            #pragma unroll
            for (int mi = 0; mi < 4; ++mi){
                int row = wr*64 + mi*16 + lr;
                int off = row*64 + ((lk8 ^ SWZ(row)) << 4);
                af[mi] = *(const short8*)((const char*)As + off);
            }
            #pragma unroll
            for (int ni = 0; ni < 4; ++ni){
                int col = wc*64 + ni*16 + lr;
                int off = col*64 + ((lk8 ^ SWZ(col)) << 4);
                bfv[ni] = *(const short8*)((const char*)Bs + off);
            }
            #pragma unroll
            for (int mi = 0; mi < 4; ++mi)
                #pragma unroll
                for (int ni = 0; ni < 4; ++ni)
                    acc[mi][ni] = __builtin_amdgcn_mfma_f32_16x16x32_bf16(
                                      af[mi], bfv[ni], acc[mi][ni], 0, 0, 0);
            __syncthreads();
        }
    }

    int rbase = lk8 * 4;
    #pragma unroll
    for (int mi = 0; mi < 4; ++mi){
        #pragma unroll
        for (int ni = 0; ni < 4; ++ni){
            int gn = n0 + wc*64 + ni*16 + lr;
            if (gn >= Ncols) continue;
            #pragma unroll
            for (int rg = 0; rg < 4; ++rg){
                int gm = m0 + wr*64 + mi*16 + rbase + rg;
                float v = acc[mi][ni][rg];
                if (EPI == 0){
                    Cout[(size_t)gm*ldc + gn] = f2b(v);
                } else if (EPI == 1){
                    v += bias[gn];
                    Cout[(size_t)gm*ldc + gn] = f2b(1.f/(1.f + expf(-v)));
                } else {
                    float hc = tanhf(v + bias[gn]);
                    float rr = b2f(zr[(size_t)gm*LDZR + Hd + gn]);
                    float ho = hbuf[(size_t)gm*Hd + gn];
                    hbuf[(size_t)gm*Hd + gn] = rr*ho + (1.f-rr)*hc;
                }
            }
        }
    }
}

// ---------------------------------------------------------------------------
// decoder cat builders (r7-verified)
// ---------------------------------------------------------------------------
__global__ void build_dec1(const float* __restrict__ go, const float* __restrict__ yc,
                           const float* __restrict__ h, bf16* __restrict__ cat0, int t)
{
    size_t idx = (size_t)blockIdx.x*256 + threadIdx.x;      // N*B*CPd
    int c = (int)(idx % CPd); size_t rb = idx / CPd;
    int n = (int)(rb >> 6), b = (int)(rb & 63);
    float v;
    if (c == 0)        v = go[rb];
    else if (c == 1)   v = yc[((size_t)b*HORt + t)*Nn + n];
    else if (c < 194)  v = h[rb*DECHd + (c-2)];
    else               v = 0.f;
    cat0[idx] = f2b(v);
}

__global__ void build_dec2(const float* __restrict__ go, const float* __restrict__ yc,
                           const float* __restrict__ h, const bf16* __restrict__ zr,
                           bf16* __restrict__ cat0, int t)
{
    size_t idx = (size_t)blockIdx.x*256 + threadIdx.x;
    int c = (int)(idx % CPd); size_t rb = idx / CPd;
    int n = (int)(rb >> 6), b = (int)(rb & 63);
    float v;
    if (c == 0)        v = go[rb];
    else if (c == 1)   v = yc[((size_t)b*HORt + t)*Nn + n];
    else if (c < 194)  v = b2f(zr[rb*LDZR + (c-2)]) * h[rb*DECHd + (c-2)];
    else               v = 0.f;
    cat0[idx] = f2b(v);
}

// ---------------------------------------------------------------------------
// attention (fp32, verified)
// ---------------------------------------------------------------------------
__global__ __launch_bounds__(64) void attn_kernel(const float* __restrict__ hT,
                                                  const float* __restrict__ Wq,
                                                  const float* __restrict__ Mem,
                                                  float* __restrict__ hdec,
                                                  int* __restrict__ ind0,
                                                  float* __restrict__ outv,
                                                  float* __restrict__ outq,
                                                  float* __restrict__ outp)
{
    int rb = blockIdx.x; int n = rb / Bb, b = rb % Bb;
    int tid = threadIdx.x;
    __shared__ float hl[Hh];
    __shared__ float ql[MDd];
    __shared__ float sm[Mm];
    __shared__ float stats[2];
    __shared__ int   smind;
    hl[tid]      = hT[(size_t)rb*Hh + tid];
    hl[tid + 64] = hT[(size_t)rb*Hh + tid + 64];
    __syncthreads();
    float q = 0.f;
    for (int hh = 0; hh < Hh; ++hh) q += hl[hh]*Wq[hh*MDd + tid];
    ql[tid] = q;
    size_t bn = (size_t)b*Nn + n;
    outq[bn*MDd + tid] = q;
    __syncthreads();
    if (tid < Mm){
        float s = 0.f;
        for (int d = 0; d < MDd; ++d) s += ql[d]*Mem[tid*MDd + d];
        sm[tid] = s;
    }
    __syncthreads();
    if (tid == 0){
        float mx = -1e30f; int am = 0;
        for (int m = 0; m < Mm; ++m) if (sm[m] > mx){ mx = sm[m]; am = m; }
        float ssum = 0.f;
        for (int m = 0; m < Mm; ++m){ float e = expf(sm[m]-mx); sm[m] = e; ssum += e; }
        stats[0] = 1.f/ssum; smind = am;
    }
    __syncthreads();
    float inv = stats[0]; int am = smind;
    float val = 0.f;
    for (int m = 0; m < Mm; ++m) val += sm[m]*inv*Mem[m*MDd + tid];
    outv[bn*MDd + tid] = val;
    outp[bn*MDd + tid] = Mem[am*MDd + tid];
    hdec[(size_t)rb*DECHd + tid]       = hl[tid];
    hdec[(size_t)rb*DECHd + 64 + tid]  = hl[tid + 64];
    hdec[(size_t)rb*DECHd + 128 + tid] = val;
    if (tid == 0) ind0[rb] = am;
}

__global__ void neg_kernel(const float* __restrict__ Mem, float* __restrict__ outn)
{
    size_t idx = (size_t)blockIdx.x*256 + threadIdx.x;
    outn[idx] = Mem[idx % (Mm*MDd)];
}

__global__ void mask_kernel(const int* __restrict__ ind0, float* __restrict__ outm)
{
    size_t idx = (size_t)blockIdx.x*256 + threadIdx.x;
    int m   = (int)(idx % Mm);
    size_t bn = idx / Mm;
    int n = (int)(bn % Nn);
    int b = (int)(bn / Nn);
    int rb = n*Bb + b;
    outm[idx] = (m != ind0[rb]) ? 1.f : 0.f;
}

__global__ __launch_bounds__(256) void proj_kernel(const float* __restrict__ h,
                                                   const float* __restrict__ pw,
                                                   const float* __restrict__ pb,
                                                   float* __restrict__ go,
                                                   float* __restrict__ out0, int t)
{
    int rb = blockIdx.x*4 + (threadIdx.x >> 6);
    int lane = threadIdx.x & 63;
    float s = 0.f;
    #pragma unroll
    for (int r = 0; r < 3; ++r){
        int i = lane + r*64;
        s += h[(size_t)rb*DECHd + i]*pw[i];
    }
    #pragma unroll
    for (int off = 32; off > 0; off >>= 1) s += __shfl_down(s, off, 64);
    if (lane == 0){
        float v = s + pb[0];
        go[rb] = v;
        int n = rb / Bb, b = rb % Bb;
        out0[((size_t)b*HORt + t)*Nn + n] = v;
    }
}

// ---------------------------------------------------------------------------
extern "C" void kernel_launch(void* const* d_in, const int* in_sizes, int n_in,
                              void* d_out, int out_size, void* d_ws, size_t ws_size,
                              hipStream_t stream)
{
    const float* x    = (const float*)d_in[0];
    const float* ycov = (const float*)d_in[1];
    const float* emb  = (const float*)d_in[2];
    const float* Mem  = (const float*)d_in[3];
    const float* Wq   = (const float*)d_in[4];
    const float* eWg  = (const float*)d_in[5];
    const float* ebg  = (const float*)d_in[6];
    const float* eWu  = (const float*)d_in[7];
    const float* ebu  = (const float*)d_in[8];
    const float* dWg  = (const float*)d_in[9];
    const float* dbg  = (const float*)d_in[10];
    const float* dWu  = (const float*)d_in[11];
    const float* dbu  = (const float*)d_in[12];
    const float* pW   = (const float*)d_in[13];
    const float* pb   = (const float*)d_in[14];

    float* out        = (float*)d_out;
    float* out_output = out;
    float* out_value  = out + 786432;
    float* out_query  = out + 4980736;
    float* out_pos    = out + 9175040;
    float* out_neg    = out + 13369344;          // 83,886,080 floats (335.5 MB)
    float* out_mask   = out + 97255424;

    // determinism hammer (r7-verified): identical state every call
    hipMemsetAsync(d_out, 0, (size_t)out_size * 4, stream);

    // ---- out_neg scratch, time-shared ----
    ushort* catEh  = (ushort*)out_neg;                       // 31,457,280
    ushort* catEl  = catEh + 31457280;                       // 31,457,280
    ushort* catETh = catEl + 31457280;                       // 10,485,760
    ushort* catETl = catETh + 10485760;                      // 10,485,760
    float*  zrE    = (float*)(catETl + 10485760);            // 16,777,216 fp32
    bf16*  cat0  = (bf16*)out_neg;                           // 14,680,064
    bf16*  cat1  = cat0 + 14680064;
    bf16*  cat2  = cat1 + 14680064;
    bf16*  cat0T = cat2 + 14680064;                          // 14,680,064
    bf16*  zrb   = cat0T + 14680064;                         // 25,165,824

    // ---- d_ws layout (~107 MB; ws >= 173 MB, r3) ----
    const size_t NEED = 106979328;
    if (ws_size < NEED){
        ws_probe_kernel<<<3072, 256, 0, stream>>>(out_output, (float)(ws_size >> 20));
        return;
    }
    float*  Sf    = (float*)d_ws;                // 1,048,576 f32
    float*  T2f   = Sf + 1048576;                // 1,048,576 f32
    ushort* Sh    = (ushort*)(T2f + 1048576);    // [Sh|T2h] stacked hi
    ushort* T2h   = Sh  + 1048576;
    ushort* Sl    = T2h + 1048576;               // [Sl|T2l] stacked lo
    ushort* T2l   = Sl  + 1048576;
    bf16*   Sb    = (bf16*)(T2l + 1048576);      // [Sb|T2b] stacked bf16
    bf16*   T2b   = Sb + 1048576;
    ushort* wgETh = (ushort*)(T2b + 1048576);    // 3*256*160 = 122,880
    ushort* wgETl = wgETh + 122880;
    ushort* wuETh = wgETl + 122880;              // 3*128*160 = 61,440
    ushort* wuETl = wuETh + 61440;
    bf16*   wgDT  = (bf16*)(wuETl + 61440);      // 3*384*224 = 258,048
    bf16*   wuDT  = wgDT + 258048;               // 3*256*224 = 172,032
    float*  henc  = (float*)(wuDT + 172032);     // 8,388,608 f32
    float*  hdec  = henc + 8388608;              // 12,582,912 f32
    float*  go    = hdec + 12582912;             // 65,536 f32
    int*    ind0  = (int*)(go + 65536);          // 65,536 int

    hipMemsetAsync(henc, 0, (size_t)8388608*4, stream);
    hipMemsetAsync(go,   0, (size_t)65536*4,   stream);

    supports_kernel<<<Nn, 256, 0, stream>>>(emb, Sf);
    t2_gemm<<<dim3(16,16), 256, 0, stream>>>(Sf, T2f);
    conv_split<<<4096, 256, 0, stream>>>(Sf,  Sh,  Sl,  4096.f);
    conv_split<<<4096, 256, 0, stream>>>(T2f, T2h, T2l, 4096.f);
    conv_f2b<<<4096, 256, 0, stream>>>(Sf,  Sb);
    conv_f2b<<<4096, 256, 0, stream>>>(T2f, T2b);
    conv_w_split_T<<<480, 256, 0, stream>>>(eWg, wgETh, wgETl, 129, CPe, 256);
    conv_w_split_T<<<240, 256, 0, stream>>>(eWu, wuETh, wuETl, 129, CPe, 128);
    conv_w_T<<<1008, 256, 0, stream>>>(dWg, wgDT, 194, CPd, 384, 384);
    conv_w_T<<<672,  256, 0, stream>>>(dWu, wuDT, 194, CPd, 192, 256);

    const size_t SL = (size_t)65536*CPe;         // 10,485,760 = 1024*JPe (contig!)

    // -------- encoder: 12 steps, split-fp16 MFMA; stacked [S;T2] GCN --------
    for (int t = 0; t < Tt; ++t){
        build_enc1_split<<<40960, 256, 0, stream>>>(x, henc, catEh, catEl, t);
        transpose2_u16<<<dim3(JPe/64, 16), 256, 0, stream>>>(catEh, catETh, catEl, catETl, JPe);
        mfma_split<0><<<dim3(JPe/128, 16), 256, 0, stream>>>(
            Sh, Sl, nullptr, nullptr, nullptr, nullptr,
            catETh, catETl, nullptr, nullptr, nullptr, nullptr,
            1, Nn, Nn, Nn,
            catEh + SL, catEl + SL, JPe, JPe, nullptr, 0, nullptr, nullptr, nullptr, 0);
        mfma_split<1><<<dim3(2, 512), 256, 0, stream>>>(
            catEh, catEl, catEh + SL, catEl + SL, catEh + 2*SL, catEl + 2*SL,
            wgETh, wgETl, wgETh + 40960, wgETl + 40960, wgETh + 81920, wgETl + 81920,
            3, CPe, CPe, CPe,
            nullptr, nullptr, 0, 256, zrE, ZRE, ebg, nullptr, nullptr, 0);
        build_enc2_split<<<40960, 256, 0, stream>>>(x, henc, zrE, catEh, catEl, t);
        transpose2_u16<<<dim3(JPe/64, 16), 256, 0, stream>>>(catEh, catETh, catEl, catETl, JPe);
        mfma_split<0><<<dim3(JPe/128, 16), 256, 0, stream>>>(
            Sh, Sl, nullptr, nullptr, nullptr, nullptr,
            catETh, catETl, nullptr, nullptr, nullptr, nullptr,
            1, Nn, Nn, Nn,
            catEh + SL, catEl + SL, JPe, JPe, nullptr, 0, nullptr, nullptr, nullptr, 0);
        mfma_split<2><<<dim3(1, 512), 256, 0, stream>>>(
            catEh, catEl, catEh + SL, catEl + SL, catEh + 2*SL, catEl + 2*SL,
            wuETh, wuETl, wuETh + 20480, wuETl + 20480, wuETh + 40960, wuETl + 40960,
            3, CPe, CPe, CPe,
            nullptr, nullptr, 0, 128, nullptr, ZRE, ebu, zrE, henc, 128);
    }

    // -------- attention (fp32 scores -> exact argmax) --------
    attn_kernel<<<65536, 64, 0, stream>>>(henc, Wq, Mem, hdec, ind0,
                                          out_value, out_query, out_pos);

    const ushort* Su   = (const ushort*)Sb;      // stacked [Sb|T2b]
    const ushort* c0u  = (const ushort*)cat0;
    const ushort* c1u  = (const ushort*)cat1;
    const ushort* c2u  = (const ushort*)cat2;
    const ushort* c0Tu = (const ushort*)cat0T;

    // -------- decoder: 12 steps, bf16 MFMA; stacked [S;T2] GCN --------
    for (int t = 0; t < HORt; ++t){
        build_dec1<<<57344, 256, 0, stream>>>(go, ycov, hdec, cat0, t);
        transpose_u16<<<dim3(JPd/64, 16), 256, 0, stream>>>(c0u, (ushort*)cat0T, JPd);
        mfma_gemm<0><<<dim3(JPd/128, 16), 256, 0, stream>>>(
            Su, nullptr, nullptr, c0Tu, nullptr, nullptr, 1, 1024, 1024, 1024,
            cat1, JPd, JPd, nullptr, nullptr, nullptr, 0);
        mfma_gemm<1><<<dim3(3, 512), 256, 0, stream>>>(
            c0u, c1u, c2u,
            (const ushort*)wgDT, (const ushort*)(wgDT + 86016), (const ushort*)(wgDT + 172032),
            3, CPd, CPd, CPd, zrb, LDZR, 384, dbg, nullptr, nullptr, 0);
        build_dec2<<<57344, 256, 0, stream>>>(go, ycov, hdec, zrb, cat0, t);
        transpose_u16<<<dim3(JPd/64, 16), 256, 0, stream>>>(c0u, (ushort*)cat0T, JPd);
        mfma_gemm<0><<<dim3(JPd/128, 16), 256, 0, stream>>>(
            Su, nullptr, nullptr, c0Tu, nullptr, nullptr, 1, 1024, 1024, 1024,
            cat1, JPd, JPd, nullptr, nullptr, nullptr, 0);
        mfma_gemm<2><<<dim3(2, 512), 256, 0, stream>>>(
            c0u, c1u, c2u,
            (const ushort*)wuDT, (const ushort*)(wuDT + 57344), (const ushort*)(wuDT + 114688),
            3, CPd, CPd, CPd, nullptr, 0, 192, dbu, zrb, hdec, 192);
        proj_kernel<<<16384, 256, 0, stream>>>(hdec, pW, pb, go, out_output, t);
    }

    // -------- aux outputs LAST --------
    neg_kernel<<<327680, 256, 0, stream>>>(Mem, out_neg);
    mask_kernel<<<5120, 256, 0, stream>>>(ind0, out_mask);
}

// Round 14
// 10995.549 us; speedup vs baseline: 5.9965x; 1.0266x over previous
//
#include <hip/hip_runtime.h>
#include <hip/hip_bf16.h>

typedef __hip_bfloat16 bf16;
typedef __attribute__((ext_vector_type(8))) short short8;
typedef __attribute__((ext_vector_type(8))) _Float16 half8;
typedef __attribute__((ext_vector_type(4))) float f32x4;
typedef __attribute__((ext_vector_type(4))) int   int4v;

#define Bb   64
#define Tt   12
#define Nn   1024
#define HORt 12
#define Hh   128
#define Ee   16
#define Mm   20
#define MDd  64
#define DECHd 192
#define CPe  160               // padded enc cat width (129 -> 160)
#define JPe  (Bb*CPe)          // 10240
#define CPd  224               // padded dec cat width (194 -> 224)
#define JPd  (Bb*CPd)          // 14336
#define LDZR 384               // decoder zr stride (bf16)
#define ZRE  256               // encoder zr stride (fp32)

#define INV_SCALE (1.f/4096.f)

// LDS chunk swizzle (2-way-max; XOR involution, r12-verified bit-identical)
#define SWZ(row) (((row) >> 1) & 3)

// async global->LDS: wave-uniform LDS base + lane*16; per-lane global src.
#define GLOAD_LDS16(gp, lp) \
    __builtin_amdgcn_global_load_lds((const __attribute__((address_space(1))) void*)(gp), \
                                     (__attribute__((address_space(3))) void*)(lp), 16, 0, 0)

__device__ __forceinline__ float b2f(bf16 v){ return __bfloat162float(v); }
__device__ __forceinline__ bf16  f2b(float v){ return __float2bfloat16(v); }
__device__ __forceinline__ void splitf16(float v, ushort& hi, ushort& lo){
    _Float16 h = (_Float16)v;
    _Float16 l = (_Float16)(v - (float)h);
    hi = __builtin_bit_cast(ushort, h);
    lo = __builtin_bit_cast(ushort, l);
}

// ---------------------------------------------------------------------------
__global__ void ws_probe_kernel(float* __restrict__ out, float val)
{
    size_t i = (size_t)blockIdx.x*256 + threadIdx.x;
    out[i] = val;
}

__global__ void conv_f2b(const float* __restrict__ src, bf16* __restrict__ dst)
{
    size_t i = (size_t)blockIdx.x*256 + threadIdx.x;
    dst[i] = f2b(src[i]);
}

__global__ void conv_split(const float* __restrict__ src, ushort* __restrict__ hi,
                           ushort* __restrict__ lo, float scale)
{
    size_t i = (size_t)blockIdx.x*256 + threadIdx.x;
    splitf16(src[i]*scale, hi[i], lo[i]);
}

// encoder weights TRANSPOSED: fp32 (3*C x No) -> f16 hi/lo [3][No][CP] x256
__global__ void conv_w_split_T(const float* __restrict__ W, ushort* __restrict__ hi,
                               ushort* __restrict__ lo, int C, int CP, int No)
{
    int idx = blockIdx.x*256 + threadIdx.x;
    if (idx >= 3*No*CP) return;
    int km = idx / (No*CP);
    int r  = idx % (No*CP);
    int o  = r / CP, k = r % CP;
    float v = (k < C) ? W[(size_t)(km*C + k)*No + o]*256.f : 0.f;
    splitf16(v, hi[idx], lo[idx]);
}

// decoder weights TRANSPOSED: fp32 (3*C x No) -> bf16 [3][NoP][CP]
__global__ void conv_w_T(const float* __restrict__ W, bf16* __restrict__ dst,
                         int C, int CP, int No, int NoP)
{
    int idx = blockIdx.x*256 + threadIdx.x;
    if (idx >= 3*NoP*CP) return;
    int km = idx / (NoP*CP);
    int r  = idx % (NoP*CP);
    int o  = r / CP, k = r % CP;
    dst[idx] = (k < C && o < No) ? f2b(W[(size_t)(km*C + k)*No + o]) : f2b(0.f);
}

// ---------------------------------------------------------------------------
// supports = softmax(relu(emb @ emb^T), axis=1)  (fp32, verified)
// ---------------------------------------------------------------------------
__global__ __launch_bounds__(256) void supports_kernel(const float* __restrict__ emb,
                                                       float* __restrict__ S)
{
    int n = blockIdx.x;
    __shared__ float row[Nn];
    __shared__ float en[Ee];
    __shared__ float red[256];
    int tid = threadIdx.x;
    if (tid < Ee) en[tid] = emb[n*Ee + tid];
    __syncthreads();
    float lmax = -1e30f;
    for (int j = tid; j < Nn; j += 256){
        float d = 0.f;
        #pragma unroll
        for (int e = 0; e < Ee; ++e) d += en[e]*emb[j*Ee + e];
        d = d > 0.f ? d : 0.f;
        row[j] = d;
        lmax = fmaxf(lmax, d);
    }
    red[tid] = lmax; __syncthreads();
    for (int s = 128; s > 0; s >>= 1){ if (tid < s) red[tid] = fmaxf(red[tid], red[tid+s]); __syncthreads(); }
    float mx = red[0]; __syncthreads();
    float lsum = 0.f;
    for (int j = tid; j < Nn; j += 256){ float e = expf(row[j]-mx); row[j] = e; lsum += e; }
    red[tid] = lsum; __syncthreads();
    for (int s = 128; s > 0; s >>= 1){ if (tid < s) red[tid] += red[tid+s]; __syncthreads(); }
    float inv = 1.f/red[0];
    for (int j = tid; j < Nn; j += 256) S[n*Nn + j] = row[j]*inv;
}

// ---------------------------------------------------------------------------
// T2 = 2*S@S - I   (fp32, verified)
// ---------------------------------------------------------------------------
__global__ __launch_bounds__(256) void t2_gemm(const float* __restrict__ S,
                                               float* __restrict__ T2)
{
    int n0 = blockIdx.y*64, j0 = blockIdx.x*64;
    __shared__ float As[16][65];
    __shared__ float Xs[16][65];
    int tid = threadIdx.x; int tx = tid & 15, ty = tid >> 4;
    float acc[4][4] = {};
    for (int k0 = 0; k0 < Nn; k0 += 16){
        #pragma unroll
        for (int r = 0; r < 4; ++r){
            int idx = tid + r*256;
            int ar = idx >> 4, ak = idx & 15;
            As[ak][ar] = S[(n0+ar)*Nn + k0+ak];
        }
        #pragma unroll
        for (int r = 0; r < 4; ++r){
            int idx = tid + r*256;
            int xm = idx >> 6, xj = idx & 63;
            Xs[xm][xj] = S[(k0+xm)*Nn + j0+xj];
        }
        __syncthreads();
        #pragma unroll
        for (int kk = 0; kk < 16; ++kk){
            float a[4], xv[4];
            #pragma unroll
            for (int i = 0; i < 4; ++i) a[i]  = As[kk][ty*4+i];
            #pragma unroll
            for (int j = 0; j < 4; ++j) xv[j] = Xs[kk][tx*4+j];
            #pragma unroll
            for (int i = 0; i < 4; ++i)
                #pragma unroll
                for (int j = 0; j < 4; ++j) acc[i][j] += a[i]*xv[j];
        }
        __syncthreads();
    }
    #pragma unroll
    for (int i = 0; i < 4; ++i){
        int n = n0 + ty*4 + i;
        #pragma unroll
        for (int j = 0; j < 4; ++j){
            int c = j0 + tx*4 + j;
            T2[n*Nn + c] = 2.f*acc[i][j] - (n == c ? 1.f : 0.f);
        }
    }
}

// ---------------------------------------------------------------------------
// FUSED encoder cat builder + transpose: computes v(n,j) once, writes BOTH
// cat[n][j] (row-major, == old (rb*CPe+c) layout) and catT[j][n] via LDS tile.
// PHASE 1: h source;  PHASE 2: zr*h source.  grid (JPe/64, 16), 256 thr.
// ---------------------------------------------------------------------------
template<int PHASE>
__global__ __launch_bounds__(256) void build_encT(
    const float* __restrict__ x, const float* __restrict__ h,
    const float* __restrict__ zre,
    ushort* __restrict__ chi, ushort* __restrict__ clo,
    ushort* __restrict__ cThi, ushort* __restrict__ cTlo, int t)
{
    __shared__ ushort th[64][66];
    __shared__ ushort tl[64][66];
    int j0 = blockIdx.x*64, n0 = blockIdx.y*64;
    for (int i = threadIdx.x; i < 4096; i += 256){
        int r = i >> 6, cc = i & 63;          // r = n_local, cc = j_local
        int n = n0 + r, j = j0 + cc;
        int b = j / CPe, c = j % CPe;
        size_t rb = (size_t)n*64 + b;
        float v;
        if (c == 0)       v = x[((size_t)b*Tt + t)*Nn + n];
        else if (c < 129) v = (PHASE == 1) ? h[rb*Hh + (c-1)]
                                           : zre[rb*ZRE + (c-1)] * h[rb*Hh + (c-1)];
        else              v = 0.f;
        ushort hi, lo; splitf16(v*16.f, hi, lo);
        th[r][cc] = hi; tl[r][cc] = lo;
        chi[(size_t)n*JPe + j] = hi;
        clo[(size_t)n*JPe + j] = lo;
    }
    __syncthreads();
    for (int i = threadIdx.x; i < 4096; i += 256){
        int cc = i >> 6, r = i & 63;
        size_t d = (size_t)(j0+cc)*1024 + n0 + r;
        cThi[d] = th[r][cc];
        cTlo[d] = tl[r][cc];
    }
}

// ---------------------------------------------------------------------------
// FUSED decoder cat builder + transpose (bf16).  grid (JPd/64, 16).
// ---------------------------------------------------------------------------
template<int PHASE>
__global__ __launch_bounds__(256) void build_decT(
    const float* __restrict__ go, const float* __restrict__ yc,
    const float* __restrict__ h, const bf16* __restrict__ zrb,
    bf16* __restrict__ cat, bf16* __restrict__ catT, int t)
{
    __shared__ ushort tt[64][66];
    int j0 = blockIdx.x*64, n0 = blockIdx.y*64;
    for (int i = threadIdx.x; i < 4096; i += 256){
        int r = i >> 6, cc = i & 63;
        int n = n0 + r, j = j0 + cc;
        int b = j / CPd, c = j % CPd;
        size_t rb = (size_t)n*64 + b;
        float v;
        if (c == 0)       v = go[rb];
        else if (c == 1)  v = yc[((size_t)b*HORt + t)*Nn + n];
        else if (c < 194) v = (PHASE == 1) ? h[rb*DECHd + (c-2)]
                                           : b2f(zrb[rb*LDZR + (c-2)]) * h[rb*DECHd + (c-2)];
        else              v = 0.f;
        bf16 bv = f2b(v);
        tt[r][cc] = __builtin_bit_cast(ushort, bv);
        cat[(size_t)n*JPd + j] = bv;
    }
    __syncthreads();
    for (int i = threadIdx.x; i < 4096; i += 256){
        int cc = i >> 6, r = i & 63;
        bf16 bv = __builtin_bit_cast(bf16, tt[r][cc]);
        catT[(size_t)(j0+cc)*1024 + n0 + r] = bv;
    }
}

// ---------------------------------------------------------------------------
// split-fp16 3-pass MFMA GEMM (r12-verified)
// ---------------------------------------------------------------------------
template<int EPI>
__global__ __launch_bounds__(256) void mfma_split(
    const ushort* __restrict__ Ah0, const ushort* __restrict__ Al0,
    const ushort* __restrict__ Ah1, const ushort* __restrict__ Al1,
    const ushort* __restrict__ Ah2, const ushort* __restrict__ Al2,
    const ushort* __restrict__ BhT0, const ushort* __restrict__ BlT0,
    const ushort* __restrict__ BhT1, const ushort* __restrict__ BlT1,
    const ushort* __restrict__ BhT2, const ushort* __restrict__ BlT2,
    int nmat, int Ksz, int lda, int ldbT,
    ushort* __restrict__ OutHi, ushort* __restrict__ OutLo, int ldc, int Ncols,
    float* __restrict__ OutF, int ldo,
    const float* __restrict__ bias, const float* __restrict__ zrf,
    float* __restrict__ hbuf, int Hd)
{
    __shared__ short Ah_s[128*32];
    __shared__ short Al_s[128*32];
    __shared__ short Bh_s[128*32];
    __shared__ short Bl_s[128*32];
    int tid = threadIdx.x;
    int m0 = blockIdx.y * 128;
    int n0 = blockIdx.x * 128;
    int wave = tid >> 6, lane = tid & 63;
    int wr = wave >> 1, wc = wave & 1;
    int lr = lane & 15, lk8 = lane >> 4;

    f32x4 acc[4][4];
    #pragma unroll
    for (int i = 0; i < 4; ++i)
        #pragma unroll
        for (int j = 0; j < 4; ++j) acc[i][j] = (f32x4){0.f,0.f,0.f,0.f};

    const ushort* Ahs[3] = {Ah0, Ah1, Ah2};
    const ushort* Als[3] = {Al0, Al1, Al2};
    const ushort* Bhs[3] = {BhT0, BhT1, BhT2};
    const ushort* Bls[3] = {BlT0, BlT1, BlT2};

    int wbase = wave * 1024;

    for (int km = 0; km < nmat; ++km){
        const ushort* Agh = Ahs[km]; const ushort* Agl = Als[km];
        const ushort* Bgh = Bhs[km]; const ushort* Bgl = Bls[km];
        for (int k0 = 0; k0 < Ksz; k0 += 32){
            #pragma unroll
            for (int r = 0; r < 2; ++r){
                int i = tid + r*256;
                int row = i >> 2, q = i & 3;
                int sq = q ^ SWZ(row);
                size_t soA = (size_t)(m0+row)*lda  + k0 + sq*8;
                size_t soB = (size_t)(n0+row)*ldbT + k0 + sq*8;
                int lofs = r*4096 + wbase;
                GLOAD_LDS16(Agh + soA, (char*)Ah_s + lofs);
                GLOAD_LDS16(Agl + soA, (char*)Al_s + lofs);
                GLOAD_LDS16(Bgh + soB, (char*)Bh_s + lofs);
                GLOAD_LDS16(Bgl + soB, (char*)Bl_s + lofs);
            }
            __syncthreads();
            half8 ah[4], al[4], bh[4], bl[4];
            #pragma unroll
            for (int mi = 0; mi < 4; ++mi){
                int row = wr*64 + mi*16 + lr;
                int off = row*64 + ((lk8 ^ SWZ(row)) << 4);
                ah[mi] = *(const half8*)((const char*)Ah_s + off);
                al[mi] = *(const half8*)((const char*)Al_s + off);
            }
            #pragma unroll
            for (int ni = 0; ni < 4; ++ni){
                int col = wc*64 + ni*16 + lr;
                int off = col*64 + ((lk8 ^ SWZ(col)) << 4);
                bh[ni] = *(const half8*)((const char*)Bh_s + off);
                bl[ni] = *(const half8*)((const char*)Bl_s + off);
            }
            #pragma unroll
            for (int mi = 0; mi < 4; ++mi)
                #pragma unroll
                for (int ni = 0; ni < 4; ++ni){
                    acc[mi][ni] = __builtin_amdgcn_mfma_f32_16x16x32_f16(ah[mi], bh[ni], acc[mi][ni], 0, 0, 0);
                    acc[mi][ni] = __builtin_amdgcn_mfma_f32_16x16x32_f16(ah[mi], bl[ni], acc[mi][ni], 0, 0, 0);
                    acc[mi][ni] = __builtin_amdgcn_mfma_f32_16x16x32_f16(al[mi], bh[ni], acc[mi][ni], 0, 0, 0);
                }
            __syncthreads();
        }
    }

    int rbase = lk8 * 4;
    #pragma unroll
    for (int mi = 0; mi < 4; ++mi){
        #pragma unroll
        for (int ni = 0; ni < 4; ++ni){
            int gn = n0 + wc*64 + ni*16 + lr;
            if (gn >= Ncols) continue;
            #pragma unroll
            for (int rg = 0; rg < 4; ++rg){
                int gm = m0 + wr*64 + mi*16 + rbase + rg;
                float v = acc[mi][ni][rg] * INV_SCALE;
                if (EPI == 0){
                    ushort h, l;
                    splitf16(v, h, l);
                    OutHi[(size_t)gm*ldc + gn] = h;
                    OutLo[(size_t)gm*ldc + gn] = l;
                } else if (EPI == 1){
                    v += bias[gn];
                    OutF[(size_t)gm*ldo + gn] = 1.f/(1.f + expf(-v));
                } else {
                    float hc = tanhf(v + bias[gn]);
                    float rr = zrf[(size_t)gm*ldo + Hd + gn];
                    float ho = hbuf[(size_t)gm*Hd + gn];
                    hbuf[(size_t)gm*Hd + gn] = rr*ho + (1.f-rr)*hc;
                }
            }
        }
    }
}

// ---------------------------------------------------------------------------
// decoder bf16 MFMA GEMM (r12-verified)
// ---------------------------------------------------------------------------
template<int EPI>
__global__ __launch_bounds__(256) void mfma_gemm(
    const ushort* __restrict__ A0, const ushort* __restrict__ A1, const ushort* __restrict__ A2,
    const ushort* __restrict__ BT0, const ushort* __restrict__ BT1, const ushort* __restrict__ BT2,
    int nmat, int Ksz, int lda, int ldbT,
    bf16* __restrict__ Cout, int ldc, int Ncols,
    const float* __restrict__ bias,
    const bf16* __restrict__ zr, float* __restrict__ hbuf, int Hd)
{
    __shared__ short As[128*32];
    __shared__ short Bs[128*32];
    int tid = threadIdx.x;
    int m0 = blockIdx.y * 128;
    int n0 = blockIdx.x * 128;
    int wave = tid >> 6, lane = tid & 63;
    int wr = wave >> 1, wc = wave & 1;
    int lr = lane & 15, lk8 = lane >> 4;

    f32x4 acc[4][4];
    #pragma unroll
    for (int i = 0; i < 4; ++i)
        #pragma unroll
        for (int j = 0; j < 4; ++j) acc[i][j] = (f32x4){0.f,0.f,0.f,0.f};

    const ushort* Aps[3] = {A0, A1, A2};
    const ushort* Bps[3] = {BT0, BT1, BT2};

    int wbase = wave * 1024;

    for (int km = 0; km < nmat; ++km){
        const ushort* Ag = Aps[km];
        const ushort* Bg = Bps[km];
        for (int k0 = 0; k0 < Ksz; k0 += 32){
            #pragma unroll
            for (int r = 0; r < 2; ++r){
                int i = tid + r*256;
                int row = i >> 2, q = i & 3;
                int sq = q ^ SWZ(row);
                size_t soA = (size_t)(m0+row)*lda  + k0 + sq*8;
                size_t soB = (size_t)(n0+row)*ldbT + k0 + sq*8;
                int lofs = r*4096 + wbase;
                GLOAD_LDS16(Ag + soA, (char*)As + lofs);
                GLOAD_LDS16(Bg + soB, (char*)Bs + lofs);
            }
            __syncthreads();
            short8 af[4], bfv[4];
            #pragma unroll
            for (int mi = 0; mi < 4; ++mi){
                int row = wr*64 + mi*16 + lr;
                int off = row*64 + ((lk8 ^ SWZ(row)) << 4);
                af[mi] = *(const short8*)((const char*)As + off);
            }
            #pragma unroll
            for (int ni = 0; ni < 4; ++ni){
                int col = wc*64 + ni*16 + lr;
                int off = col*64 + ((lk8 ^ SWZ(col)) << 4);
                bfv[ni] = *(const short8*)((const char*)Bs + off);
            }
            #pragma unroll
            for (int mi = 0; mi < 4; ++mi)
                #pragma unroll
                for (int ni = 0; ni < 4; ++ni)
                    acc[mi][ni] = __builtin_amdgcn_mfma_f32_16x16x32_bf16(
                                      af[mi], bfv[ni], acc[mi][ni], 0, 0, 0);
            __syncthreads();
        }
    }

    int rbase = lk8 * 4;
    #pragma unroll
    for (int mi = 0; mi < 4; ++mi){
        #pragma unroll
        for (int ni = 0; ni < 4; ++ni){
            int gn = n0 + wc*64 + ni*16 + lr;
            if (gn >= Ncols) continue;
            #pragma unroll
            for (int rg = 0; rg < 4; ++rg){
                int gm = m0 + wr*64 + mi*16 + rbase + rg;
                float v = acc[mi][ni][rg];
                if (EPI == 0){
                    Cout[(size_t)gm*ldc + gn] = f2b(v);
                } else if (EPI == 1){
                    v += bias[gn];
                    Cout[(size_t)gm*ldc + gn] = f2b(1.f/(1.f + expf(-v)));
                } else {
                    float hc = tanhf(v + bias[gn]);
                    float rr = b2f(zr[(size_t)gm*LDZR + Hd + gn]);
                    float ho = hbuf[(size_t)gm*Hd + gn];
                    hbuf[(size_t)gm*Hd + gn] = rr*ho + (1.f-rr)*hc;
                }
            }
        }
    }
}

// ---------------------------------------------------------------------------
// attention (fp32, verified)
// ---------------------------------------------------------------------------
__global__ __launch_bounds__(64) void attn_kernel(const float* __restrict__ hT,
                                                  const float* __restrict__ Wq,
                                                  const float* __restrict__ Mem,
                                                  float* __restrict__ hdec,
                                                  int* __restrict__ ind0,
                                                  float* __restrict__ outv,
                                                  float* __restrict__ outq,
                                                  float* __restrict__ outp)
{
    int rb = blockIdx.x; int n = rb / Bb, b = rb % Bb;
    int tid = threadIdx.x;
    __shared__ float hl[Hh];
    __shared__ float ql[MDd];
    __shared__ float sm[Mm];
    __shared__ float stats[2];
    __shared__ int   smind;
    hl[tid]      = hT[(size_t)rb*Hh + tid];
    hl[tid + 64] = hT[(size_t)rb*Hh + tid + 64];
    __syncthreads();
    float q = 0.f;
    for (int hh = 0; hh < Hh; ++hh) q += hl[hh]*Wq[hh*MDd + tid];
    ql[tid] = q;
    size_t bn = (size_t)b*Nn + n;
    outq[bn*MDd + tid] = q;
    __syncthreads();
    if (tid < Mm){
        float s = 0.f;
        for (int d = 0; d < MDd; ++d) s += ql[d]*Mem[tid*MDd + d];
        sm[tid] = s;
    }
    __syncthreads();
    if (tid == 0){
        float mx = -1e30f; int am = 0;
        for (int m = 0; m < Mm; ++m) if (sm[m] > mx){ mx = sm[m]; am = m; }
        float ssum = 0.f;
        for (int m = 0; m < Mm; ++m){ float e = expf(sm[m]-mx); sm[m] = e; ssum += e; }
        stats[0] = 1.f/ssum; smind = am;
    }
    __syncthreads();
    float inv = stats[0]; int am = smind;
    float val = 0.f;
    for (int m = 0; m < Mm; ++m) val += sm[m]*inv*Mem[m*MDd + tid];
    outv[bn*MDd + tid] = val;
    outp[bn*MDd + tid] = Mem[am*MDd + tid];
    hdec[(size_t)rb*DECHd + tid]       = hl[tid];
    hdec[(size_t)rb*DECHd + 64 + tid]  = hl[tid + 64];
    hdec[(size_t)rb*DECHd + 128 + tid] = val;
    if (tid == 0) ind0[rb] = am;
}

__global__ void neg_kernel(const float* __restrict__ Mem, float* __restrict__ outn)
{
    size_t idx = (size_t)blockIdx.x*256 + threadIdx.x;
    outn[idx] = Mem[idx % (Mm*MDd)];
}

__global__ void mask_kernel(const int* __restrict__ ind0, float* __restrict__ outm)
{
    size_t idx = (size_t)blockIdx.x*256 + threadIdx.x;
    int m   = (int)(idx % Mm);
    size_t bn = idx / Mm;
    int n = (int)(bn % Nn);
    int b = (int)(bn / Nn);
    int rb = n*Bb + b;
    outm[idx] = (m != ind0[rb]) ? 1.f : 0.f;
}

__global__ __launch_bounds__(256) void proj_kernel(const float* __restrict__ h,
                                                   const float* __restrict__ pw,
                                                   const float* __restrict__ pb,
                                                   float* __restrict__ go,
                                                   float* __restrict__ out0, int t)
{
    int rb = blockIdx.x*4 + (threadIdx.x >> 6);
    int lane = threadIdx.x & 63;
    float s = 0.f;
    #pragma unroll
    for (int r = 0; r < 3; ++r){
        int i = lane + r*64;
        s += h[(size_t)rb*DECHd + i]*pw[i];
    }
    #pragma unroll
    for (int off = 32; off > 0; off >>= 1) s += __shfl_down(s, off, 64);
    if (lane == 0){
        float v = s + pb[0];
        go[rb] = v;
        int n = rb / Bb, b = rb % Bb;
        out0[((size_t)b*HORt + t)*Nn + n] = v;
    }
}

// ---------------------------------------------------------------------------
extern "C" void kernel_launch(void* const* d_in, const int* in_sizes, int n_in,
                              void* d_out, int out_size, void* d_ws, size_t ws_size,
                              hipStream_t stream)
{
    const float* x    = (const float*)d_in[0];
    const float* ycov = (const float*)d_in[1];
    const float* emb  = (const float*)d_in[2];
    const float* Mem  = (const float*)d_in[3];
    const float* Wq   = (const float*)d_in[4];
    const float* eWg  = (const float*)d_in[5];
    const float* ebg  = (const float*)d_in[6];
    const float* eWu  = (const float*)d_in[7];
    const float* ebu  = (const float*)d_in[8];
    const float* dWg  = (const float*)d_in[9];
    const float* dbg  = (const float*)d_in[10];
    const float* dWu  = (const float*)d_in[11];
    const float* dbu  = (const float*)d_in[12];
    const float* pW   = (const float*)d_in[13];
    const float* pb   = (const float*)d_in[14];

    float* out        = (float*)d_out;
    float* out_output = out;
    float* out_value  = out + 786432;
    float* out_query  = out + 4980736;
    float* out_pos    = out + 9175040;
    float* out_neg    = out + 13369344;          // 83,886,080 floats (335.5 MB)
    float* out_mask   = out + 97255424;

    // determinism hammer (r7-verified): identical state every call
    hipMemsetAsync(d_out, 0, (size_t)out_size * 4, stream);

    // ---- out_neg scratch, time-shared ----
    ushort* catEh  = (ushort*)out_neg;                       // 31,457,280
    ushort* catEl  = catEh + 31457280;                       // 31,457,280
    ushort* catETh = catEl + 31457280;                       // 10,485,760
    ushort* catETl = catETh + 10485760;                      // 10,485,760
    float*  zrE    = (float*)(catETl + 10485760);            // 16,777,216 fp32
    bf16*  cat0  = (bf16*)out_neg;                           // 14,680,064
    bf16*  cat1  = cat0 + 14680064;
    bf16*  cat2  = cat1 + 14680064;
    bf16*  cat0T = cat2 + 14680064;                          // 14,680,064
    bf16*  zrb   = cat0T + 14680064;                         // 25,165,824

    // ---- d_ws layout (~107 MB; ws >= 173 MB, r3) ----
    const size_t NEED = 106979328;
    if (ws_size < NEED){
        ws_probe_kernel<<<3072, 256, 0, stream>>>(out_output, (float)(ws_size >> 20));
        return;
    }
    float*  Sf    = (float*)d_ws;                // 1,048,576 f32
    float*  T2f   = Sf + 1048576;                // 1,048,576 f32
    ushort* Sh    = (ushort*)(T2f + 1048576);    // [Sh|T2h] stacked hi
    ushort* T2h   = Sh  + 1048576;
    ushort* Sl    = T2h + 1048576;               // [Sl|T2l] stacked lo
    ushort* T2l   = Sl  + 1048576;
    bf16*   Sb    = (bf16*)(T2l + 1048576);      // [Sb|T2b] stacked bf16
    bf16*   T2b   = Sb + 1048576;
    ushort* wgETh = (ushort*)(T2b + 1048576);    // 3*256*160 = 122,880
    ushort* wgETl = wgETh + 122880;
    ushort* wuETh = wgETl + 122880;              // 3*128*160 = 61,440
    ushort* wuETl = wuETh + 61440;
    bf16*   wgDT  = (bf16*)(wuETl + 61440);      // 3*384*224 = 258,048
    bf16*   wuDT  = wgDT + 258048;               // 3*256*224 = 172,032
    float*  henc  = (float*)(wuDT + 172032);     // 8,388,608 f32
    float*  hdec  = henc + 8388608;              // 12,582,912 f32
    float*  go    = hdec + 12582912;             // 65,536 f32
    int*    ind0  = (int*)(go + 65536);          // 65,536 int

    hipMemsetAsync(henc, 0, (size_t)8388608*4, stream);
    hipMemsetAsync(go,   0, (size_t)65536*4,   stream);

    supports_kernel<<<Nn, 256, 0, stream>>>(emb, Sf);
    t2_gemm<<<dim3(16,16), 256, 0, stream>>>(Sf, T2f);
    conv_split<<<4096, 256, 0, stream>>>(Sf,  Sh,  Sl,  4096.f);
    conv_split<<<4096, 256, 0, stream>>>(T2f, T2h, T2l, 4096.f);
    conv_f2b<<<4096, 256, 0, stream>>>(Sf,  Sb);
    conv_f2b<<<4096, 256, 0, stream>>>(T2f, T2b);
    conv_w_split_T<<<480, 256, 0, stream>>>(eWg, wgETh, wgETl, 129, CPe, 256);
    conv_w_split_T<<<240, 256, 0, stream>>>(eWu, wuETh, wuETl, 129, CPe, 128);
    conv_w_T<<<1008, 256, 0, stream>>>(dWg, wgDT, 194, CPd, 384, 384);
    conv_w_T<<<672,  256, 0, stream>>>(dWu, wuDT, 194, CPd, 192, 256);

    const size_t SL = (size_t)65536*CPe;         // 10,485,760 = 1024*JPe (contig!)

    // -------- encoder: 12 steps, split-fp16 MFMA; fused build+T --------
    for (int t = 0; t < Tt; ++t){
        build_encT<1><<<dim3(JPe/64, 16), 256, 0, stream>>>(
            x, henc, nullptr, catEh, catEl, catETh, catETl, t);
        mfma_split<0><<<dim3(JPe/128, 16), 256, 0, stream>>>(
            Sh, Sl, nullptr, nullptr, nullptr, nullptr,
            catETh, catETl, nullptr, nullptr, nullptr, nullptr,
            1, Nn, Nn, Nn,
            catEh + SL, catEl + SL, JPe, JPe, nullptr, 0, nullptr, nullptr, nullptr, 0);
        mfma_split<1><<<dim3(2, 512), 256, 0, stream>>>(
            catEh, catEl, catEh + SL, catEl + SL, catEh + 2*SL, catEl + 2*SL,
            wgETh, wgETl, wgETh + 40960, wgETl + 40960, wgETh + 81920, wgETl + 81920,
            3, CPe, CPe, CPe,
            nullptr, nullptr, 0, 256, zrE, ZRE, ebg, nullptr, nullptr, 0);
        build_encT<2><<<dim3(JPe/64, 16), 256, 0, stream>>>(
            x, henc, zrE, catEh, catEl, catETh, catETl, t);
        mfma_split<0><<<dim3(JPe/128, 16), 256, 0, stream>>>(
            Sh, Sl, nullptr, nullptr, nullptr, nullptr,
            catETh, catETl, nullptr, nullptr, nullptr, nullptr,
            1, Nn, Nn, Nn,
            catEh + SL, catEl + SL, JPe, JPe, nullptr, 0, nullptr, nullptr, nullptr, 0);
        mfma_split<2><<<dim3(1, 512), 256, 0, stream>>>(
            catEh, catEl, catEh + SL, catEl + SL, catEh + 2*SL, catEl + 2*SL,
            wuETh, wuETl, wuETh + 20480, wuETl + 20480, wuETh + 40960, wuETl + 40960,
            3, CPe, CPe, CPe,
            nullptr, nullptr, 0, 128, nullptr, ZRE, ebu, zrE, henc, 128);
    }

    // -------- attention (fp32 scores -> exact argmax) --------
    attn_kernel<<<65536, 64, 0, stream>>>(henc, Wq, Mem, hdec, ind0,
                                          out_value, out_query, out_pos);

    const ushort* Su   = (const ushort*)Sb;      // stacked [Sb|T2b]
    const ushort* c0u  = (const ushort*)cat0;
    const ushort* c1u  = (const ushort*)cat1;
    const ushort* c2u  = (const ushort*)cat2;
    const ushort* c0Tu = (const ushort*)cat0T;

    // -------- decoder: 12 steps, bf16 MFMA; fused build+T --------
    for (int t = 0; t < HORt; ++t){
        build_decT<1><<<dim3(JPd/64, 16), 256, 0, stream>>>(
            go, ycov, hdec, nullptr, cat0, cat0T, t);
        mfma_gemm<0><<<dim3(JPd/128, 16), 256, 0, stream>>>(
            Su, nullptr, nullptr, c0Tu, nullptr, nullptr, 1, 1024, 1024, 1024,
            cat1, JPd, JPd, nullptr, nullptr, nullptr, 0);
        mfma_gemm<1><<<dim3(3, 512), 256, 0, stream>>>(
            c0u, c1u, c2u,
            (const ushort*)wgDT, (const ushort*)(wgDT + 86016), (const ushort*)(wgDT + 172032),
            3, CPd, CPd, CPd, zrb, LDZR, 384, dbg, nullptr, nullptr, 0);
        build_decT<2><<<dim3(JPd/64, 16), 256, 0, stream>>>(
            go, ycov, hdec, zrb, cat0, cat0T, t);
        mfma_gemm<0><<<dim3(JPd/128, 16), 256, 0, stream>>>(
            Su, nullptr, nullptr, c0Tu, nullptr, nullptr, 1, 1024, 1024, 1024,
            cat1, JPd, JPd, nullptr, nullptr, nullptr, 0);
        mfma_gemm<2><<<dim3(2, 512), 256, 0, stream>>>(
            c0u, c1u, c2u,
            (const ushort*)wuDT, (const ushort*)(wuDT + 57344), (const ushort*)(wuDT + 114688),
            3, CPd, CPd, CPd, nullptr, 0, 192, dbu, zrb, hdec, 192);
        proj_kernel<<<16384, 256, 0, stream>>>(hdec, pW, pb, go, out_output, t);
    }

    // -------- aux outputs LAST --------
    neg_kernel<<<327680, 256, 0, stream>>>(Mem, out_neg);
    mask_kernel<<<5120, 256, 0, stream>>>(ind0, out_mask);
}